// Round 5
// baseline (750.826 us; speedup 1.0000x reference)
//
#include <hip/hip_runtime.h>
#include <math.h>

#define NB 2
#define C1 128
#define C2 256
#define HH 128
#define WW 128
#define NPIX (HH*WW)
#define NHEADS 8
#define DH 16
#define NG 8

typedef unsigned short u16;
typedef _Float16 f16;
typedef __attribute__((ext_vector_type(8))) _Float16 h8_t;
typedef __attribute__((ext_vector_type(8))) short bf8_t;
typedef __attribute__((ext_vector_type(4))) float f4_t;

__device__ __forceinline__ float sigmoidf_(float v) { return 1.f / (1.f + expf(-v)); }
__device__ __forceinline__ u16 f2bf(float f) {
  unsigned u = __float_as_uint(f);
  return (u16)((u + 0x7FFFu + ((u >> 16) & 1u)) >> 16);
}
__device__ __forceinline__ float bf2f(u16 h) { return __uint_as_float(((unsigned)h) << 16); }

// ---------------- NCHW fp32 (y|x) -> NHWC: f16 cat + bf16 hi/lo cat ----------------
__global__ __launch_bounds__(256) void splitcat_k(const float* __restrict__ y,
                                                  const float* __restrict__ x,
                                                  f16* __restrict__ catf,
                                                  u16* __restrict__ cbh,
                                                  u16* __restrict__ cbl) {
  __shared__ float tile[64][65];
  int b = blockIdx.z, c0 = blockIdx.y * 64, p0 = blockIdx.x * 64;
  int tid = threadIdx.x;
  const float* src = (c0 < 128) ? y : x;
  int cc0 = c0 & 127;
  for (int e = tid; e < 4096; e += 256) {
    int c = e >> 6, p = e & 63;
    tile[c][p] = src[((size_t)b * C1 + cc0 + c) * NPIX + p0 + p];
  }
  __syncthreads();
  for (int e = tid; e < 4096; e += 256) {
    int p = e >> 6, c = e & 63;
    float v = tile[c][p];
    size_t o = ((size_t)b * NPIX + p0 + p) * C2 + c0 + c;
    catf[o] = (f16)v;
    u16 h = f2bf(v);
    cbh[o] = h;
    cbl[o] = f2bf(v - bf2f(h));
  }
}

// ---------------- avgpool2 on bf16-pair cat -> PH/PL [b][4096][256] ----------------
__global__ __launch_bounds__(256) void avgpool_b_k(const u16* __restrict__ cbh,
                                                   const u16* __restrict__ cbl,
                                                   u16* __restrict__ ph,
                                                   u16* __restrict__ pl) {
  int idx = blockIdx.x * 256 + threadIdx.x;
  if (idx >= NB * 4096 * 32) return;
  int c8 = idx & 31;
  int p = (idx >> 5) & 4095;
  int b = idx >> 17;
  int yo = p >> 6, xo = p & 63;
  size_t base = ((size_t)b * NPIX + (yo * 2) * WW + xo * 2) * C2 + c8 * 8;
  const size_t d01 = C2, d10 = (size_t)WW * C2, d11 = (size_t)WW * C2 + C2;
  bf8_t h00 = *(const bf8_t*)(cbh + base), l00 = *(const bf8_t*)(cbl + base);
  bf8_t h01 = *(const bf8_t*)(cbh + base + d01), l01 = *(const bf8_t*)(cbl + base + d01);
  bf8_t h10 = *(const bf8_t*)(cbh + base + d10), l10 = *(const bf8_t*)(cbl + base + d10);
  bf8_t h11 = *(const bf8_t*)(cbh + base + d11), l11 = *(const bf8_t*)(cbl + base + d11);
  bf8_t oh, ol;
#pragma unroll
  for (int j = 0; j < 8; j++) {
    float v00 = bf2f((u16)h00[j]) + bf2f((u16)l00[j]);
    float v01 = bf2f((u16)h01[j]) + bf2f((u16)l01[j]);
    float v10 = bf2f((u16)h10[j]) + bf2f((u16)l10[j]);
    float v11 = bf2f((u16)h11[j]) + bf2f((u16)l11[j]);
    float v = 0.25f * (v00 + v01 + v10 + v11);
    u16 h = f2bf(v);
    oh[j] = (short)h;
    ol[j] = (short)f2bf(v - bf2f(h));
  }
  size_t o = ((size_t)b * 4096 + p) * C2 + c8 * 8;
  *(bf8_t*)(ph + o) = oh;
  *(bf8_t*)(pl + o) = ol;
}

// ---------------- 3x3-conv weight transform: rows [(t*8+cq)*OCR+oc] of [32hi|32lo] ----------------
__global__ __launch_bounds__(256) void wtrans_k(const float* __restrict__ w, u16* __restrict__ w2,
                                                int OC, int OCR) {
  int idx = blockIdx.x * 256 + threadIdx.x;
  int total = 9 * 256 * OCR;
  if (idx >= total) return;
  int t = idx / (256 * OCR);
  int rem = idx - t * 256 * OCR;
  int ic = rem / OCR;
  int oc = rem - ic * OCR;
  float v = (oc < OC) ? w[((size_t)oc * 256 + ic) * 9 + t] : 0.f;
  u16 h = f2bf(v);
  u16 l = f2bf(v - bf2f(h));
  size_t row = (size_t)(t * 8 + (ic >> 5)) * OCR + oc;
  w2[row * 64 + (ic & 31)] = h;
  w2[row * 64 + 32 + (ic & 31)] = l;
}

// ---------------- 1x1 weight: fp32 -> f16 ----------------
__global__ __launch_bounds__(256) void w1trans_k(const float* __restrict__ w,
                                                 f16* __restrict__ wh, int n) {
  int i = blockIdx.x * 256 + threadIdx.x;
  if (i < n) wh[i] = (f16)w[i];
}

// ---------------- deform weight: [128][16][9] -> [oc][160] f16 ----------------
__global__ __launch_bounds__(256) void wdprep_k(const float* __restrict__ w,
                                                f16* __restrict__ wh) {
  int idx = blockIdx.x * 256 + threadIdx.x;
  if (idx >= 128 * 160) return;
  int oc = idx / 160, k = idx - oc * 160;
  int t = k >> 4, ic = k & 15;
  wh[idx] = (t < 9) ? (f16)w[((size_t)oc * 16 + ic) * 9 + t] : (f16)0.f;
}

// ---------------- implicit-GEMM 3x3 conv, bf16 hi/lo 3-product MFMA, 64px dbuf ----------------
// A rows: 64 px x [32hi|32lo] u16; W rows: OCB oc x [32hi|32lo]. XOR swizzle slot^(row&7).
template<int MF, int NF, int WO, int HO, int WI, int HI, int PAD, int OCTOT, int OCR, bool GATE>
__global__ __launch_bounds__(256) void convmfma_k(
    const u16* __restrict__ inH, const u16* __restrict__ inL,
    const u16* __restrict__ w2,
    const float* __restrict__ gy, const float* __restrict__ gx,
    const float* __restrict__ gB,
    float* __restrict__ outF, u16* __restrict__ outH, u16* __restrict__ outL) {
  constexpr int NW_PX = 64 / (MF * 16);
  constexpr int NW_OC = 4 / NW_PX;
  constexpr int OCB = NW_OC * NF * 16;
  constexpr int WPT = OCB * 8 / 256;  // k3:4 k2:2 k4:1 (all exact)
  __shared__ u16 lds_a[2][64 * 64];
  __shared__ u16 lds_w[2][OCB * 64];
  const int b = blockIdx.z, oc0 = blockIdx.y * OCB, px0 = blockIdx.x * 64;
  const int tid = threadIdx.x, lane = tid & 63, wid = tid >> 6;
  const int wpx = (wid % NW_PX) * (MF * 16);
  const int woc = (wid / NW_PX) * (NF * 16);

  // A stager: thread -> (row=tid>>2, q=tid&3); hi slot q, lo slot q+4
  const int art = tid >> 2, aq = tid & 3;
  const int aopx = px0 + art;
  const int apy = aopx / WO, apxx = aopx % WO;
  const bool aok = aopx < HO * WO;
  const int awoH = art * 64 + ((aq ^ (art & 7)) << 3);
  const int awoL = art * 64 + (((aq + 4) ^ (art & 7)) << 3);
  // W stager: slots s = tid + i*256; row=s>>3, slot=s&7
  int wgrow[WPT], wgslot[WPT], wlo[WPT];
#pragma unroll
  for (int i = 0; i < WPT; i++) {
    int s = tid + i * 256;
    int row = s >> 3, sl = s & 7;
    wgrow[i] = row;
    wgslot[i] = sl;
    wlo[i] = row * 64 + ((sl ^ (row & 7)) << 3);
  }
  // fragment read offsets
  int aofH[MF], aofL[MF], wofH[NF], wofL[NF];
#pragma unroll
  for (int mf = 0; mf < MF; mf++) {
    int r = wpx + mf * 16 + (lane & 15);
    int s = lane >> 4;
    aofH[mf] = r * 64 + ((s ^ (r & 7)) << 3);
    aofL[mf] = r * 64 + (((s + 4) ^ (r & 7)) << 3);
  }
#pragma unroll
  for (int nf = 0; nf < NF; nf++) {
    int r = woc + nf * 16 + (lane & 15);
    int s = lane >> 4;
    wofH[nf] = r * 64 + ((s ^ (r & 7)) << 3);
    wofL[nf] = r * 64 + (((s + 4) ^ (r & 7)) << 3);
  }

  f4_t acc[MF][NF];
#pragma unroll
  for (int mf = 0; mf < MF; mf++)
#pragma unroll
    for (int nf = 0; nf < NF; nf++) { f4_t z = {0.f, 0.f, 0.f, 0.f}; acc[mf][nf] = z; }

  uint4 aRH, aRL;
  uint4 wR[WPT];
  auto load_gc = [&](int gc) {
    int t = gc >> 3, c = gc & 7;
    int ky = t / 3, kx = t - 3 * ky;
    int iy = apy + ky - PAD, ix = apxx + kx - PAD;
    uint4 z = {0, 0, 0, 0};
    aRH = z; aRL = z;
    if (aok && iy >= 0 && iy < HI && ix >= 0 && ix < WI) {
      size_t a0 = ((size_t)b * (HI * WI) + (size_t)(iy * WI + ix)) * 256 + c * 32 + aq * 8;
      aRH = *(const uint4*)(inH + a0);
      aRL = *(const uint4*)(inL + a0);
    }
    const u16* wp = w2 + (size_t)gc * OCR * 64;
#pragma unroll
    for (int i = 0; i < WPT; i++)
      wR[i] = *(const uint4*)(wp + (size_t)(oc0 + wgrow[i]) * 64 + wgslot[i] * 8);
  };
  auto store_gc = [&](int nb) {
    *(uint4*)(lds_a[nb] + awoH) = aRH;
    *(uint4*)(lds_a[nb] + awoL) = aRL;
#pragma unroll
    for (int i = 0; i < WPT; i++) *(uint4*)(lds_w[nb] + wlo[i]) = wR[i];
  };

  load_gc(0);
  store_gc(0);
  for (int gc = 0; gc < 72; ++gc) {
    if (gc < 71) load_gc(gc + 1);
    __syncthreads();
    const int cb = gc & 1;
    bf8_t ah[MF], al[MF], wh[NF], wl[NF];
#pragma unroll
    for (int mf = 0; mf < MF; mf++) {
      ah[mf] = *(const bf8_t*)(lds_a[cb] + aofH[mf]);
      al[mf] = *(const bf8_t*)(lds_a[cb] + aofL[mf]);
    }
#pragma unroll
    for (int nf = 0; nf < NF; nf++) {
      wh[nf] = *(const bf8_t*)(lds_w[cb] + wofH[nf]);
      wl[nf] = *(const bf8_t*)(lds_w[cb] + wofL[nf]);
    }
#pragma unroll
    for (int mf = 0; mf < MF; mf++)
#pragma unroll
      for (int nf = 0; nf < NF; nf++) {
        acc[mf][nf] = __builtin_amdgcn_mfma_f32_16x16x32_bf16(ah[mf], wh[nf], acc[mf][nf], 0, 0, 0);
        acc[mf][nf] = __builtin_amdgcn_mfma_f32_16x16x32_bf16(al[mf], wh[nf], acc[mf][nf], 0, 0, 0);
        acc[mf][nf] = __builtin_amdgcn_mfma_f32_16x16x32_bf16(ah[mf], wl[nf], acc[mf][nf], 0, 0, 0);
      }
    if (gc < 71) store_gc((gc + 1) & 1);
  }

  // epilogue: D row=(lane>>4)*4+r = px, col=lane&15 = oc
#pragma unroll
  for (int mf = 0; mf < MF; mf++) {
    const int pxb = px0 + wpx + mf * 16 + ((lane >> 4) << 2);
#pragma unroll
    for (int nf = 0; nf < NF; nf++) {
      const int oc = oc0 + woc + nf * 16 + (lane & 15);
      if (GATE) {
        const float* gp = (oc < 128) ? gy : gx;
        const size_t gbase = ((size_t)b * C1 + (oc & 127)) * NPIX;
#pragma unroll
        for (int r = 0; r < 4; r++) {
          const int px = pxb + r;
          const int pyy = px >> 7, px2 = px & 127;
          const int iiy = (pyy * 62) >> 7, iix = (px2 * 62) >> 7;
          float gv = gp[gbase + px] + gB[((size_t)b * C2 + oc) * 3844 + iiy * 62 + iix];
          float v = acc[mf][nf][r] * sigmoidf_(gv);
          u16 h = f2bf(v);
          size_t o = ((size_t)b * NPIX + px) * C2 + oc;
          outH[o] = h;
          outL[o] = f2bf(v - bf2f(h));
        }
      } else {
        if (pxb < HO * WO && oc < OCTOT)
          *(f4_t*)&outF[((size_t)b * OCTOT + oc) * (HO * WO) + pxb] = acc[mf][nf];
      }
    }
  }
}

// ---------------- 1x1 conv as fp16 MFMA GEMM, direct-global fragments ----------------
template<int AS, int AOFF, bool BIAS, bool SPLIT_OUT>
__global__ __launch_bounds__(256) void gemm1x1_k(const f16* __restrict__ inA,
                                                 const f16* __restrict__ w,
                                                 const float* __restrict__ bias,
                                                 float* __restrict__ outF,
                                                 f16* __restrict__ outH) {
  const int b = blockIdx.z, nb0 = blockIdx.y * 128, px0 = blockIdx.x * 128;
  const int CoutTot = gridDim.y * 128;
  const int tid = threadIdx.x, lane = tid & 63, wid = tid >> 6;
  const int wpx = px0 + wid * 32;
  const int kslot = (lane >> 4) * 8;

  f4_t acc[2][8];
#pragma unroll
  for (int mf = 0; mf < 2; mf++)
#pragma unroll
    for (int nf = 0; nf < 8; nf++) { f4_t z = {0.f, 0.f, 0.f, 0.f}; acc[mf][nf] = z; }

  size_t arow[2];
#pragma unroll
  for (int mf = 0; mf < 2; mf++)
    arow[mf] = ((size_t)b * NPIX + wpx + mf * 16 + (lane & 15)) * AS + AOFF;
  size_t wrow[8];
#pragma unroll
  for (int nf = 0; nf < 8; nf++)
    wrow[nf] = (size_t)(nb0 + nf * 16 + (lane & 15)) * 128;

#pragma unroll
  for (int ks = 0; ks < 4; ks++) {
    const int ko = ks * 32 + kslot;
    h8_t a[2], bw[8];
#pragma unroll
    for (int mf = 0; mf < 2; mf++) a[mf] = *(const h8_t*)(inA + arow[mf] + ko);
#pragma unroll
    for (int nf = 0; nf < 8; nf++) bw[nf] = *(const h8_t*)(w + wrow[nf] + ko);
#pragma unroll
    for (int mf = 0; mf < 2; mf++)
#pragma unroll
      for (int nf = 0; nf < 8; nf++)
        acc[mf][nf] = __builtin_amdgcn_mfma_f32_16x16x32_f16(a[mf], bw[nf], acc[mf][nf], 0, 0, 0);
  }

#pragma unroll
  for (int mf = 0; mf < 2; mf++) {
    const int pxq = wpx + mf * 16 + (lane >> 4) * 4;
#pragma unroll
    for (int nf = 0; nf < 8; nf++) {
      const int oc = nb0 + nf * 16 + (lane & 15);
      f4_t v = acc[mf][nf];
      if (BIAS) {
        float bv = bias[oc];
        v[0] += bv; v[1] += bv; v[2] += bv; v[3] += bv;
      }
      if (SPLIT_OUT) {
#pragma unroll
        for (int r = 0; r < 4; r++)
          outH[((size_t)b * NPIX + pxq + r) * 128 + oc] = (f16)v[r];
      } else {
        *(f4_t*)&outF[((size_t)b * CoutTot + oc) * NPIX + pxq] = v;
      }
    }
  }
}

// ---------------- fused modulated-deform-conv: NHWC f16 gather + grouped MFMA ----------------
__global__ __launch_bounds__(256) void dgemm_k(const f16* __restrict__ catf,
                                               const float* __restrict__ offs,
                                               const f16* __restrict__ wd,
                                               const float* __restrict__ dbias,
                                               f16* __restrict__ feat) {
  const int b = blockIdx.z, g = blockIdx.y;
  const int px0 = blockIdx.x * 128;
  const int tid = threadIdx.x;
  const int lane = tid & 63, wid = tid >> 6;
  const int chunk = lane >> 4;
  const int thalf = chunk >> 1;
  const int ic0 = (chunk & 1) * 8;
  const f16* yb = catf + (size_t)b * NPIX * C2;  // channels 0..127 of cat = y
  const float* ob = offs + (size_t)b * 18 * NPIX;

  int pm[2];
  float pyb[2], pxb2[2];
#pragma unroll
  for (int mf = 0; mf < 2; mf++) {
    pm[mf] = px0 + wid * 32 + mf * 16 + (lane & 15);
    pyb[mf] = (float)(pm[mf] >> 7);
    pxb2[mf] = (float)(pm[mf] & 127);
  }

  f4_t acc[2];
  { f4_t z = {0.f, 0.f, 0.f, 0.f}; acc[0] = z; acc[1] = z; }

  const size_t wbase = (size_t)(g * 16 + (lane & 15)) * 160;
#pragma unroll
  for (int s = 0; s < 5; s++) {
    h8_t ah[2];
#pragma unroll
    for (int mf = 0; mf < 2; mf++) {
      int t = 2 * s + thalf;
      int teff = t > 8 ? 8 : t;
      float dy = ob[(size_t)(2 * teff) * NPIX + pm[mf]];
      float dx = ob[(size_t)(2 * teff + 1) * NPIX + pm[mf]];
      float mk = sigmoidf_(ob[(size_t)teff * NPIX + pm[mf]]);
      int ky = teff / 3, kx = teff - 3 * ky;
      float pyf = pyb[mf] - 1.f + (float)ky + dy;
      float pxf = pxb2[mf] - 1.f + (float)kx + dx;
      float y0f = floorf(pyf), x0f = floorf(pxf);
      float fy = pyf - y0f, fx = pxf - x0f;
      int y0 = (int)y0f, x0 = (int)x0f;
      int y1 = y0 + 1, x1 = x0 + 1;
      float w00 = (1.f - fy) * (1.f - fx) * mk;
      float w01 = (1.f - fy) * fx * mk;
      float w10 = fy * (1.f - fx) * mk;
      float w11 = fy * fx * mk;
      bool vy0 = (y0 >= 0 && y0 < HH), vy1 = (y1 >= 0 && y1 < HH);
      bool vx0 = (x0 >= 0 && x0 < WW), vx1 = (x1 >= 0 && x1 < WW);
      if (!(vy0 && vx0)) w00 = 0.f;
      if (!(vy0 && vx1)) w01 = 0.f;
      if (!(vy1 && vx0)) w10 = 0.f;
      if (!(vy1 && vx1)) w11 = 0.f;
      int cy0 = min(max(y0, 0), HH - 1), cy1 = min(max(y1, 0), HH - 1);
      int cx0 = min(max(x0, 0), WW - 1), cx1 = min(max(x1, 0), WW - 1);
      const f16* p00 = yb + (size_t)(cy0 * WW + cx0) * C2 + g * 16 + ic0;
      const f16* p01 = yb + (size_t)(cy0 * WW + cx1) * C2 + g * 16 + ic0;
      const f16* p10 = yb + (size_t)(cy1 * WW + cx0) * C2 + g * 16 + ic0;
      const f16* p11 = yb + (size_t)(cy1 * WW + cx1) * C2 + g * 16 + ic0;
      h8_t a00 = *(const h8_t*)p00;
      h8_t a01 = *(const h8_t*)p01;
      h8_t a10 = *(const h8_t*)p10;
      h8_t a11 = *(const h8_t*)p11;
      h8_t hh;
#pragma unroll
      for (int j = 0; j < 8; j++) {
        float sv = w00 * (float)a00[j] + w01 * (float)a01[j] +
                   w10 * (float)a10[j] + w11 * (float)a11[j];
        hh[j] = (f16)sv;
      }
      ah[mf] = hh;
    }
    h8_t wv = *(const h8_t*)(wd + wbase + s * 32 + chunk * 8);
#pragma unroll
    for (int mf = 0; mf < 2; mf++)
      acc[mf] = __builtin_amdgcn_mfma_f32_16x16x32_f16(ah[mf], wv, acc[mf], 0, 0, 0);
  }

  const int oc = g * 16 + (lane & 15);
  const float bv = dbias[oc];
#pragma unroll
  for (int mf = 0; mf < 2; mf++) {
    const int pxq = px0 + wid * 32 + mf * 16 + (lane >> 4) * 4;
#pragma unroll
    for (int r = 0; r < 4; r++) {
      float v = fmaxf(acc[mf][r] + bv, 0.f);  // bias + relu (pw input)
      feat[((size_t)b * NPIX + pxq + r) * 128 + oc] = (f16)v;
    }
  }
}

// ---------------- depthwise 3x3, pad=1 (fp32 NCHW) ----------------
__global__ __launch_bounds__(256) void dw3x3_k(const float* __restrict__ in,
                                               const float* __restrict__ w,
                                               float* __restrict__ out, int Cc) {
  int idx = blockIdx.x * 256 + threadIdx.x;
  int total = NB * Cc * NPIX;
  if (idx >= total) return;
  int n = idx & (NPIX - 1);
  int bc = idx >> 14;
  int c = bc % Cc;
  int yy = n >> 7, xx = n & 127;
  const float* p = in + (size_t)bc * NPIX;
  const float* wc = w + c * 9;
  float acc = 0.f;
#pragma unroll
  for (int ky = 0; ky < 3; ky++) {
    int iy = yy + ky - 1;
    if (iy < 0 || iy >= HH) continue;
#pragma unroll
    for (int kx = 0; kx < 3; kx++) {
      int ix = xx + kx - 1;
      if (ix < 0 || ix >= WW) continue;
      acc += wc[ky * 3 + kx] * p[iy * WW + ix];
    }
  }
  out[idx] = acc;
}

// ---------------- zero small accumulators ----------------
__global__ void zero_k(float* p, int n) {
  int i = blockIdx.x * 256 + threadIdx.x;
  if (i < n) p[i] = 0.f;
}

// ---------------- attention: partial Gram + sumsq ----------------
__global__ __launch_bounds__(256) void attn_partial_k(const float* __restrict__ qbuf,
                                                      const float* __restrict__ kvbuf,
                                                      float* __restrict__ s_acc,
                                                      float* __restrict__ qss,
                                                      float* __restrict__ kss) {
  __shared__ float qs[16][129];
  __shared__ float ks[16][129];
  int b = blockIdx.z, h = blockIdx.y, seg = blockIdx.x;
  int tid = threadIdx.x;
  int dd = tid & 15, cc = tid >> 4;
  int n_start = seg * (NPIX / 16);
  float acc = 0.f, q2 = 0.f, k2s = 0.f;
  const float* qb = qbuf + ((size_t)b * C1 + h * DH) * NPIX;
  const float* kb = kvbuf + ((size_t)b * C2 + h * DH) * NPIX;
  for (int n0 = n_start; n0 < n_start + NPIX / 16; n0 += 128) {
    for (int e = tid; e < 16 * 128; e += 256) {
      int r = e >> 7, col = e & 127;
      qs[r][col] = qb[(size_t)r * NPIX + n0 + col];
      ks[r][col] = kb[(size_t)r * NPIX + n0 + col];
    }
    __syncthreads();
#pragma unroll 8
    for (int j = 0; j < 128; j++) {
      float qv = qs[cc][j], kv = ks[dd][j];
      acc += qv * kv;
      q2 += qv * qv;
      k2s += kv * kv;
    }
    __syncthreads();
  }
  int bh = b * NHEADS + h;
  atomicAdd(&s_acc[((size_t)bh * 16 + cc) * 16 + dd], acc);
  if (dd == 0) atomicAdd(&qss[bh * 16 + cc], q2);
  if (cc == 0) atomicAdd(&kss[bh * 16 + dd], k2s);
}

// ---------------- attention: normalize + softmax ----------------
__global__ __launch_bounds__(256) void attn_final_k(const float* __restrict__ s_acc,
                                                    const float* __restrict__ qss,
                                                    const float* __restrict__ kss,
                                                    const float* __restrict__ temp,
                                                    float* __restrict__ attn) {
  __shared__ float S[16][17];
  __shared__ float qn[16], kn[16];
  int bh = blockIdx.x;
  int h = bh % NHEADS;
  int tid = threadIdx.x;
  int dd = tid & 15, cc = tid >> 4;
  if (tid < 16) {
    qn[tid] = fmaxf(sqrtf(qss[bh * 16 + tid]), 1e-12f);
    kn[tid] = fmaxf(sqrtf(kss[bh * 16 + tid]), 1e-12f);
  }
  __syncthreads();
  float t = temp[h];
  float s = s_acc[((size_t)bh * 16 + cc) * 16 + dd] / (qn[cc] * kn[dd]) * t;
  S[cc][dd] = s;
  __syncthreads();
  float mx = -1e30f;
#pragma unroll
  for (int j = 0; j < 16; j++) mx = fmaxf(mx, S[cc][j]);
  float sum = 0.f;
#pragma unroll
  for (int j = 0; j < 16; j++) sum += expf(S[cc][j] - mx);
  attn[((size_t)bh * 16 + cc) * 16 + dd] = expf(s - mx) / sum;
}

// ---------------- attention: out = attn @ v -> NHWC f16 ----------------
__global__ __launch_bounds__(256) void attnout_k(const float* __restrict__ attn,
                                                 const float* __restrict__ kvbuf,
                                                 f16* __restrict__ outA) {
  __shared__ float s_a[16][16];
  int b = blockIdx.z, h = blockIdx.y;
  int tid = threadIdx.x;
  int bh = b * NHEADS + h;
  s_a[tid >> 4][tid & 15] = attn[((size_t)bh * 16 + (tid >> 4)) * 16 + (tid & 15)];
  __syncthreads();
  int n = blockIdx.x * 256 + tid;
  const float* vb = kvbuf + ((size_t)b * C2 + C1 + h * DH) * NPIX;
  float acc[16];
#pragma unroll
  for (int c = 0; c < 16; c++) acc[c] = 0.f;
#pragma unroll
  for (int d = 0; d < 16; d++) {
    float vv = vb[(size_t)d * NPIX + n];
#pragma unroll
    for (int c = 0; c < 16; c++) acc[c] += s_a[c][d] * vv;
  }
  h8_t o0, o1;
#pragma unroll
  for (int c = 0; c < 8; c++) {
    o0[c] = (f16)acc[c];
    o1[c] = (f16)acc[8 + c];
  }
  size_t base = ((size_t)b * NPIX + n) * 128 + h * 16;
  *(h8_t*)(outA + base) = o0;
  *(h8_t*)(outA + base + 8) = o1;
}

extern "C" void kernel_launch(void* const* d_in, const int* in_sizes, int n_in,
                              void* d_out, int out_size, void* d_ws, size_t ws_size,
                              hipStream_t stream) {
  const float* x = (const float*)d_in[0];
  const float* y = (const float*)d_in[1];
  const float* q_w = (const float*)d_in[2];
  const float* qd_w = (const float*)d_in[3];
  const float* kv_w = (const float*)d_in[4];
  const float* kvd_w = (const float*)d_in[5];
  const float* proj_w = (const float*)d_in[6];
  const float* temperature = (const float*)d_in[7];
  const float* k2_w = (const float*)d_in[8];
  const float* k3_w = (const float*)d_in[9];
  const float* k4_w = (const float*)d_in[10];
  const float* dcn_w = (const float*)d_in[11];
  const float* dcn_b = (const float*)d_in[12];
  const float* pw_w = (const float*)d_in[13];
  const float* pw_b = (const float*)d_in[14];
  float* out = (float*)d_out;

  char* ws = (char*)d_ws;
  size_t off = 0;
  auto alloc = [&](size_t nbytes) {
    char* p = ws + off;
    off += (nbytes + 255) & ~(size_t)255;
    return p;
  };
  f16* CATF = (f16*)alloc((size_t)NB * NPIX * C2 * 2);       // f16 cat (dgemm gathers + q input)
  u16* CBH = (u16*)alloc((size_t)NB * NPIX * C2 * 2);        // bf16-hi cat; later KV1 (fp32, spans CBH+CBL)
  u16* CBL = (u16*)alloc((size_t)NB * NPIX * C2 * 2);
  u16* PH = (u16*)alloc((size_t)NB * 4096 * C2 * 2);
  u16* PL = (u16*)alloc((size_t)NB * 4096 * C2 * 2);
  float* A2 = (float*)alloc((size_t)NB * C2 * 3844 * 4);
  u16* OUT3H = (u16*)alloc((size_t)NB * NPIX * C2 * 2);      // early: QT1 (fp32); late: KVb (fp32 spans both)
  u16* OUT3L = (u16*)alloc((size_t)NB * NPIX * C2 * 2);
  float* OFFS = (float*)alloc((size_t)NB * 18 * NPIX * 4);
  f16* FEAT = (f16*)alloc((size_t)NB * NPIX * C1 * 2);       // later: AO
  f16* AL = (f16*)alloc((size_t)NB * NPIX * C1 * 2);
  float* Qb = (float*)alloc((size_t)NB * C1 * NPIX * 4);
  u16* W2K2 = (u16*)alloc((size_t)72 * 256 * 64 * 2);
  u16* W2K3 = (u16*)alloc((size_t)72 * 256 * 64 * 2);
  u16* W2K4 = (u16*)alloc((size_t)72 * 32 * 64 * 2);
  f16* WD = (f16*)alloc((size_t)128 * 160 * 2);
  f16* WQ = (f16*)alloc((size_t)128 * 128 * 2);
  f16* WPW = (f16*)alloc((size_t)128 * 128 * 2);
  f16* WKV = (f16*)alloc((size_t)256 * 128 * 2);
  f16* WPJ = (f16*)alloc((size_t)128 * 128 * 2);
  float* SACC = (float*)alloc((size_t)(NB * NHEADS * 256 + 512 + NB * NHEADS * 256) * 4);
  float* QSS = SACC + NB * NHEADS * 256;
  float* KSS = QSS + 256;
  float* ATTN = KSS + 256;

  // region reuse (lifetimes: QT1 dead before k3; CBH/CBL dead after k3;
  // OUT3 dead after k4; FEAT dead after pw)
  float* QT1 = (float*)OUT3H;   // q 1x1 out, fp32, 16.78MB
  float* KV1 = (float*)CBH;     // kv 1x1 out, fp32, spans CBH+CBL (33.55MB)
  float* KVb = (float*)OUT3H;   // kv dw out, fp32, spans OUT3H+OUT3L
  f16* AO = FEAT;               // attn out

  dim3 blk(256);

  // weight prep
  w1trans_k<<<dim3(64), blk, 0, stream>>>(q_w, WQ, 128 * 128);
  w1trans_k<<<dim3(64), blk, 0, stream>>>(pw_w, WPW, 128 * 128);
  w1trans_k<<<dim3(128), blk, 0, stream>>>(kv_w, WKV, 256 * 128);
  w1trans_k<<<dim3(64), blk, 0, stream>>>(proj_w, WPJ, 128 * 128);
  wdprep_k<<<dim3(80), blk, 0, stream>>>(dcn_w, WD);
  wtrans_k<<<dim3((9 * 256 * 256 + 255) / 256), blk, 0, stream>>>(k2_w, W2K2, 256, 256);
  wtrans_k<<<dim3((9 * 256 * 256 + 255) / 256), blk, 0, stream>>>(k3_w, W2K3, 256, 256);
  wtrans_k<<<dim3((9 * 256 * 32 + 255) / 256), blk, 0, stream>>>(k4_w, W2K4, 18, 32);

  // cat split: f16 (gathers/q) + bf16 hi/lo (conv head)
  splitcat_k<<<dim3(NPIX / 64, C2 / 64, NB), blk, 0, stream>>>(y, x, CATF, CBH, CBL);

  // q path: 1x1 MFMA on x-half of catf -> depthwise
  gemm1x1_k<C2, C1, false, false><<<dim3(NPIX / 128, 1, NB), blk, 0, stream>>>(
      CATF, WQ, nullptr, QT1, nullptr);
  dw3x3_k<<<dim3((NB * C1 * NPIX + 255) / 256), blk, 0, stream>>>(QT1, qd_w, Qb, C1);

  // offset head (bf16 hi/lo 3-product)
  avgpool_b_k<<<dim3((NB * 4096 * 32 + 255) / 256), blk, 0, stream>>>(CBH, CBL, PH, PL);
  convmfma_k<2, 2, 62, 62, 64, 64, 0, 256, 256, false>
      <<<dim3(61, 4, NB), blk, 0, stream>>>(PH, PL, W2K2, nullptr, nullptr, nullptr, A2, nullptr, nullptr);
  convmfma_k<2, 4, 128, 128, 128, 128, 1, 256, 256, true>
      <<<dim3(256, 2, NB), blk, 0, stream>>>(CBH, CBL, W2K3, y, x, A2, nullptr, OUT3H, OUT3L);
  convmfma_k<1, 2, 128, 128, 128, 128, 1, 18, 32, false>
      <<<dim3(256, 1, NB), blk, 0, stream>>>(OUT3H, OUT3L, W2K4, nullptr, nullptr, nullptr, OFFS, nullptr, nullptr);

  // deformable alignment (gathers from y-half of catf) + pw 1x1
  dgemm_k<<<dim3(NPIX / 128, NG, NB), blk, 0, stream>>>(CATF, OFFS, WD, dcn_b, FEAT);
  gemm1x1_k<C1, 0, true, true><<<dim3(NPIX / 128, 1, NB), blk, 0, stream>>>(
      FEAT, WPW, pw_b, nullptr, AL);

  // kv path
  gemm1x1_k<C1, 0, false, false><<<dim3(NPIX / 128, 2, NB), blk, 0, stream>>>(
      AL, WKV, nullptr, KV1, nullptr);
  dw3x3_k<<<dim3((NB * C2 * NPIX + 255) / 256), blk, 0, stream>>>(KV1, kvd_w, KVb, C2);

  // attention
  zero_k<<<dim3((4608 + 255) / 256), blk, 0, stream>>>(SACC, 4608);
  attn_partial_k<<<dim3(16, NHEADS, NB), blk, 0, stream>>>(Qb, KVb, SACC, QSS, KSS);
  attn_final_k<<<dim3(NB * NHEADS), blk, 0, stream>>>(SACC, QSS, KSS, temperature, ATTN);
  attnout_k<<<dim3(NPIX / 256, NHEADS, NB), blk, 0, stream>>>(ATTN, KVb, AO);
  gemm1x1_k<C1, 0, false, false><<<dim3(NPIX / 128, 1, NB), blk, 0, stream>>>(
      AO, WPJ, nullptr, out, nullptr);
}

// Round 6
// 523.740 us; speedup vs baseline: 1.4336x; 1.4336x over previous
//
#include <hip/hip_runtime.h>
#include <math.h>

#define NB 2
#define C1 128
#define C2 256
#define HH 128
#define WW 128
#define NPIX (HH*WW)
#define NHEADS 8
#define DH 16
#define NG 8

typedef unsigned short u16;
typedef _Float16 f16;
typedef __attribute__((ext_vector_type(8))) _Float16 h8_t;
typedef __attribute__((ext_vector_type(8))) short bf8_t;
typedef __attribute__((ext_vector_type(4))) float f4_t;

__device__ __forceinline__ float sigmoidf_(float v) { return 1.f / (1.f + expf(-v)); }
__device__ __forceinline__ u16 f2bf(float f) {
  unsigned u = __float_as_uint(f);
  return (u16)((u + 0x7FFFu + ((u >> 16) & 1u)) >> 16);
}
__device__ __forceinline__ float bf2f(u16 h) { return __uint_as_float(((unsigned)h) << 16); }

// ---------------- NCHW fp32 (y|x) -> NHWC: f16 cat + bf16 hi/lo cat ----------------
__global__ __launch_bounds__(256) void splitcat_k(const float* __restrict__ y,
                                                  const float* __restrict__ x,
                                                  f16* __restrict__ catf,
                                                  u16* __restrict__ cbh,
                                                  u16* __restrict__ cbl) {
  __shared__ float tile[64][65];
  int b = blockIdx.z, c0 = blockIdx.y * 64, p0 = blockIdx.x * 64;
  int tid = threadIdx.x;
  const float* src = (c0 < 128) ? y : x;
  int cc0 = c0 & 127;
  for (int e = tid; e < 4096; e += 256) {
    int c = e >> 6, p = e & 63;
    tile[c][p] = src[((size_t)b * C1 + cc0 + c) * NPIX + p0 + p];
  }
  __syncthreads();
  for (int e = tid; e < 4096; e += 256) {
    int p = e >> 6, c = e & 63;
    float v = tile[c][p];
    size_t o = ((size_t)b * NPIX + p0 + p) * C2 + c0 + c;
    catf[o] = (f16)v;
    u16 h = f2bf(v);
    cbh[o] = h;
    cbl[o] = f2bf(v - bf2f(h));
  }
}

// ---------------- avgpool2 on bf16-pair cat -> PH/PL [b][4096][256] ----------------
__global__ __launch_bounds__(256) void avgpool_b_k(const u16* __restrict__ cbh,
                                                   const u16* __restrict__ cbl,
                                                   u16* __restrict__ ph,
                                                   u16* __restrict__ pl) {
  int idx = blockIdx.x * 256 + threadIdx.x;
  if (idx >= NB * 4096 * 32) return;
  int c8 = idx & 31;
  int p = (idx >> 5) & 4095;
  int b = idx >> 17;
  int yo = p >> 6, xo = p & 63;
  size_t base = ((size_t)b * NPIX + (yo * 2) * WW + xo * 2) * C2 + c8 * 8;
  const size_t d01 = C2, d10 = (size_t)WW * C2, d11 = (size_t)WW * C2 + C2;
  bf8_t h00 = *(const bf8_t*)(cbh + base), l00 = *(const bf8_t*)(cbl + base);
  bf8_t h01 = *(const bf8_t*)(cbh + base + d01), l01 = *(const bf8_t*)(cbl + base + d01);
  bf8_t h10 = *(const bf8_t*)(cbh + base + d10), l10 = *(const bf8_t*)(cbl + base + d10);
  bf8_t h11 = *(const bf8_t*)(cbh + base + d11), l11 = *(const bf8_t*)(cbl + base + d11);
  bf8_t oh, ol;
#pragma unroll
  for (int j = 0; j < 8; j++) {
    float v00 = bf2f((u16)h00[j]) + bf2f((u16)l00[j]);
    float v01 = bf2f((u16)h01[j]) + bf2f((u16)l01[j]);
    float v10 = bf2f((u16)h10[j]) + bf2f((u16)l10[j]);
    float v11 = bf2f((u16)h11[j]) + bf2f((u16)l11[j]);
    float v = 0.25f * (v00 + v01 + v10 + v11);
    u16 h = f2bf(v);
    oh[j] = (short)h;
    ol[j] = (short)f2bf(v - bf2f(h));
  }
  size_t o = ((size_t)b * 4096 + p) * C2 + c8 * 8;
  *(bf8_t*)(ph + o) = oh;
  *(bf8_t*)(pl + o) = ol;
}

// ---------------- 3x3-conv weight transform: rows [(t*8+cq)*OCR+oc] of [32hi|32lo] ----------------
__global__ __launch_bounds__(256) void wtrans_k(const float* __restrict__ w, u16* __restrict__ w2,
                                                int OC, int OCR) {
  int idx = blockIdx.x * 256 + threadIdx.x;
  int total = 9 * 256 * OCR;
  if (idx >= total) return;
  int t = idx / (256 * OCR);
  int rem = idx - t * 256 * OCR;
  int ic = rem / OCR;
  int oc = rem - ic * OCR;
  float v = (oc < OC) ? w[((size_t)oc * 256 + ic) * 9 + t] : 0.f;
  u16 h = f2bf(v);
  u16 l = f2bf(v - bf2f(h));
  size_t row = (size_t)(t * 8 + (ic >> 5)) * OCR + oc;
  w2[row * 64 + (ic & 31)] = h;
  w2[row * 64 + 32 + (ic & 31)] = l;
}

// ---------------- 1x1 weight: fp32 -> f16 ----------------
__global__ __launch_bounds__(256) void w1trans_k(const float* __restrict__ w,
                                                 f16* __restrict__ wh, int n) {
  int i = blockIdx.x * 256 + threadIdx.x;
  if (i < n) wh[i] = (f16)w[i];
}

// ---------------- deform weight: [128][16][9] -> [oc][160] f16 ----------------
__global__ __launch_bounds__(256) void wdprep_k(const float* __restrict__ w,
                                                f16* __restrict__ wh) {
  int idx = blockIdx.x * 256 + threadIdx.x;
  if (idx >= 128 * 160) return;
  int oc = idx / 160, k = idx - oc * 160;
  int t = k >> 4, ic = k & 15;
  wh[idx] = (t < 9) ? (f16)w[((size_t)oc * 16 + ic) * 9 + t] : (f16)0.f;
}

// ---------------- implicit-GEMM 3x3 conv via split-bf16 MFMA (R3-measured structure) ----------------
// Block: 128 px x OCB oc, 4 waves. K = 9 taps x 256 ic (BK=32). LDS rows [32hi|32lo], XOR swizzle.
template<int OCB, int WO, int HO, int WI, int HI, int PAD, int OCTOT, int OCR, bool GATE, bool OUTF_NHWC>
__global__ __launch_bounds__(256) void convmfma_k(
    const u16* __restrict__ inH, const u16* __restrict__ inL,
    const u16* __restrict__ w2,
    const float* __restrict__ gy, const float* __restrict__ gx,
    const float* __restrict__ gB,
    float* __restrict__ outF, u16* __restrict__ outH, u16* __restrict__ outL) {
  constexpr int CIN = 256;
  constexpr int MF = (OCB == 128) ? 4 : 2;
  constexpr int NF = (OCB == 128) ? 4 : 2;
  __shared__ u16 lds_a[128 * 64];
  __shared__ u16 lds_w[OCB * 64];
  char* la = (char*)lds_a;
  char* lw = (char*)lds_w;
  const int b = blockIdx.z;
  const int oc0 = blockIdx.y * OCB;
  const int px0 = blockIdx.x * 128;
  const int tid = threadIdx.x;
  const int lane = tid & 63, wid = tid >> 6;
  const int wpx = (OCB == 128) ? ((wid >> 1) * 64) : (wid * 32);
  const int woc = (OCB == 128) ? ((wid & 1) * 64) : 0;

  const int spx = tid >> 1;
  const int shalf = tid & 1;
  const int opx = px0 + spx;
  const int py = opx / WO, pxx = opx % WO;
  const bool prow_ok = (opx < HO * WO);
  const int ar7 = spx & 7;
  const int awo0 = spx * 128 + (((shalf * 2 + 0) ^ ar7) << 4);
  const int awo1 = spx * 128 + (((shalf * 2 + 1) ^ ar7) << 4);
  const int awo2 = spx * 128 + (((shalf * 2 + 4) ^ ar7) << 4);
  const int awo3 = spx * 128 + (((shalf * 2 + 5) ^ ar7) << 4);
  const bool wact = (OCB == 128) ? true : (tid < OCB * 2);
  const int wrow = tid >> 1, whalf = tid & 1;
  int wwo[4];
#pragma unroll
  for (int j = 0; j < 4; j++) wwo[j] = wrow * 128 + (((whalf * 4 + j) ^ (wrow & 7)) << 4);

  int aoh[MF], aol[MF], woh[NF], wol[NF];
#pragma unroll
  for (int mf = 0; mf < MF; mf++) {
    int r = wpx + mf * 16 + (lane & 15);
    int s = lane >> 4;
    aoh[mf] = r * 128 + ((s ^ (r & 7)) << 4);
    aol[mf] = r * 128 + (((s + 4) ^ (r & 7)) << 4);
  }
#pragma unroll
  for (int nf = 0; nf < NF; nf++) {
    int r = woc + nf * 16 + (lane & 15);
    int s = lane >> 4;
    woh[nf] = r * 128 + ((s ^ (r & 7)) << 4);
    wol[nf] = r * 128 + (((s + 4) ^ (r & 7)) << 4);
  }

  f4_t acc[MF][NF];
#pragma unroll
  for (int mf = 0; mf < MF; mf++)
#pragma unroll
    for (int nf = 0; nf < NF; nf++) { f4_t z = {0.f, 0.f, 0.f, 0.f}; acc[mf][nf] = z; }

  const size_t inb = (size_t)b * (HI * WI) * CIN;
  size_t wg = (size_t)(oc0 + wrow) * 64 + (size_t)whalf * 32;
  for (int t = 0; t < 9; t++) {
    const int iy = py + (t / 3) - PAD;
    const int ix = pxx + (t % 3) - PAD;
    const bool val = prow_ok && iy >= 0 && iy < HI && ix >= 0 && ix < WI;
    const int pixoff = iy * WI + ix;
    for (int c = 0; c < CIN / 32; c++) {
      uint4 ah0 = {0,0,0,0}, ah1 = {0,0,0,0}, al0 = {0,0,0,0}, al1 = {0,0,0,0};
      if (val) {
        size_t a0 = inb + (size_t)pixoff * CIN + c * 32 + shalf * 16;
        const uint4* ph = (const uint4*)(inH + a0);
        const uint4* pl = (const uint4*)(inL + a0);
        ah0 = ph[0]; ah1 = ph[1]; al0 = pl[0]; al1 = pl[1];
      }
      uint4 wv0 = {0,0,0,0}, wv1 = {0,0,0,0}, wv2 = {0,0,0,0}, wv3 = {0,0,0,0};
      if (wact) {
        const uint4* q = (const uint4*)(w2 + wg);
        wv0 = q[0]; wv1 = q[1]; wv2 = q[2]; wv3 = q[3];
      }
      __syncthreads();
      *(uint4*)(la + awo0) = ah0;
      *(uint4*)(la + awo1) = ah1;
      *(uint4*)(la + awo2) = al0;
      *(uint4*)(la + awo3) = al1;
      if (wact) {
        *(uint4*)(lw + wwo[0]) = wv0;
        *(uint4*)(lw + wwo[1]) = wv1;
        *(uint4*)(lw + wwo[2]) = wv2;
        *(uint4*)(lw + wwo[3]) = wv3;
      }
      __syncthreads();
      bf8_t ah[MF], al[MF], wh[NF], wl[NF];
#pragma unroll
      for (int mf = 0; mf < MF; mf++) {
        ah[mf] = *(const bf8_t*)(la + aoh[mf]);
        al[mf] = *(const bf8_t*)(la + aol[mf]);
      }
#pragma unroll
      for (int nf = 0; nf < NF; nf++) {
        wh[nf] = *(const bf8_t*)(lw + woh[nf]);
        wl[nf] = *(const bf8_t*)(lw + wol[nf]);
      }
#pragma unroll
      for (int mf = 0; mf < MF; mf++)
#pragma unroll
        for (int nf = 0; nf < NF; nf++) {
          acc[mf][nf] = __builtin_amdgcn_mfma_f32_16x16x32_bf16(ah[mf], wh[nf], acc[mf][nf], 0, 0, 0);
          acc[mf][nf] = __builtin_amdgcn_mfma_f32_16x16x32_bf16(al[mf], wh[nf], acc[mf][nf], 0, 0, 0);
          acc[mf][nf] = __builtin_amdgcn_mfma_f32_16x16x32_bf16(ah[mf], wl[nf], acc[mf][nf], 0, 0, 0);
        }
      wg += (size_t)OCR * 64;
    }
  }

  // epilogue: D row=(lane>>4)*4+r = px, col=lane&15 = oc  [m89-verified]
#pragma unroll
  for (int mf = 0; mf < MF; mf++) {
    const int pxb = px0 + wpx + mf * 16 + ((lane >> 4) << 2);
#pragma unroll
    for (int nf = 0; nf < NF; nf++) {
      const int oc = oc0 + woc + nf * 16 + (lane & 15);
      if (GATE) {
        const float* gp = (oc < 128) ? gy : gx;
        const size_t gbase = ((size_t)b * C1 + (oc & 127)) * NPIX;
#pragma unroll
        for (int r = 0; r < 4; r++) {
          const int px = pxb + r;
          const int pyy = px >> 7, px2 = px & 127;
          const int iiy = (pyy * 62) >> 7, iix = (px2 * 62) >> 7;
          float gv = gp[gbase + px] + gB[((size_t)b * 3844 + iiy * 62 + iix) * 256 + oc];
          float v = acc[mf][nf][r] * sigmoidf_(gv);
          u16 h = f2bf(v);
          size_t o = ((size_t)b * NPIX + px) * C2 + oc;
          outH[o] = h;
          outL[o] = f2bf(v - bf2f(h));
        }
      } else if (OUTF_NHWC) {
        if (oc < OCTOT) {
#pragma unroll
          for (int r = 0; r < 4; r++) {
            const int px = pxb + r;
            if (px < HO * WO)
              outF[((size_t)b * (HO * WO) + px) * OCTOT + oc] = acc[mf][nf][r];
          }
        }
      } else {
        if (pxb < HO * WO && oc < OCTOT)
          *(f4_t*)&outF[((size_t)b * OCTOT + oc) * (HO * WO) + pxb] = acc[mf][nf];
      }
    }
  }
}

// ---------------- 1x1 conv as fp16 MFMA GEMM, direct-global fragments ----------------
template<int AS, int AOFF, bool BIAS, bool SPLIT_OUT>
__global__ __launch_bounds__(256) void gemm1x1_k(const f16* __restrict__ inA,
                                                 const f16* __restrict__ w,
                                                 const float* __restrict__ bias,
                                                 float* __restrict__ outF,
                                                 f16* __restrict__ outH) {
  const int b = blockIdx.z, nb0 = blockIdx.y * 128, px0 = blockIdx.x * 128;
  const int CoutTot = gridDim.y * 128;
  const int tid = threadIdx.x, lane = tid & 63, wid = tid >> 6;
  const int wpx = px0 + wid * 32;
  const int kslot = (lane >> 4) * 8;

  f4_t acc[2][8];
#pragma unroll
  for (int mf = 0; mf < 2; mf++)
#pragma unroll
    for (int nf = 0; nf < 8; nf++) { f4_t z = {0.f, 0.f, 0.f, 0.f}; acc[mf][nf] = z; }

  size_t arow[2];
#pragma unroll
  for (int mf = 0; mf < 2; mf++)
    arow[mf] = ((size_t)b * NPIX + wpx + mf * 16 + (lane & 15)) * AS + AOFF;
  size_t wrow[8];
#pragma unroll
  for (int nf = 0; nf < 8; nf++)
    wrow[nf] = (size_t)(nb0 + nf * 16 + (lane & 15)) * 128;

#pragma unroll
  for (int ks = 0; ks < 4; ks++) {
    const int ko = ks * 32 + kslot;
    h8_t a[2], bw[8];
#pragma unroll
    for (int mf = 0; mf < 2; mf++) a[mf] = *(const h8_t*)(inA + arow[mf] + ko);
#pragma unroll
    for (int nf = 0; nf < 8; nf++) bw[nf] = *(const h8_t*)(w + wrow[nf] + ko);
#pragma unroll
    for (int mf = 0; mf < 2; mf++)
#pragma unroll
      for (int nf = 0; nf < 8; nf++)
        acc[mf][nf] = __builtin_amdgcn_mfma_f32_16x16x32_f16(a[mf], bw[nf], acc[mf][nf], 0, 0, 0);
  }

#pragma unroll
  for (int mf = 0; mf < 2; mf++) {
    const int pxq = wpx + mf * 16 + (lane >> 4) * 4;
#pragma unroll
    for (int nf = 0; nf < 8; nf++) {
      const int oc = nb0 + nf * 16 + (lane & 15);
      f4_t v = acc[mf][nf];
      if (BIAS) {
        float bv = bias[oc];
        v[0] += bv; v[1] += bv; v[2] += bv; v[3] += bv;
      }
      if (SPLIT_OUT) {
#pragma unroll
        for (int r = 0; r < 4; r++)
          outH[((size_t)b * NPIX + pxq + r) * 128 + oc] = (f16)v[r];
      } else {
        *(f4_t*)&outF[((size_t)b * CoutTot + oc) * NPIX + pxq] = v;
      }
    }
  }
}

// ---------------- fused modulated-deform-conv: NHWC f16 gather + grouped MFMA ----------------
__global__ __launch_bounds__(256) void dgemm_k(const f16* __restrict__ catf,
                                               const float* __restrict__ offs,
                                               const f16* __restrict__ wd,
                                               const float* __restrict__ dbias,
                                               f16* __restrict__ feat) {
  const int b = blockIdx.z, g = blockIdx.y;
  const int px0 = blockIdx.x * 128;
  const int tid = threadIdx.x;
  const int lane = tid & 63, wid = tid >> 6;
  const int chunk = lane >> 4;
  const int thalf = chunk >> 1;
  const int ic0 = (chunk & 1) * 8;
  const f16* yb = catf + (size_t)b * NPIX * C2;  // channels 0..127 of cat = y
  const float* ob = offs + (size_t)b * 18 * NPIX;

  int pm[2];
  float pyb[2], pxb2[2];
#pragma unroll
  for (int mf = 0; mf < 2; mf++) {
    pm[mf] = px0 + wid * 32 + mf * 16 + (lane & 15);
    pyb[mf] = (float)(pm[mf] >> 7);
    pxb2[mf] = (float)(pm[mf] & 127);
  }

  f4_t acc[2];
  { f4_t z = {0.f, 0.f, 0.f, 0.f}; acc[0] = z; acc[1] = z; }

  const size_t wbase = (size_t)(g * 16 + (lane & 15)) * 160;
#pragma unroll
  for (int s = 0; s < 5; s++) {
    h8_t ah[2];
#pragma unroll
    for (int mf = 0; mf < 2; mf++) {
      int t = 2 * s + thalf;
      int teff = t > 8 ? 8 : t;
      float dy = ob[(size_t)(2 * teff) * NPIX + pm[mf]];
      float dx = ob[(size_t)(2 * teff + 1) * NPIX + pm[mf]];
      float mk = sigmoidf_(ob[(size_t)teff * NPIX + pm[mf]]);
      int ky = teff / 3, kx = teff - 3 * ky;
      float pyf = pyb[mf] - 1.f + (float)ky + dy;
      float pxf = pxb2[mf] - 1.f + (float)kx + dx;
      float y0f = floorf(pyf), x0f = floorf(pxf);
      float fy = pyf - y0f, fx = pxf - x0f;
      int y0 = (int)y0f, x0 = (int)x0f;
      int y1 = y0 + 1, x1 = x0 + 1;
      float w00 = (1.f - fy) * (1.f - fx) * mk;
      float w01 = (1.f - fy) * fx * mk;
      float w10 = fy * (1.f - fx) * mk;
      float w11 = fy * fx * mk;
      bool vy0 = (y0 >= 0 && y0 < HH), vy1 = (y1 >= 0 && y1 < HH);
      bool vx0 = (x0 >= 0 && x0 < WW), vx1 = (x1 >= 0 && x1 < WW);
      if (!(vy0 && vx0)) w00 = 0.f;
      if (!(vy0 && vx1)) w01 = 0.f;
      if (!(vy1 && vx0)) w10 = 0.f;
      if (!(vy1 && vx1)) w11 = 0.f;
      int cy0 = min(max(y0, 0), HH - 1), cy1 = min(max(y1, 0), HH - 1);
      int cx0 = min(max(x0, 0), WW - 1), cx1 = min(max(x1, 0), WW - 1);
      const f16* p00 = yb + (size_t)(cy0 * WW + cx0) * C2 + g * 16 + ic0;
      const f16* p01 = yb + (size_t)(cy0 * WW + cx1) * C2 + g * 16 + ic0;
      const f16* p10 = yb + (size_t)(cy1 * WW + cx0) * C2 + g * 16 + ic0;
      const f16* p11 = yb + (size_t)(cy1 * WW + cx1) * C2 + g * 16 + ic0;
      h8_t a00 = *(const h8_t*)p00;
      h8_t a01 = *(const h8_t*)p01;
      h8_t a10 = *(const h8_t*)p10;
      h8_t a11 = *(const h8_t*)p11;
      h8_t hh;
#pragma unroll
      for (int j = 0; j < 8; j++) {
        float sv = w00 * (float)a00[j] + w01 * (float)a01[j] +
                   w10 * (float)a10[j] + w11 * (float)a11[j];
        hh[j] = (f16)sv;
      }
      ah[mf] = hh;
    }
    h8_t wv = *(const h8_t*)(wd + wbase + s * 32 + chunk * 8);
#pragma unroll
    for (int mf = 0; mf < 2; mf++)
      acc[mf] = __builtin_amdgcn_mfma_f32_16x16x32_f16(ah[mf], wv, acc[mf], 0, 0, 0);
  }

  const int oc = g * 16 + (lane & 15);
  const float bv = dbias[oc];
#pragma unroll
  for (int mf = 0; mf < 2; mf++) {
    const int pxq = px0 + wid * 32 + mf * 16 + (lane >> 4) * 4;
#pragma unroll
    for (int r = 0; r < 4; r++) {
      float v = fmaxf(acc[mf][r] + bv, 0.f);  // bias + relu (pw input)
      feat[((size_t)b * NPIX + pxq + r) * 128 + oc] = (f16)v;
    }
  }
}

// ---------------- depthwise 3x3, pad=1 (fp32 NCHW) ----------------
__global__ __launch_bounds__(256) void dw3x3_k(const float* __restrict__ in,
                                               const float* __restrict__ w,
                                               float* __restrict__ out, int Cc) {
  int idx = blockIdx.x * 256 + threadIdx.x;
  int total = NB * Cc * NPIX;
  if (idx >= total) return;
  int n = idx & (NPIX - 1);
  int bc = idx >> 14;
  int c = bc % Cc;
  int yy = n >> 7, xx = n & 127;
  const float* p = in + (size_t)bc * NPIX;
  const float* wc = w + c * 9;
  float acc = 0.f;
#pragma unroll
  for (int ky = 0; ky < 3; ky++) {
    int iy = yy + ky - 1;
    if (iy < 0 || iy >= HH) continue;
#pragma unroll
    for (int kx = 0; kx < 3; kx++) {
      int ix = xx + kx - 1;
      if (ix < 0 || ix >= WW) continue;
      acc += wc[ky * 3 + kx] * p[iy * WW + ix];
    }
  }
  out[idx] = acc;
}

// ---------------- zero small accumulators ----------------
__global__ void zero_k(float* p, int n) {
  int i = blockIdx.x * 256 + threadIdx.x;
  if (i < n) p[i] = 0.f;
}

// ---------------- attention: partial Gram + sumsq ----------------
__global__ __launch_bounds__(256) void attn_partial_k(const float* __restrict__ qbuf,
                                                      const float* __restrict__ kvbuf,
                                                      float* __restrict__ s_acc,
                                                      float* __restrict__ qss,
                                                      float* __restrict__ kss) {
  __shared__ float qs[16][129];
  __shared__ float ks[16][129];
  int b = blockIdx.z, h = blockIdx.y, seg = blockIdx.x;
  int tid = threadIdx.x;
  int dd = tid & 15, cc = tid >> 4;
  int n_start = seg * (NPIX / 16);
  float acc = 0.f, q2 = 0.f, k2s = 0.f;
  const float* qb = qbuf + ((size_t)b * C1 + h * DH) * NPIX;
  const float* kb = kvbuf + ((size_t)b * C2 + h * DH) * NPIX;
  for (int n0 = n_start; n0 < n_start + NPIX / 16; n0 += 128) {
    for (int e = tid; e < 16 * 128; e += 256) {
      int r = e >> 7, col = e & 127;
      qs[r][col] = qb[(size_t)r * NPIX + n0 + col];
      ks[r][col] = kb[(size_t)r * NPIX + n0 + col];
    }
    __syncthreads();
#pragma unroll 8
    for (int j = 0; j < 128; j++) {
      float qv = qs[cc][j], kv = ks[dd][j];
      acc += qv * kv;
      q2 += qv * qv;
      k2s += kv * kv;
    }
    __syncthreads();
  }
  int bh = b * NHEADS + h;
  atomicAdd(&s_acc[((size_t)bh * 16 + cc) * 16 + dd], acc);
  if (dd == 0) atomicAdd(&qss[bh * 16 + cc], q2);
  if (cc == 0) atomicAdd(&kss[bh * 16 + dd], k2s);
}

// ---------------- attention: normalize + softmax ----------------
__global__ __launch_bounds__(256) void attn_final_k(const float* __restrict__ s_acc,
                                                    const float* __restrict__ qss,
                                                    const float* __restrict__ kss,
                                                    const float* __restrict__ temp,
                                                    float* __restrict__ attn) {
  __shared__ float S[16][17];
  __shared__ float qn[16], kn[16];
  int bh = blockIdx.x;
  int h = bh % NHEADS;
  int tid = threadIdx.x;
  int dd = tid & 15, cc = tid >> 4;
  if (tid < 16) {
    qn[tid] = fmaxf(sqrtf(qss[bh * 16 + tid]), 1e-12f);
    kn[tid] = fmaxf(sqrtf(kss[bh * 16 + tid]), 1e-12f);
  }
  __syncthreads();
  float t = temp[h];
  float s = s_acc[((size_t)bh * 16 + cc) * 16 + dd] / (qn[cc] * kn[dd]) * t;
  S[cc][dd] = s;
  __syncthreads();
  float mx = -1e30f;
#pragma unroll
  for (int j = 0; j < 16; j++) mx = fmaxf(mx, S[cc][j]);
  float sum = 0.f;
#pragma unroll
  for (int j = 0; j < 16; j++) sum += expf(S[cc][j] - mx);
  attn[((size_t)bh * 16 + cc) * 16 + dd] = expf(s - mx) / sum;
}

// ---------------- attention: out = attn @ v -> NHWC f16 ----------------
__global__ __launch_bounds__(256) void attnout_k(const float* __restrict__ attn,
                                                 const float* __restrict__ kvbuf,
                                                 f16* __restrict__ outA) {
  __shared__ float s_a[16][16];
  int b = blockIdx.z, h = blockIdx.y;
  int tid = threadIdx.x;
  int bh = b * NHEADS + h;
  s_a[tid >> 4][tid & 15] = attn[((size_t)bh * 16 + (tid >> 4)) * 16 + (tid & 15)];
  __syncthreads();
  int n = blockIdx.x * 256 + tid;
  const float* vb = kvbuf + ((size_t)b * C2 + C1 + h * DH) * NPIX;
  float acc[16];
#pragma unroll
  for (int c = 0; c < 16; c++) acc[c] = 0.f;
#pragma unroll
  for (int d = 0; d < 16; d++) {
    float vv = vb[(size_t)d * NPIX + n];
#pragma unroll
    for (int c = 0; c < 16; c++) acc[c] += s_a[c][d] * vv;
  }
  h8_t o0, o1;
#pragma unroll
  for (int c = 0; c < 8; c++) {
    o0[c] = (f16)acc[c];
    o1[c] = (f16)acc[8 + c];
  }
  size_t base = ((size_t)b * NPIX + n) * 128 + h * 16;
  *(h8_t*)(outA + base) = o0;
  *(h8_t*)(outA + base + 8) = o1;
}

extern "C" void kernel_launch(void* const* d_in, const int* in_sizes, int n_in,
                              void* d_out, int out_size, void* d_ws, size_t ws_size,
                              hipStream_t stream) {
  const float* x = (const float*)d_in[0];
  const float* y = (const float*)d_in[1];
  const float* q_w = (const float*)d_in[2];
  const float* qd_w = (const float*)d_in[3];
  const float* kv_w = (const float*)d_in[4];
  const float* kvd_w = (const float*)d_in[5];
  const float* proj_w = (const float*)d_in[6];
  const float* temperature = (const float*)d_in[7];
  const float* k2_w = (const float*)d_in[8];
  const float* k3_w = (const float*)d_in[9];
  const float* k4_w = (const float*)d_in[10];
  const float* dcn_w = (const float*)d_in[11];
  const float* dcn_b = (const float*)d_in[12];
  const float* pw_w = (const float*)d_in[13];
  const float* pw_b = (const float*)d_in[14];
  float* out = (float*)d_out;

  char* ws = (char*)d_ws;
  size_t off = 0;
  auto alloc = [&](size_t nbytes) {
    char* p = ws + off;
    off += (nbytes + 255) & ~(size_t)255;
    return p;
  };
  f16* CATF = (f16*)alloc((size_t)NB * NPIX * C2 * 2);       // f16 cat (dgemm gathers + q input)
  u16* CBH = (u16*)alloc((size_t)NB * NPIX * C2 * 2);        // bf16-hi cat; later KV1 (fp32 spans CBH+CBL)
  u16* CBL = (u16*)alloc((size_t)NB * NPIX * C2 * 2);
  u16* PH = (u16*)alloc((size_t)NB * 4096 * C2 * 2);
  u16* PL = (u16*)alloc((size_t)NB * 4096 * C2 * 2);
  float* A2 = (float*)alloc((size_t)NB * 3844 * C2 * 4);     // NHWC [b][3844][256]
  u16* OUT3H = (u16*)alloc((size_t)NB * NPIX * C2 * 2);      // early: QT1 (fp32); late: KVb (fp32 spans both)
  u16* OUT3L = (u16*)alloc((size_t)NB * NPIX * C2 * 2);
  float* OFFS = (float*)alloc((size_t)NB * 18 * NPIX * 4);
  f16* FEAT = (f16*)alloc((size_t)NB * NPIX * C1 * 2);       // later: AO
  f16* AL = (f16*)alloc((size_t)NB * NPIX * C1 * 2);
  float* Qb = (float*)alloc((size_t)NB * C1 * NPIX * 4);
  u16* W2K2 = (u16*)alloc((size_t)72 * 256 * 64 * 2);
  u16* W2K3 = (u16*)alloc((size_t)72 * 256 * 64 * 2);
  u16* W2K4 = (u16*)alloc((size_t)72 * 32 * 64 * 2);
  f16* WD = (f16*)alloc((size_t)128 * 160 * 2);
  f16* WQ = (f16*)alloc((size_t)128 * 128 * 2);
  f16* WPW = (f16*)alloc((size_t)128 * 128 * 2);
  f16* WKV = (f16*)alloc((size_t)256 * 128 * 2);
  f16* WPJ = (f16*)alloc((size_t)128 * 128 * 2);
  float* SACC = (float*)alloc((size_t)(NB * NHEADS * 256 + 512 + NB * NHEADS * 256) * 4);
  float* QSS = SACC + NB * NHEADS * 256;
  float* KSS = QSS + 256;
  float* ATTN = KSS + 256;

  // region reuse (lifetimes: QT1 dead before k3; CBH/CBL dead after k3;
  // OUT3 dead after k4; FEAT dead after pw)
  float* QT1 = (float*)OUT3H;   // q 1x1 out, fp32, 16.78MB
  float* KV1 = (float*)CBH;     // kv 1x1 out, fp32, spans CBH+CBL (33.55MB)
  float* KVb = (float*)OUT3H;   // kv dw out, fp32, spans OUT3H+OUT3L
  f16* AO = FEAT;               // attn out

  dim3 blk(256);

  // weight prep
  w1trans_k<<<dim3(64), blk, 0, stream>>>(q_w, WQ, 128 * 128);
  w1trans_k<<<dim3(64), blk, 0, stream>>>(pw_w, WPW, 128 * 128);
  w1trans_k<<<dim3(128), blk, 0, stream>>>(kv_w, WKV, 256 * 128);
  w1trans_k<<<dim3(64), blk, 0, stream>>>(proj_w, WPJ, 128 * 128);
  wdprep_k<<<dim3(80), blk, 0, stream>>>(dcn_w, WD);
  wtrans_k<<<dim3((9 * 256 * 256 + 255) / 256), blk, 0, stream>>>(k2_w, W2K2, 256, 256);
  wtrans_k<<<dim3((9 * 256 * 256 + 255) / 256), blk, 0, stream>>>(k3_w, W2K3, 256, 256);
  wtrans_k<<<dim3((9 * 256 * 32 + 255) / 256), blk, 0, stream>>>(k4_w, W2K4, 18, 32);

  // cat split: f16 (gathers/q) + bf16 hi/lo (conv head)
  splitcat_k<<<dim3(NPIX / 64, C2 / 64, NB), blk, 0, stream>>>(y, x, CATF, CBH, CBL);

  // q path: 1x1 MFMA on x-half of catf -> depthwise
  gemm1x1_k<C2, C1, false, false><<<dim3(NPIX / 128, 1, NB), blk, 0, stream>>>(
      CATF, WQ, nullptr, QT1, nullptr);
  dw3x3_k<<<dim3((NB * C1 * NPIX + 255) / 256), blk, 0, stream>>>(QT1, qd_w, Qb, C1);

  // offset head (bf16 hi/lo 3-product, R3-measured structure)
  avgpool_b_k<<<dim3((NB * 4096 * 32 + 255) / 256), blk, 0, stream>>>(CBH, CBL, PH, PL);
  convmfma_k<128, 62, 62, 64, 64, 0, 256, 256, false, true>
      <<<dim3(31, 2, NB), blk, 0, stream>>>(PH, PL, W2K2, nullptr, nullptr, nullptr, A2, nullptr, nullptr);
  convmfma_k<128, 128, 128, 128, 128, 1, 256, 256, true, false>
      <<<dim3(128, 2, NB), blk, 0, stream>>>(CBH, CBL, W2K3, y, x, A2, nullptr, OUT3H, OUT3L);
  convmfma_k<32, 128, 128, 128, 128, 1, 18, 32, false, false>
      <<<dim3(128, 1, NB), blk, 0, stream>>>(OUT3H, OUT3L, W2K4, nullptr, nullptr, nullptr, OFFS, nullptr, nullptr);

  // deformable alignment (gathers from y-half of catf) + pw 1x1
  dgemm_k<<<dim3(NPIX / 128, NG, NB), blk, 0, stream>>>(CATF, OFFS, WD, dcn_b, FEAT);
  gemm1x1_k<C1, 0, true, true><<<dim3(NPIX / 128, 1, NB), blk, 0, stream>>>(
      FEAT, WPW, pw_b, nullptr, AL);

  // kv path
  gemm1x1_k<C1, 0, false, false><<<dim3(NPIX / 128, 2, NB), blk, 0, stream>>>(
      AL, WKV, nullptr, KV1, nullptr);
  dw3x3_k<<<dim3((NB * C2 * NPIX + 255) / 256), blk, 0, stream>>>(KV1, kvd_w, KVb, C2);

  // attention
  zero_k<<<dim3((4608 + 255) / 256), blk, 0, stream>>>(SACC, 4608);
  attn_partial_k<<<dim3(16, NHEADS, NB), blk, 0, stream>>>(Qb, KVb, SACC, QSS, KSS);
  attn_final_k<<<dim3(NB * NHEADS), blk, 0, stream>>>(SACC, QSS, KSS, temperature, ATTN);
  attnout_k<<<dim3(NPIX / 256, NHEADS, NB), blk, 0, stream>>>(ATTN, KVb, AO);
  gemm1x1_k<C1, 0, false, false><<<dim3(NPIX / 128, 1, NB), blk, 0, stream>>>(
      AO, WPJ, nullptr, out, nullptr);
}

// Round 7
// 514.581 us; speedup vs baseline: 1.4591x; 1.0178x over previous
//
#include <hip/hip_runtime.h>
#include <math.h>

#define NB 2
#define C1 128
#define C2 256
#define HH 128
#define WW 128
#define NPIX (HH*WW)
#define NHEADS 8
#define DH 16
#define NG 8

typedef unsigned short u16;
typedef _Float16 f16;
typedef __attribute__((ext_vector_type(8))) _Float16 h8_t;
typedef __attribute__((ext_vector_type(8))) short bf8_t;
typedef __attribute__((ext_vector_type(4))) float f4_t;

__device__ __forceinline__ float sigmoidf_(float v) { return 1.f / (1.f + expf(-v)); }
__device__ __forceinline__ u16 f2bf(float f) {
  unsigned u = __float_as_uint(f);
  return (u16)((u + 0x7FFFu + ((u >> 16) & 1u)) >> 16);
}
__device__ __forceinline__ float bf2f(u16 h) { return __uint_as_float(((unsigned)h) << 16); }

// ---------------- NCHW fp32 (y|x) -> NHWC: f16 cat + bf16 hi/lo cat ----------------
__global__ __launch_bounds__(256) void splitcat_k(const float* __restrict__ y,
                                                  const float* __restrict__ x,
                                                  f16* __restrict__ catf,
                                                  u16* __restrict__ cbh,
                                                  u16* __restrict__ cbl) {
  __shared__ float tile[64][65];
  int b = blockIdx.z, c0 = blockIdx.y * 64, p0 = blockIdx.x * 64;
  int tid = threadIdx.x;
  const float* src = (c0 < 128) ? y : x;
  int cc0 = c0 & 127;
  for (int e = tid; e < 4096; e += 256) {
    int c = e >> 6, p = e & 63;
    tile[c][p] = src[((size_t)b * C1 + cc0 + c) * NPIX + p0 + p];
  }
  __syncthreads();
  for (int e = tid; e < 4096; e += 256) {
    int p = e >> 6, c = e & 63;
    float v = tile[c][p];
    size_t o = ((size_t)b * NPIX + p0 + p) * C2 + c0 + c;
    catf[o] = (f16)v;
    u16 h = f2bf(v);
    cbh[o] = h;
    cbl[o] = f2bf(v - bf2f(h));
  }
}

// ---------------- avgpool2 on bf16-pair cat -> PH/PL [b][4096][256] ----------------
__global__ __launch_bounds__(256) void avgpool_b_k(const u16* __restrict__ cbh,
                                                   const u16* __restrict__ cbl,
                                                   u16* __restrict__ ph,
                                                   u16* __restrict__ pl) {
  int idx = blockIdx.x * 256 + threadIdx.x;
  if (idx >= NB * 4096 * 32) return;
  int c8 = idx & 31;
  int p = (idx >> 5) & 4095;
  int b = idx >> 17;
  int yo = p >> 6, xo = p & 63;
  size_t base = ((size_t)b * NPIX + (yo * 2) * WW + xo * 2) * C2 + c8 * 8;
  const size_t d01 = C2, d10 = (size_t)WW * C2, d11 = (size_t)WW * C2 + C2;
  bf8_t h00 = *(const bf8_t*)(cbh + base), l00 = *(const bf8_t*)(cbl + base);
  bf8_t h01 = *(const bf8_t*)(cbh + base + d01), l01 = *(const bf8_t*)(cbl + base + d01);
  bf8_t h10 = *(const bf8_t*)(cbh + base + d10), l10 = *(const bf8_t*)(cbl + base + d10);
  bf8_t h11 = *(const bf8_t*)(cbh + base + d11), l11 = *(const bf8_t*)(cbl + base + d11);
  bf8_t oh, ol;
#pragma unroll
  for (int j = 0; j < 8; j++) {
    float v00 = bf2f((u16)h00[j]) + bf2f((u16)l00[j]);
    float v01 = bf2f((u16)h01[j]) + bf2f((u16)l01[j]);
    float v10 = bf2f((u16)h10[j]) + bf2f((u16)l10[j]);
    float v11 = bf2f((u16)h11[j]) + bf2f((u16)l11[j]);
    float v = 0.25f * (v00 + v01 + v10 + v11);
    u16 h = f2bf(v);
    oh[j] = (short)h;
    ol[j] = (short)f2bf(v - bf2f(h));
  }
  size_t o = ((size_t)b * 4096 + p) * C2 + c8 * 8;
  *(bf8_t*)(ph + o) = oh;
  *(bf8_t*)(pl + o) = ol;
}

// ---------------- fused weight prep (all weights, one launch) ----------------
__device__ __forceinline__ void wtrans_body(const float* __restrict__ w, u16* __restrict__ w2,
                                            int OC, int OCR, int idx) {
  int t = idx / (256 * OCR);
  int rem = idx - t * 256 * OCR;
  int ic = rem / OCR;
  int oc = rem - ic * OCR;
  float v = (oc < OC) ? w[((size_t)oc * 256 + ic) * 9 + t] : 0.f;
  u16 h = f2bf(v);
  u16 l = f2bf(v - bf2f(h));
  size_t row = (size_t)(t * 8 + (ic >> 5)) * OCR + oc;
  w2[row * 64 + (ic & 31)] = h;
  w2[row * 64 + 32 + (ic & 31)] = l;
}

__global__ __launch_bounds__(256) void wprep_all_k(
    const float* __restrict__ q_w, const float* __restrict__ pw_w,
    const float* __restrict__ kv_w, const float* __restrict__ proj_w,
    const float* __restrict__ dcn_w, const float* __restrict__ k2_w,
    const float* __restrict__ k3_w, const float* __restrict__ k4_w,
    f16* __restrict__ WQ, f16* __restrict__ WPW, f16* __restrict__ WKV,
    f16* __restrict__ WPJ, f16* __restrict__ WD,
    u16* __restrict__ W2K2, u16* __restrict__ W2K3, u16* __restrict__ W2K4) {
  int idx = blockIdx.x * 256 + threadIdx.x;
  if (idx < 16384) { WQ[idx] = (f16)q_w[idx]; return; }
  idx -= 16384;
  if (idx < 16384) { WPW[idx] = (f16)pw_w[idx]; return; }
  idx -= 16384;
  if (idx < 32768) { WKV[idx] = (f16)kv_w[idx]; return; }
  idx -= 32768;
  if (idx < 16384) { WPJ[idx] = (f16)proj_w[idx]; return; }
  idx -= 16384;
  if (idx < 20480) {
    int oc = idx / 160, k = idx - oc * 160;
    int t = k >> 4, ic = k & 15;
    WD[idx] = (t < 9) ? (f16)dcn_w[((size_t)oc * 16 + ic) * 9 + t] : (f16)0.f;
    return;
  }
  idx -= 20480;
  if (idx < 589824) { wtrans_body(k2_w, W2K2, 256, 256, idx); return; }
  idx -= 589824;
  if (idx < 589824) { wtrans_body(k3_w, W2K3, 256, 256, idx); return; }
  idx -= 589824;
  if (idx < 73728) { wtrans_body(k4_w, W2K4, 18, 32, idx); }
}

// ---------------- implicit-GEMM 3x3 conv, bf16 hi/lo 3-product, LDS dbuf 1-barrier ----------------
// Block: 128 px x OCB oc, 4 waves. K = 9 taps x 256 ic (BK=32). LDS rows [32hi|32lo], XOR swizzle.
template<int OCB, int WO, int HO, int WI, int HI, int PAD, int OCTOT, int OCR, bool GATE, bool OUTF_NHWC>
__global__ __launch_bounds__(256) void convmfma_k(
    const u16* __restrict__ inH, const u16* __restrict__ inL,
    const u16* __restrict__ w2,
    const float* __restrict__ gy, const float* __restrict__ gx,
    const float* __restrict__ gB,
    float* __restrict__ outF, u16* __restrict__ outH, u16* __restrict__ outL) {
  constexpr int CIN = 256;
  constexpr int MF = (OCB == 128) ? 4 : 2;
  constexpr int NF = (OCB == 128) ? 4 : 2;
  __shared__ u16 lds_a[2][128 * 64];
  __shared__ u16 lds_w[2][OCB * 64];
  const int b = blockIdx.z;
  const int oc0 = blockIdx.y * OCB;
  const int px0 = blockIdx.x * 128;
  const int tid = threadIdx.x;
  const int lane = tid & 63, wid = tid >> 6;
  const int wpx = (OCB == 128) ? ((wid >> 1) * 64) : (wid * 32);
  const int woc = (OCB == 128) ? ((wid & 1) * 64) : 0;

  const int spx = tid >> 1;
  const int shalf = tid & 1;
  const int opx = px0 + spx;
  const int py = opx / WO, pxx = opx % WO;
  const bool prow_ok = (opx < HO * WO);
  const int ar7 = spx & 7;
  const int awo0 = spx * 128 + (((shalf * 2 + 0) ^ ar7) << 4);
  const int awo1 = spx * 128 + (((shalf * 2 + 1) ^ ar7) << 4);
  const int awo2 = spx * 128 + (((shalf * 2 + 4) ^ ar7) << 4);
  const int awo3 = spx * 128 + (((shalf * 2 + 5) ^ ar7) << 4);
  const bool wact = (OCB == 128) ? true : (tid < OCB * 2);
  const int wrow = tid >> 1, whalf = tid & 1;
  int wwo[4];
#pragma unroll
  for (int j = 0; j < 4; j++) wwo[j] = wrow * 128 + (((whalf * 4 + j) ^ (wrow & 7)) << 4);

  int aoh[MF], aol[MF], woh[NF], wol[NF];
#pragma unroll
  for (int mf = 0; mf < MF; mf++) {
    int r = wpx + mf * 16 + (lane & 15);
    int s = lane >> 4;
    aoh[mf] = r * 128 + ((s ^ (r & 7)) << 4);
    aol[mf] = r * 128 + (((s + 4) ^ (r & 7)) << 4);
  }
#pragma unroll
  for (int nf = 0; nf < NF; nf++) {
    int r = woc + nf * 16 + (lane & 15);
    int s = lane >> 4;
    woh[nf] = r * 128 + ((s ^ (r & 7)) << 4);
    wol[nf] = r * 128 + (((s + 4) ^ (r & 7)) << 4);
  }

  f4_t acc[MF][NF];
#pragma unroll
  for (int mf = 0; mf < MF; mf++)
#pragma unroll
    for (int nf = 0; nf < NF; nf++) { f4_t z = {0.f, 0.f, 0.f, 0.f}; acc[mf][nf] = z; }

  const size_t inb = (size_t)b * (HI * WI) * CIN;
  const size_t wg0 = (size_t)(oc0 + wrow) * 64 + (size_t)whalf * 32;
  uint4 rah0, rah1, ral0, ral1, rwv0, rwv1, rwv2, rwv3;

  auto load_gc = [&](int gc) {
    const int t = gc >> 3, c = gc & 7;
    const int iy = py + (t / 3) - PAD;
    const int ix = pxx + (t % 3) - PAD;
    const bool val = prow_ok && iy >= 0 && iy < HI && ix >= 0 && ix < WI;
    uint4 z = {0, 0, 0, 0};
    rah0 = z; rah1 = z; ral0 = z; ral1 = z;
    if (val) {
      size_t a0 = inb + (size_t)(iy * WI + ix) * CIN + c * 32 + shalf * 16;
      const uint4* ph = (const uint4*)(inH + a0);
      const uint4* pl = (const uint4*)(inL + a0);
      rah0 = ph[0]; rah1 = ph[1]; ral0 = pl[0]; ral1 = pl[1];
    }
    if (wact) {
      const uint4* q = (const uint4*)(w2 + (size_t)gc * OCR * 64 + wg0);
      rwv0 = q[0]; rwv1 = q[1]; rwv2 = q[2]; rwv3 = q[3];
    }
  };
  auto store_gc = [&](int nb) {
    char* la = (char*)lds_a[nb];
    char* lw = (char*)lds_w[nb];
    *(uint4*)(la + awo0) = rah0;
    *(uint4*)(la + awo1) = rah1;
    *(uint4*)(la + awo2) = ral0;
    *(uint4*)(la + awo3) = ral1;
    if (wact) {
      *(uint4*)(lw + wwo[0]) = rwv0;
      *(uint4*)(lw + wwo[1]) = rwv1;
      *(uint4*)(lw + wwo[2]) = rwv2;
      *(uint4*)(lw + wwo[3]) = rwv3;
    }
  };

  load_gc(0);
  store_gc(0);
  __syncthreads();
  for (int gc = 0; gc < 72; ++gc) {
    const int cb = gc & 1;
    if (gc < 71) load_gc(gc + 1);  // issue next-chunk global loads; latency hides under MFMA
    const char* la = (const char*)lds_a[cb];
    const char* lw = (const char*)lds_w[cb];
    bf8_t ah[MF], al[MF], wh[NF], wl[NF];
#pragma unroll
    for (int mf = 0; mf < MF; mf++) {
      ah[mf] = *(const bf8_t*)(la + aoh[mf]);
      al[mf] = *(const bf8_t*)(la + aol[mf]);
    }
#pragma unroll
    for (int nf = 0; nf < NF; nf++) {
      wh[nf] = *(const bf8_t*)(lw + woh[nf]);
      wl[nf] = *(const bf8_t*)(lw + wol[nf]);
    }
#pragma unroll
    for (int mf = 0; mf < MF; mf++)
#pragma unroll
      for (int nf = 0; nf < NF; nf++) {
        acc[mf][nf] = __builtin_amdgcn_mfma_f32_16x16x32_bf16(ah[mf], wh[nf], acc[mf][nf], 0, 0, 0);
        acc[mf][nf] = __builtin_amdgcn_mfma_f32_16x16x32_bf16(al[mf], wh[nf], acc[mf][nf], 0, 0, 0);
        acc[mf][nf] = __builtin_amdgcn_mfma_f32_16x16x32_bf16(ah[mf], wl[nf], acc[mf][nf], 0, 0, 0);
      }
    if (gc < 71) store_gc(cb ^ 1);  // vmcnt wait lands here, after the MFMA block
    __syncthreads();
  }

  // epilogue: D row=(lane>>4)*4+r = px, col=lane&15 = oc  [m89-verified]
#pragma unroll
  for (int mf = 0; mf < MF; mf++) {
    const int pxb = px0 + wpx + mf * 16 + ((lane >> 4) << 2);
#pragma unroll
    for (int nf = 0; nf < NF; nf++) {
      const int oc = oc0 + woc + nf * 16 + (lane & 15);
      if (GATE) {
        const float* gp = (oc < 128) ? gy : gx;
        const size_t gbase = ((size_t)b * C1 + (oc & 127)) * NPIX;
#pragma unroll
        for (int r = 0; r < 4; r++) {
          const int px = pxb + r;
          const int pyy = px >> 7, px2 = px & 127;
          const int iiy = (pyy * 62) >> 7, iix = (px2 * 62) >> 7;
          float gv = gp[gbase + px] + gB[((size_t)b * 3844 + iiy * 62 + iix) * 256 + oc];
          float v = acc[mf][nf][r] * sigmoidf_(gv);
          u16 h = f2bf(v);
          size_t o = ((size_t)b * NPIX + px) * C2 + oc;
          outH[o] = h;
          outL[o] = f2bf(v - bf2f(h));
        }
      } else if (OUTF_NHWC) {
        if (oc < OCTOT) {
#pragma unroll
          for (int r = 0; r < 4; r++) {
            const int px = pxb + r;
            if (px < HO * WO)
              outF[((size_t)b * (HO * WO) + px) * OCTOT + oc] = acc[mf][nf][r];
          }
        }
      } else {
        if (pxb < HO * WO && oc < OCTOT)
          *(f4_t*)&outF[((size_t)b * OCTOT + oc) * (HO * WO) + pxb] = acc[mf][nf];
      }
    }
  }
}

// ---------------- 1x1 conv as fp16 MFMA GEMM, direct-global fragments ----------------
template<int AS, int AOFF, bool BIAS, bool SPLIT_OUT>
__global__ __launch_bounds__(256) void gemm1x1_k(const f16* __restrict__ inA,
                                                 const f16* __restrict__ w,
                                                 const float* __restrict__ bias,
                                                 float* __restrict__ outF,
                                                 f16* __restrict__ outH) {
  const int b = blockIdx.z, nb0 = blockIdx.y * 128, px0 = blockIdx.x * 128;
  const int CoutTot = gridDim.y * 128;
  const int tid = threadIdx.x, lane = tid & 63, wid = tid >> 6;
  const int wpx = px0 + wid * 32;
  const int kslot = (lane >> 4) * 8;

  f4_t acc[2][8];
#pragma unroll
  for (int mf = 0; mf < 2; mf++)
#pragma unroll
    for (int nf = 0; nf < 8; nf++) { f4_t z = {0.f, 0.f, 0.f, 0.f}; acc[mf][nf] = z; }

  size_t arow[2];
#pragma unroll
  for (int mf = 0; mf < 2; mf++)
    arow[mf] = ((size_t)b * NPIX + wpx + mf * 16 + (lane & 15)) * AS + AOFF;
  size_t wrow[8];
#pragma unroll
  for (int nf = 0; nf < 8; nf++)
    wrow[nf] = (size_t)(nb0 + nf * 16 + (lane & 15)) * 128;

#pragma unroll
  for (int ks = 0; ks < 4; ks++) {
    const int ko = ks * 32 + kslot;
    h8_t a[2], bw[8];
#pragma unroll
    for (int mf = 0; mf < 2; mf++) a[mf] = *(const h8_t*)(inA + arow[mf] + ko);
#pragma unroll
    for (int nf = 0; nf < 8; nf++) bw[nf] = *(const h8_t*)(w + wrow[nf] + ko);
#pragma unroll
    for (int mf = 0; mf < 2; mf++)
#pragma unroll
      for (int nf = 0; nf < 8; nf++)
        acc[mf][nf] = __builtin_amdgcn_mfma_f32_16x16x32_f16(a[mf], bw[nf], acc[mf][nf], 0, 0, 0);
  }

#pragma unroll
  for (int mf = 0; mf < 2; mf++) {
    const int pxq = wpx + mf * 16 + (lane >> 4) * 4;
#pragma unroll
    for (int nf = 0; nf < 8; nf++) {
      const int oc = nb0 + nf * 16 + (lane & 15);
      f4_t v = acc[mf][nf];
      if (BIAS) {
        float bv = bias[oc];
        v[0] += bv; v[1] += bv; v[2] += bv; v[3] += bv;
      }
      if (SPLIT_OUT) {
#pragma unroll
        for (int r = 0; r < 4; r++)
          outH[((size_t)b * NPIX + pxq + r) * 128 + oc] = (f16)v[r];
      } else {
        *(f4_t*)&outF[((size_t)b * CoutTot + oc) * NPIX + pxq] = v;
      }
    }
  }
}

// ---------------- fused modulated-deform-conv: NHWC f16 gather + grouped MFMA ----------------
__global__ __launch_bounds__(256) void dgemm_k(const f16* __restrict__ catf,
                                               const float* __restrict__ offs,
                                               const f16* __restrict__ wd,
                                               const float* __restrict__ dbias,
                                               f16* __restrict__ feat) {
  const int b = blockIdx.z, g = blockIdx.y;
  const int px0 = blockIdx.x * 128;
  const int tid = threadIdx.x;
  const int lane = tid & 63, wid = tid >> 6;
  const int chunk = lane >> 4;
  const int thalf = chunk >> 1;
  const int ic0 = (chunk & 1) * 8;
  const f16* yb = catf + (size_t)b * NPIX * C2;  // channels 0..127 of cat = y
  const float* ob = offs + (size_t)b * 18 * NPIX;

  int pm[2];
  float pyb[2], pxb2[2];
#pragma unroll
  for (int mf = 0; mf < 2; mf++) {
    pm[mf] = px0 + wid * 32 + mf * 16 + (lane & 15);
    pyb[mf] = (float)(pm[mf] >> 7);
    pxb2[mf] = (float)(pm[mf] & 127);
  }

  f4_t acc[2];
  { f4_t z = {0.f, 0.f, 0.f, 0.f}; acc[0] = z; acc[1] = z; }

  const size_t wbase = (size_t)(g * 16 + (lane & 15)) * 160;
#pragma unroll
  for (int s = 0; s < 5; s++) {
    h8_t ah[2];
#pragma unroll
    for (int mf = 0; mf < 2; mf++) {
      int t = 2 * s + thalf;
      int teff = t > 8 ? 8 : t;
      float dy = ob[(size_t)(2 * teff) * NPIX + pm[mf]];
      float dx = ob[(size_t)(2 * teff + 1) * NPIX + pm[mf]];
      float mk = sigmoidf_(ob[(size_t)teff * NPIX + pm[mf]]);
      int ky = teff / 3, kx = teff - 3 * ky;
      float pyf = pyb[mf] - 1.f + (float)ky + dy;
      float pxf = pxb2[mf] - 1.f + (float)kx + dx;
      float y0f = floorf(pyf), x0f = floorf(pxf);
      float fy = pyf - y0f, fx = pxf - x0f;
      int y0 = (int)y0f, x0 = (int)x0f;
      int y1 = y0 + 1, x1 = x0 + 1;
      float w00 = (1.f - fy) * (1.f - fx) * mk;
      float w01 = (1.f - fy) * fx * mk;
      float w10 = fy * (1.f - fx) * mk;
      float w11 = fy * fx * mk;
      bool vy0 = (y0 >= 0 && y0 < HH), vy1 = (y1 >= 0 && y1 < HH);
      bool vx0 = (x0 >= 0 && x0 < WW), vx1 = (x1 >= 0 && x1 < WW);
      if (!(vy0 && vx0)) w00 = 0.f;
      if (!(vy0 && vx1)) w01 = 0.f;
      if (!(vy1 && vx0)) w10 = 0.f;
      if (!(vy1 && vx1)) w11 = 0.f;
      int cy0 = min(max(y0, 0), HH - 1), cy1 = min(max(y1, 0), HH - 1);
      int cx0 = min(max(x0, 0), WW - 1), cx1 = min(max(x1, 0), WW - 1);
      const f16* p00 = yb + (size_t)(cy0 * WW + cx0) * C2 + g * 16 + ic0;
      const f16* p01 = yb + (size_t)(cy0 * WW + cx1) * C2 + g * 16 + ic0;
      const f16* p10 = yb + (size_t)(cy1 * WW + cx0) * C2 + g * 16 + ic0;
      const f16* p11 = yb + (size_t)(cy1 * WW + cx1) * C2 + g * 16 + ic0;
      h8_t a00 = *(const h8_t*)p00;
      h8_t a01 = *(const h8_t*)p01;
      h8_t a10 = *(const h8_t*)p10;
      h8_t a11 = *(const h8_t*)p11;
      h8_t hh;
#pragma unroll
      for (int j = 0; j < 8; j++) {
        float sv = w00 * (float)a00[j] + w01 * (float)a01[j] +
                   w10 * (float)a10[j] + w11 * (float)a11[j];
        hh[j] = (f16)sv;
      }
      ah[mf] = hh;
    }
    h8_t wv = *(const h8_t*)(wd + wbase + s * 32 + chunk * 8);
#pragma unroll
    for (int mf = 0; mf < 2; mf++)
      acc[mf] = __builtin_amdgcn_mfma_f32_16x16x32_f16(ah[mf], wv, acc[mf], 0, 0, 0);
  }

  const int oc = g * 16 + (lane & 15);
  const float bv = dbias[oc];
#pragma unroll
  for (int mf = 0; mf < 2; mf++) {
    const int pxq = px0 + wid * 32 + mf * 16 + (lane >> 4) * 4;
#pragma unroll
    for (int r = 0; r < 4; r++) {
      float v = fmaxf(acc[mf][r] + bv, 0.f);  // bias + relu (pw input)
      feat[((size_t)b * NPIX + pxq + r) * 128 + oc] = (f16)v;
    }
  }
}

// ---------------- depthwise 3x3, pad=1 (fp32 NCHW) ----------------
__global__ __launch_bounds__(256) void dw3x3_k(const float* __restrict__ in,
                                               const float* __restrict__ w,
                                               float* __restrict__ out, int Cc) {
  int idx = blockIdx.x * 256 + threadIdx.x;
  int total = NB * Cc * NPIX;
  if (idx >= total) return;
  int n = idx & (NPIX - 1);
  int bc = idx >> 14;
  int c = bc % Cc;
  int yy = n >> 7, xx = n & 127;
  const float* p = in + (size_t)bc * NPIX;
  const float* wc = w + c * 9;
  float acc = 0.f;
#pragma unroll
  for (int ky = 0; ky < 3; ky++) {
    int iy = yy + ky - 1;
    if (iy < 0 || iy >= HH) continue;
#pragma unroll
    for (int kx = 0; kx < 3; kx++) {
      int ix = xx + kx - 1;
      if (ix < 0 || ix >= WW) continue;
      acc += wc[ky * 3 + kx] * p[iy * WW + ix];
    }
  }
  out[idx] = acc;
}

// ---------------- zero small accumulators ----------------
__global__ void zero_k(float* p, int n) {
  int i = blockIdx.x * 256 + threadIdx.x;
  if (i < n) p[i] = 0.f;
}

// ---------------- attention: partial Gram + sumsq ----------------
__global__ __launch_bounds__(256) void attn_partial_k(const float* __restrict__ qbuf,
                                                      const float* __restrict__ kvbuf,
                                                      float* __restrict__ s_acc,
                                                      float* __restrict__ qss,
                                                      float* __restrict__ kss) {
  __shared__ float qs[16][129];
  __shared__ float ks[16][129];
  int b = blockIdx.z, h = blockIdx.y, seg = blockIdx.x;
  int tid = threadIdx.x;
  int dd = tid & 15, cc = tid >> 4;
  int n_start = seg * (NPIX / 16);
  float acc = 0.f, q2 = 0.f, k2s = 0.f;
  const float* qb = qbuf + ((size_t)b * C1 + h * DH) * NPIX;
  const float* kb = kvbuf + ((size_t)b * C2 + h * DH) * NPIX;
  for (int n0 = n_start; n0 < n_start + NPIX / 16; n0 += 128) {
    for (int e = tid; e < 16 * 128; e += 256) {
      int r = e >> 7, col = e & 127;
      qs[r][col] = qb[(size_t)r * NPIX + n0 + col];
      ks[r][col] = kb[(size_t)r * NPIX + n0 + col];
    }
    __syncthreads();
#pragma unroll 8
    for (int j = 0; j < 128; j++) {
      float qv = qs[cc][j], kv = ks[dd][j];
      acc += qv * kv;
      q2 += qv * qv;
      k2s += kv * kv;
    }
    __syncthreads();
  }
  int bh = b * NHEADS + h;
  atomicAdd(&s_acc[((size_t)bh * 16 + cc) * 16 + dd], acc);
  if (dd == 0) atomicAdd(&qss[bh * 16 + cc], q2);
  if (cc == 0) atomicAdd(&kss[bh * 16 + dd], k2s);
}

// ---------------- attention: normalize + softmax ----------------
__global__ __launch_bounds__(256) void attn_final_k(const float* __restrict__ s_acc,
                                                    const float* __restrict__ qss,
                                                    const float* __restrict__ kss,
                                                    const float* __restrict__ temp,
                                                    float* __restrict__ attn) {
  __shared__ float S[16][17];
  __shared__ float qn[16], kn[16];
  int bh = blockIdx.x;
  int h = bh % NHEADS;
  int tid = threadIdx.x;
  int dd = tid & 15, cc = tid >> 4;
  if (tid < 16) {
    qn[tid] = fmaxf(sqrtf(qss[bh * 16 + tid]), 1e-12f);
    kn[tid] = fmaxf(sqrtf(kss[bh * 16 + tid]), 1e-12f);
  }
  __syncthreads();
  float t = temp[h];
  float s = s_acc[((size_t)bh * 16 + cc) * 16 + dd] / (qn[cc] * kn[dd]) * t;
  S[cc][dd] = s;
  __syncthreads();
  float mx = -1e30f;
#pragma unroll
  for (int j = 0; j < 16; j++) mx = fmaxf(mx, S[cc][j]);
  float sum = 0.f;
#pragma unroll
  for (int j = 0; j < 16; j++) sum += expf(S[cc][j] - mx);
  attn[((size_t)bh * 16 + cc) * 16 + dd] = expf(s - mx) / sum;
}

// ---------------- attention: out = attn @ v -> NHWC f16 ----------------
__global__ __launch_bounds__(256) void attnout_k(const float* __restrict__ attn,
                                                 const float* __restrict__ kvbuf,
                                                 f16* __restrict__ outA) {
  __shared__ float s_a[16][16];
  int b = blockIdx.z, h = blockIdx.y;
  int tid = threadIdx.x;
  int bh = b * NHEADS + h;
  s_a[tid >> 4][tid & 15] = attn[((size_t)bh * 16 + (tid >> 4)) * 16 + (tid & 15)];
  __syncthreads();
  int n = blockIdx.x * 256 + tid;
  const float* vb = kvbuf + ((size_t)b * C2 + C1 + h * DH) * NPIX;
  float acc[16];
#pragma unroll
  for (int c = 0; c < 16; c++) acc[c] = 0.f;
#pragma unroll
  for (int d = 0; d < 16; d++) {
    float vv = vb[(size_t)d * NPIX + n];
#pragma unroll
    for (int c = 0; c < 16; c++) acc[c] += s_a[c][d] * vv;
  }
  h8_t o0, o1;
#pragma unroll
  for (int c = 0; c < 8; c++) {
    o0[c] = (f16)acc[c];
    o1[c] = (f16)acc[8 + c];
  }
  size_t base = ((size_t)b * NPIX + n) * 128 + h * 16;
  *(h8_t*)(outA + base) = o0;
  *(h8_t*)(outA + base + 8) = o1;
}

extern "C" void kernel_launch(void* const* d_in, const int* in_sizes, int n_in,
                              void* d_out, int out_size, void* d_ws, size_t ws_size,
                              hipStream_t stream) {
  const float* x = (const float*)d_in[0];
  const float* y = (const float*)d_in[1];
  const float* q_w = (const float*)d_in[2];
  const float* qd_w = (const float*)d_in[3];
  const float* kv_w = (const float*)d_in[4];
  const float* kvd_w = (const float*)d_in[5];
  const float* proj_w = (const float*)d_in[6];
  const float* temperature = (const float*)d_in[7];
  const float* k2_w = (const float*)d_in[8];
  const float* k3_w = (const float*)d_in[9];
  const float* k4_w = (const float*)d_in[10];
  const float* dcn_w = (const float*)d_in[11];
  const float* dcn_b = (const float*)d_in[12];
  const float* pw_w = (const float*)d_in[13];
  const float* pw_b = (const float*)d_in[14];
  float* out = (float*)d_out;

  char* ws = (char*)d_ws;
  size_t off = 0;
  auto alloc = [&](size_t nbytes) {
    char* p = ws + off;
    off += (nbytes + 255) & ~(size_t)255;
    return p;
  };
  f16* CATF = (f16*)alloc((size_t)NB * NPIX * C2 * 2);       // f16 cat (dgemm gathers + q input)
  u16* CBH = (u16*)alloc((size_t)NB * NPIX * C2 * 2);        // bf16-hi cat; later KV1 (fp32 spans CBH+CBL)
  u16* CBL = (u16*)alloc((size_t)NB * NPIX * C2 * 2);
  u16* PH = (u16*)alloc((size_t)NB * 4096 * C2 * 2);
  u16* PL = (u16*)alloc((size_t)NB * 4096 * C2 * 2);
  float* A2 = (float*)alloc((size_t)NB * 3844 * C2 * 4);     // NHWC [b][3844][256]
  u16* OUT3H = (u16*)alloc((size_t)NB * NPIX * C2 * 2);      // early: QT1 (fp32); late: KVb (fp32 spans both)
  u16* OUT3L = (u16*)alloc((size_t)NB * NPIX * C2 * 2);
  float* OFFS = (float*)alloc((size_t)NB * 18 * NPIX * 4);
  f16* FEAT = (f16*)alloc((size_t)NB * NPIX * C1 * 2);       // later: AO
  f16* AL = (f16*)alloc((size_t)NB * NPIX * C1 * 2);
  float* Qb = (float*)alloc((size_t)NB * C1 * NPIX * 4);
  u16* W2K2 = (u16*)alloc((size_t)72 * 256 * 64 * 2);
  u16* W2K3 = (u16*)alloc((size_t)72 * 256 * 64 * 2);
  u16* W2K4 = (u16*)alloc((size_t)72 * 32 * 64 * 2);
  f16* WD = (f16*)alloc((size_t)128 * 160 * 2);
  f16* WQ = (f16*)alloc((size_t)128 * 128 * 2);
  f16* WPW = (f16*)alloc((size_t)128 * 128 * 2);
  f16* WKV = (f16*)alloc((size_t)256 * 128 * 2);
  f16* WPJ = (f16*)alloc((size_t)128 * 128 * 2);
  float* SACC = (float*)alloc((size_t)(NB * NHEADS * 256 + 512 + NB * NHEADS * 256) * 4);
  float* QSS = SACC + NB * NHEADS * 256;
  float* KSS = QSS + 256;
  float* ATTN = KSS + 256;

  // region reuse (lifetimes: QT1 dead before k3; CBH/CBL dead after k3;
  // OUT3 dead after k4; FEAT dead after pw)
  float* QT1 = (float*)OUT3H;   // q 1x1 out, fp32, 16.78MB
  float* KV1 = (float*)CBH;     // kv 1x1 out, fp32, spans CBH+CBL (33.55MB)
  float* KVb = (float*)OUT3H;   // kv dw out, fp32, spans OUT3H+OUT3L
  f16* AO = FEAT;               // attn out

  dim3 blk(256);

  // fused weight prep (one launch)
  wprep_all_k<<<dim3(5296), blk, 0, stream>>>(q_w, pw_w, kv_w, proj_w, dcn_w, k2_w, k3_w, k4_w,
                                              WQ, WPW, WKV, WPJ, WD, W2K2, W2K3, W2K4);

  // cat split: f16 (gathers/q) + bf16 hi/lo (conv head)
  splitcat_k<<<dim3(NPIX / 64, C2 / 64, NB), blk, 0, stream>>>(y, x, CATF, CBH, CBL);

  // q path: 1x1 MFMA on x-half of catf -> depthwise
  gemm1x1_k<C2, C1, false, false><<<dim3(NPIX / 128, 1, NB), blk, 0, stream>>>(
      CATF, WQ, nullptr, QT1, nullptr);
  dw3x3_k<<<dim3((NB * C1 * NPIX + 255) / 256), blk, 0, stream>>>(QT1, qd_w, Qb, C1);

  // offset head (bf16 hi/lo 3-product, dbuf single-barrier loop)
  avgpool_b_k<<<dim3((NB * 4096 * 32 + 255) / 256), blk, 0, stream>>>(CBH, CBL, PH, PL);
  convmfma_k<32, 62, 62, 64, 64, 0, 256, 256, false, true>
      <<<dim3(31, 8, NB), blk, 0, stream>>>(PH, PL, W2K2, nullptr, nullptr, nullptr, A2, nullptr, nullptr);
  convmfma_k<128, 128, 128, 128, 128, 1, 256, 256, true, false>
      <<<dim3(128, 2, NB), blk, 0, stream>>>(CBH, CBL, W2K3, y, x, A2, nullptr, OUT3H, OUT3L);
  convmfma_k<32, 128, 128, 128, 128, 1, 18, 32, false, false>
      <<<dim3(128, 1, NB), blk, 0, stream>>>(OUT3H, OUT3L, W2K4, nullptr, nullptr, nullptr, OFFS, nullptr, nullptr);

  // deformable alignment (gathers from y-half of catf) + pw 1x1
  dgemm_k<<<dim3(NPIX / 128, NG, NB), blk, 0, stream>>>(CATF, OFFS, WD, dcn_b, FEAT);
  gemm1x1_k<C1, 0, true, true><<<dim3(NPIX / 128, 1, NB), blk, 0, stream>>>(
      FEAT, WPW, pw_b, nullptr, AL);

  // kv path
  gemm1x1_k<C1, 0, false, false><<<dim3(NPIX / 128, 2, NB), blk, 0, stream>>>(
      AL, WKV, nullptr, KV1, nullptr);
  dw3x3_k<<<dim3((NB * C2 * NPIX + 255) / 256), blk, 0, stream>>>(KV1, kvd_w, KVb, C2);

  // attention
  zero_k<<<dim3((4608 + 255) / 256), blk, 0, stream>>>(SACC, 4608);
  attn_partial_k<<<dim3(16, NHEADS, NB), blk, 0, stream>>>(Qb, KVb, SACC, QSS, KSS);
  attn_final_k<<<dim3(NB * NHEADS), blk, 0, stream>>>(SACC, QSS, KSS, temperature, ATTN);
  attnout_k<<<dim3(NPIX / 256, NHEADS, NB), blk, 0, stream>>>(ATTN, KVb, AO);
  gemm1x1_k<C1, 0, false, false><<<dim3(NPIX / 128, 1, NB), blk, 0, stream>>>(
      AO, WPJ, nullptr, out, nullptr);
}

// Round 8
// 467.568 us; speedup vs baseline: 1.6058x; 1.1005x over previous
//
#include <hip/hip_runtime.h>
#include <math.h>

#define NB 2
#define C1 128
#define C2 256
#define HH 128
#define WW 128
#define NPIX (HH*WW)
#define NHEADS 8
#define DH 16
#define NG 8

typedef unsigned short u16;
typedef _Float16 f16;
typedef __attribute__((ext_vector_type(8))) _Float16 h8_t;
typedef __attribute__((ext_vector_type(8))) short bf8_t;
typedef __attribute__((ext_vector_type(4))) float f4_t;

__device__ __forceinline__ float sigmoidf_(float v) { return 1.f / (1.f + expf(-v)); }
__device__ __forceinline__ u16 f2bf(float f) {
  unsigned u = __float_as_uint(f);
  return (u16)((u + 0x7FFFu + ((u >> 16) & 1u)) >> 16);
}
__device__ __forceinline__ float bf2f(u16 h) { return __uint_as_float(((unsigned)h) << 16); }

// ---------------- NCHW fp32 (y|x) -> NHWC: f16 cat + bf16 hi/lo cat ----------------
__global__ __launch_bounds__(256) void splitcat_k(const float* __restrict__ y,
                                                  const float* __restrict__ x,
                                                  f16* __restrict__ catf,
                                                  u16* __restrict__ cbh,
                                                  u16* __restrict__ cbl) {
  __shared__ float tile[64][65];
  int b = blockIdx.z, c0 = blockIdx.y * 64, p0 = blockIdx.x * 64;
  int tid = threadIdx.x;
  const float* src = (c0 < 128) ? y : x;
  int cc0 = c0 & 127;
  for (int e = tid; e < 4096; e += 256) {
    int c = e >> 6, p = e & 63;
    tile[c][p] = src[((size_t)b * C1 + cc0 + c) * NPIX + p0 + p];
  }
  __syncthreads();
  for (int e = tid; e < 4096; e += 256) {
    int p = e >> 6, c = e & 63;
    float v = tile[c][p];
    size_t o = ((size_t)b * NPIX + p0 + p) * C2 + c0 + c;
    catf[o] = (f16)v;
    u16 h = f2bf(v);
    cbh[o] = h;
    cbl[o] = f2bf(v - bf2f(h));
  }
}

// ---------------- avgpool2 on bf16-pair cat -> PH/PL [b][4096][256] ----------------
__global__ __launch_bounds__(256) void avgpool_b_k(const u16* __restrict__ cbh,
                                                   const u16* __restrict__ cbl,
                                                   u16* __restrict__ ph,
                                                   u16* __restrict__ pl) {
  int idx = blockIdx.x * 256 + threadIdx.x;
  if (idx >= NB * 4096 * 32) return;
  int c8 = idx & 31;
  int p = (idx >> 5) & 4095;
  int b = idx >> 17;
  int yo = p >> 6, xo = p & 63;
  size_t base = ((size_t)b * NPIX + (yo * 2) * WW + xo * 2) * C2 + c8 * 8;
  const size_t d01 = C2, d10 = (size_t)WW * C2, d11 = (size_t)WW * C2 + C2;
  bf8_t h00 = *(const bf8_t*)(cbh + base), l00 = *(const bf8_t*)(cbl + base);
  bf8_t h01 = *(const bf8_t*)(cbh + base + d01), l01 = *(const bf8_t*)(cbl + base + d01);
  bf8_t h10 = *(const bf8_t*)(cbh + base + d10), l10 = *(const bf8_t*)(cbl + base + d10);
  bf8_t h11 = *(const bf8_t*)(cbh + base + d11), l11 = *(const bf8_t*)(cbl + base + d11);
  bf8_t oh, ol;
#pragma unroll
  for (int j = 0; j < 8; j++) {
    float v00 = bf2f((u16)h00[j]) + bf2f((u16)l00[j]);
    float v01 = bf2f((u16)h01[j]) + bf2f((u16)l01[j]);
    float v10 = bf2f((u16)h10[j]) + bf2f((u16)l10[j]);
    float v11 = bf2f((u16)h11[j]) + bf2f((u16)l11[j]);
    float v = 0.25f * (v00 + v01 + v10 + v11);
    u16 h = f2bf(v);
    oh[j] = (short)h;
    ol[j] = (short)f2bf(v - bf2f(h));
  }
  size_t o = ((size_t)b * 4096 + p) * C2 + c8 * 8;
  *(bf8_t*)(ph + o) = oh;
  *(bf8_t*)(pl + o) = ol;
}

// ---------------- fused weight prep (all weights, one launch) ----------------
__device__ __forceinline__ void wtrans_body(const float* __restrict__ w, u16* __restrict__ w2,
                                            int OC, int OCR, int idx) {
  int t = idx / (256 * OCR);
  int rem = idx - t * 256 * OCR;
  int ic = rem / OCR;
  int oc = rem - ic * OCR;
  float v = (oc < OC) ? w[((size_t)oc * 256 + ic) * 9 + t] : 0.f;
  u16 h = f2bf(v);
  u16 l = f2bf(v - bf2f(h));
  size_t row = (size_t)(t * 8 + (ic >> 5)) * OCR + oc;
  w2[row * 64 + (ic & 31)] = h;
  w2[row * 64 + 32 + (ic & 31)] = l;
}

__global__ __launch_bounds__(256) void wprep_all_k(
    const float* __restrict__ q_w, const float* __restrict__ pw_w,
    const float* __restrict__ kv_w, const float* __restrict__ proj_w,
    const float* __restrict__ dcn_w, const float* __restrict__ k2_w,
    const float* __restrict__ k3_w, const float* __restrict__ k4_w,
    f16* __restrict__ WQ, f16* __restrict__ WPW, f16* __restrict__ WKV,
    f16* __restrict__ WPJ, f16* __restrict__ WD,
    u16* __restrict__ W2K2, u16* __restrict__ W2K3, u16* __restrict__ W2K4) {
  int idx = blockIdx.x * 256 + threadIdx.x;
  if (idx < 16384) { WQ[idx] = (f16)q_w[idx]; return; }
  idx -= 16384;
  if (idx < 16384) { WPW[idx] = (f16)pw_w[idx]; return; }
  idx -= 16384;
  if (idx < 32768) { WKV[idx] = (f16)kv_w[idx]; return; }
  idx -= 32768;
  if (idx < 16384) { WPJ[idx] = (f16)proj_w[idx]; return; }
  idx -= 16384;
  if (idx < 20480) {
    int oc = idx / 160, k = idx - oc * 160;
    int t = k >> 4, ic = k & 15;
    WD[idx] = (t < 9) ? (f16)dcn_w[((size_t)oc * 16 + ic) * 9 + t] : (f16)0.f;
    return;
  }
  idx -= 20480;
  if (idx < 589824) { wtrans_body(k2_w, W2K2, 256, 256, idx); return; }
  idx -= 589824;
  if (idx < 589824) { wtrans_body(k3_w, W2K3, 256, 256, idx); return; }
  idx -= 589824;
  if (idx < 73728) { wtrans_body(k4_w, W2K4, 18, 32, idx); }
}

// ---------------- implicit-GEMM 3x3 conv, bf16 hi/lo 3-product, dbuf, split-K ----------------
// Block: 128 px x OCB oc, 4 waves. gridDim.y = NPAN * SPLITK (oc-panel minor, kz major).
template<int OCB, int NPAN, int SPLITK, int WO, int HO, int WI, int HI, int PAD,
         int OCTOT, int OCR, bool GATE, bool OUTF_NHWC>
__global__ __launch_bounds__(256) void convmfma_k(
    const u16* __restrict__ inH, const u16* __restrict__ inL,
    const u16* __restrict__ w2,
    const float* __restrict__ gy, const float* __restrict__ gx,
    const float* __restrict__ gB0, const float* __restrict__ gB1,
    float* __restrict__ outFp, size_t pstride,
    u16* __restrict__ outH, u16* __restrict__ outL) {
  constexpr int CIN = 256;
  constexpr int MF = (OCB == 128) ? 4 : 2;
  constexpr int NF = (OCB == 128) ? 4 : 2;
  constexpr int GCN = 72 / SPLITK;
  __shared__ u16 lds_a[2][128 * 64];
  __shared__ u16 lds_w[2][OCB * 64];
  const int b = blockIdx.z;
  const int oc0 = (blockIdx.y % NPAN) * OCB;
  const int kz = blockIdx.y / NPAN;
  const int gbase = kz * GCN;
  float* outF = outFp + (size_t)kz * pstride;
  const int px0 = blockIdx.x * 128;
  const int tid = threadIdx.x;
  const int lane = tid & 63, wid = tid >> 6;
  const int wpx = (OCB == 128) ? ((wid >> 1) * 64) : (wid * 32);
  const int woc = (OCB == 128) ? ((wid & 1) * 64) : 0;

  const int spx = tid >> 1;
  const int shalf = tid & 1;
  const int opx = px0 + spx;
  const int py = opx / WO, pxx = opx % WO;
  const bool prow_ok = (opx < HO * WO);
  const int ar7 = spx & 7;
  const int awo0 = spx * 128 + (((shalf * 2 + 0) ^ ar7) << 4);
  const int awo1 = spx * 128 + (((shalf * 2 + 1) ^ ar7) << 4);
  const int awo2 = spx * 128 + (((shalf * 2 + 4) ^ ar7) << 4);
  const int awo3 = spx * 128 + (((shalf * 2 + 5) ^ ar7) << 4);
  const bool wact = (OCB == 128) ? true : (tid < OCB * 2);
  const int wrow = tid >> 1, whalf = tid & 1;
  int wwo[4];
#pragma unroll
  for (int j = 0; j < 4; j++) wwo[j] = wrow * 128 + (((whalf * 4 + j) ^ (wrow & 7)) << 4);

  int aoh[MF], aol[MF], woh[NF], wol[NF];
#pragma unroll
  for (int mf = 0; mf < MF; mf++) {
    int r = wpx + mf * 16 + (lane & 15);
    int s = lane >> 4;
    aoh[mf] = r * 128 + ((s ^ (r & 7)) << 4);
    aol[mf] = r * 128 + (((s + 4) ^ (r & 7)) << 4);
  }
#pragma unroll
  for (int nf = 0; nf < NF; nf++) {
    int r = woc + nf * 16 + (lane & 15);
    int s = lane >> 4;
    woh[nf] = r * 128 + ((s ^ (r & 7)) << 4);
    wol[nf] = r * 128 + (((s + 4) ^ (r & 7)) << 4);
  }

  f4_t acc[MF][NF];
#pragma unroll
  for (int mf = 0; mf < MF; mf++)
#pragma unroll
    for (int nf = 0; nf < NF; nf++) { f4_t z = {0.f, 0.f, 0.f, 0.f}; acc[mf][nf] = z; }

  const size_t inb = (size_t)b * (HI * WI) * CIN;
  const size_t wg0 = (size_t)(oc0 + wrow) * 64 + (size_t)whalf * 32;
  uint4 rah0, rah1, ral0, ral1, rwv0, rwv1, rwv2, rwv3;

  auto load_gc = [&](int gc) {
    const int t = gc >> 3, c = gc & 7;
    const int iy = py + (t / 3) - PAD;
    const int ix = pxx + (t % 3) - PAD;
    const bool val = prow_ok && iy >= 0 && iy < HI && ix >= 0 && ix < WI;
    uint4 z = {0, 0, 0, 0};
    rah0 = z; rah1 = z; ral0 = z; ral1 = z;
    if (val) {
      size_t a0 = inb + (size_t)(iy * WI + ix) * CIN + c * 32 + shalf * 16;
      const uint4* ph = (const uint4*)(inH + a0);
      const uint4* pl = (const uint4*)(inL + a0);
      rah0 = ph[0]; rah1 = ph[1]; ral0 = pl[0]; ral1 = pl[1];
    }
    if (wact) {
      const uint4* q = (const uint4*)(w2 + (size_t)gc * OCR * 64 + wg0);
      rwv0 = q[0]; rwv1 = q[1]; rwv2 = q[2]; rwv3 = q[3];
    }
  };
  auto store_gc = [&](int nb) {
    char* la = (char*)lds_a[nb];
    char* lw = (char*)lds_w[nb];
    *(uint4*)(la + awo0) = rah0;
    *(uint4*)(la + awo1) = rah1;
    *(uint4*)(la + awo2) = ral0;
    *(uint4*)(la + awo3) = ral1;
    if (wact) {
      *(uint4*)(lw + wwo[0]) = rwv0;
      *(uint4*)(lw + wwo[1]) = rwv1;
      *(uint4*)(lw + wwo[2]) = rwv2;
      *(uint4*)(lw + wwo[3]) = rwv3;
    }
  };

  load_gc(gbase);
  store_gc(0);
  __syncthreads();
  for (int i = 0; i < GCN; ++i) {
    const int cb = i & 1;
    if (i < GCN - 1) load_gc(gbase + i + 1);
    const char* la = (const char*)lds_a[cb];
    const char* lw = (const char*)lds_w[cb];
    bf8_t ah[MF], al[MF], wh[NF], wl[NF];
#pragma unroll
    for (int mf = 0; mf < MF; mf++) {
      ah[mf] = *(const bf8_t*)(la + aoh[mf]);
      al[mf] = *(const bf8_t*)(la + aol[mf]);
    }
#pragma unroll
    for (int nf = 0; nf < NF; nf++) {
      wh[nf] = *(const bf8_t*)(lw + woh[nf]);
      wl[nf] = *(const bf8_t*)(lw + wol[nf]);
    }
#pragma unroll
    for (int mf = 0; mf < MF; mf++)
#pragma unroll
      for (int nf = 0; nf < NF; nf++) {
        acc[mf][nf] = __builtin_amdgcn_mfma_f32_16x16x32_bf16(ah[mf], wh[nf], acc[mf][nf], 0, 0, 0);
        acc[mf][nf] = __builtin_amdgcn_mfma_f32_16x16x32_bf16(al[mf], wh[nf], acc[mf][nf], 0, 0, 0);
        acc[mf][nf] = __builtin_amdgcn_mfma_f32_16x16x32_bf16(ah[mf], wl[nf], acc[mf][nf], 0, 0, 0);
      }
    if (i < GCN - 1) store_gc(cb ^ 1);
    __syncthreads();
  }

  // epilogue: D row=(lane>>4)*4+r = px, col=lane&15 = oc  [m89-verified]
#pragma unroll
  for (int mf = 0; mf < MF; mf++) {
    const int pxb = px0 + wpx + mf * 16 + ((lane >> 4) << 2);
#pragma unroll
    for (int nf = 0; nf < NF; nf++) {
      const int oc = oc0 + woc + nf * 16 + (lane & 15);
      if (GATE) {
        const float* gp = (oc < 128) ? gy : gx;
        const size_t gbse = ((size_t)b * C1 + (oc & 127)) * NPIX;
#pragma unroll
        for (int r = 0; r < 4; r++) {
          const int px = pxb + r;
          const int pyy = px >> 7, px2 = px & 127;
          const int iiy = (pyy * 62) >> 7, iix = (px2 * 62) >> 7;
          const size_t gi = ((size_t)b * 3844 + iiy * 62 + iix) * 256 + oc;
          float gv = gp[gbse + px] + gB0[gi] + gB1[gi];
          float v = acc[mf][nf][r] * sigmoidf_(gv);
          u16 h = f2bf(v);
          size_t o = ((size_t)b * NPIX + px) * C2 + oc;
          outH[o] = h;
          outL[o] = f2bf(v - bf2f(h));
        }
      } else if (OUTF_NHWC) {
        if (oc < OCTOT) {
#pragma unroll
          for (int r = 0; r < 4; r++) {
            const int px = pxb + r;
            if (px < HO * WO)
              outF[((size_t)b * (HO * WO) + px) * OCTOT + oc] = acc[mf][nf][r];
          }
        }
      } else {
        if (pxb < HO * WO && oc < OCTOT)
          *(f4_t*)&outF[((size_t)b * OCTOT + oc) * (HO * WO) + pxb] = acc[mf][nf];
      }
    }
  }
}

// ---------------- sum 4 split-K partial planes ----------------
__global__ __launch_bounds__(256) void reduce4_k(const float* __restrict__ p,
                                                 float* __restrict__ o, int n4) {
  int i = blockIdx.x * 256 + threadIdx.x;
  if (i >= n4) return;
  const f4_t* v = (const f4_t*)p;
  int n = n4;  // planes are n4 float4s apart
  f4_t a = v[i], b2 = v[i + n], c = v[i + 2 * n], d = v[i + 3 * n];
  f4_t r = {a[0] + b2[0] + c[0] + d[0], a[1] + b2[1] + c[1] + d[1],
            a[2] + b2[2] + c[2] + d[2], a[3] + b2[3] + c[3] + d[3]};
  ((f4_t*)o)[i] = r;
}

// ---------------- 1x1 conv as fp16 MFMA GEMM, direct-global fragments ----------------
template<int AS, int AOFF, bool BIAS, bool SPLIT_OUT>
__global__ __launch_bounds__(256) void gemm1x1_k(const f16* __restrict__ inA,
                                                 const f16* __restrict__ w,
                                                 const float* __restrict__ bias,
                                                 float* __restrict__ outF,
                                                 f16* __restrict__ outH) {
  const int b = blockIdx.z, nb0 = blockIdx.y * 128, px0 = blockIdx.x * 128;
  const int CoutTot = gridDim.y * 128;
  const int tid = threadIdx.x, lane = tid & 63, wid = tid >> 6;
  const int wpx = px0 + wid * 32;
  const int kslot = (lane >> 4) * 8;

  f4_t acc[2][8];
#pragma unroll
  for (int mf = 0; mf < 2; mf++)
#pragma unroll
    for (int nf = 0; nf < 8; nf++) { f4_t z = {0.f, 0.f, 0.f, 0.f}; acc[mf][nf] = z; }

  size_t arow[2];
#pragma unroll
  for (int mf = 0; mf < 2; mf++)
    arow[mf] = ((size_t)b * NPIX + wpx + mf * 16 + (lane & 15)) * AS + AOFF;
  size_t wrow[8];
#pragma unroll
  for (int nf = 0; nf < 8; nf++)
    wrow[nf] = (size_t)(nb0 + nf * 16 + (lane & 15)) * 128;

#pragma unroll
  for (int ks = 0; ks < 4; ks++) {
    const int ko = ks * 32 + kslot;
    h8_t a[2], bw[8];
#pragma unroll
    for (int mf = 0; mf < 2; mf++) a[mf] = *(const h8_t*)(inA + arow[mf] + ko);
#pragma unroll
    for (int nf = 0; nf < 8; nf++) bw[nf] = *(const h8_t*)(w + wrow[nf] + ko);
#pragma unroll
    for (int mf = 0; mf < 2; mf++)
#pragma unroll
      for (int nf = 0; nf < 8; nf++)
        acc[mf][nf] = __builtin_amdgcn_mfma_f32_16x16x32_f16(a[mf], bw[nf], acc[mf][nf], 0, 0, 0);
  }

#pragma unroll
  for (int mf = 0; mf < 2; mf++) {
    const int pxq = wpx + mf * 16 + (lane >> 4) * 4;
#pragma unroll
    for (int nf = 0; nf < 8; nf++) {
      const int oc = nb0 + nf * 16 + (lane & 15);
      f4_t v = acc[mf][nf];
      if (BIAS) {
        float bv = bias[oc];
        v[0] += bv; v[1] += bv; v[2] += bv; v[3] += bv;
      }
      if (SPLIT_OUT) {
#pragma unroll
        for (int r = 0; r < 4; r++)
          outH[((size_t)b * NPIX + pxq + r) * 128 + oc] = (f16)v[r];
      } else {
        *(f4_t*)&outF[((size_t)b * CoutTot + oc) * NPIX + pxq] = v;
      }
    }
  }
}

// ---------------- fused modulated-deform-conv: NHWC f16 gather + grouped MFMA ----------------
__global__ __launch_bounds__(256) void dgemm_k(const f16* __restrict__ catf,
                                               const float* __restrict__ offs,
                                               const f16* __restrict__ wd,
                                               const float* __restrict__ dbias,
                                               f16* __restrict__ feat) {
  const int b = blockIdx.z, g = blockIdx.y;
  const int px0 = blockIdx.x * 128;
  const int tid = threadIdx.x;
  const int lane = tid & 63, wid = tid >> 6;
  const int chunk = lane >> 4;
  const int thalf = chunk >> 1;
  const int ic0 = (chunk & 1) * 8;
  const f16* yb = catf + (size_t)b * NPIX * C2;  // channels 0..127 of cat = y
  const float* ob = offs + (size_t)b * 18 * NPIX;

  int pm[2];
  float pyb[2], pxb2[2];
#pragma unroll
  for (int mf = 0; mf < 2; mf++) {
    pm[mf] = px0 + wid * 32 + mf * 16 + (lane & 15);
    pyb[mf] = (float)(pm[mf] >> 7);
    pxb2[mf] = (float)(pm[mf] & 127);
  }

  f4_t acc[2];
  { f4_t z = {0.f, 0.f, 0.f, 0.f}; acc[0] = z; acc[1] = z; }

  const size_t wbase = (size_t)(g * 16 + (lane & 15)) * 160;
#pragma unroll
  for (int s = 0; s < 5; s++) {
    h8_t ah[2];
#pragma unroll
    for (int mf = 0; mf < 2; mf++) {
      int t = 2 * s + thalf;
      int teff = t > 8 ? 8 : t;
      float dy = ob[(size_t)(2 * teff) * NPIX + pm[mf]];
      float dx = ob[(size_t)(2 * teff + 1) * NPIX + pm[mf]];
      float mk = sigmoidf_(ob[(size_t)teff * NPIX + pm[mf]]);
      int ky = teff / 3, kx = teff - 3 * ky;
      float pyf = pyb[mf] - 1.f + (float)ky + dy;
      float pxf = pxb2[mf] - 1.f + (float)kx + dx;
      float y0f = floorf(pyf), x0f = floorf(pxf);
      float fy = pyf - y0f, fx = pxf - x0f;
      int y0 = (int)y0f, x0 = (int)x0f;
      int y1 = y0 + 1, x1 = x0 + 1;
      float w00 = (1.f - fy) * (1.f - fx) * mk;
      float w01 = (1.f - fy) * fx * mk;
      float w10 = fy * (1.f - fx) * mk;
      float w11 = fy * fx * mk;
      bool vy0 = (y0 >= 0 && y0 < HH), vy1 = (y1 >= 0 && y1 < HH);
      bool vx0 = (x0 >= 0 && x0 < WW), vx1 = (x1 >= 0 && x1 < WW);
      if (!(vy0 && vx0)) w00 = 0.f;
      if (!(vy0 && vx1)) w01 = 0.f;
      if (!(vy1 && vx0)) w10 = 0.f;
      if (!(vy1 && vx1)) w11 = 0.f;
      int cy0 = min(max(y0, 0), HH - 1), cy1 = min(max(y1, 0), HH - 1);
      int cx0 = min(max(x0, 0), WW - 1), cx1 = min(max(x1, 0), WW - 1);
      const f16* p00 = yb + (size_t)(cy0 * WW + cx0) * C2 + g * 16 + ic0;
      const f16* p01 = yb + (size_t)(cy0 * WW + cx1) * C2 + g * 16 + ic0;
      const f16* p10 = yb + (size_t)(cy1 * WW + cx0) * C2 + g * 16 + ic0;
      const f16* p11 = yb + (size_t)(cy1 * WW + cx1) * C2 + g * 16 + ic0;
      h8_t a00 = *(const h8_t*)p00;
      h8_t a01 = *(const h8_t*)p01;
      h8_t a10 = *(const h8_t*)p10;
      h8_t a11 = *(const h8_t*)p11;
      h8_t hh;
#pragma unroll
      for (int j = 0; j < 8; j++) {
        float sv = w00 * (float)a00[j] + w01 * (float)a01[j] +
                   w10 * (float)a10[j] + w11 * (float)a11[j];
        hh[j] = (f16)sv;
      }
      ah[mf] = hh;
    }
    h8_t wv = *(const h8_t*)(wd + wbase + s * 32 + chunk * 8);
#pragma unroll
    for (int mf = 0; mf < 2; mf++)
      acc[mf] = __builtin_amdgcn_mfma_f32_16x16x32_f16(ah[mf], wv, acc[mf], 0, 0, 0);
  }

  const int oc = g * 16 + (lane & 15);
  const float bv = dbias[oc];
#pragma unroll
  for (int mf = 0; mf < 2; mf++) {
    const int pxq = px0 + wid * 32 + mf * 16 + (lane >> 4) * 4;
#pragma unroll
    for (int r = 0; r < 4; r++) {
      float v = fmaxf(acc[mf][r] + bv, 0.f);  // bias + relu (pw input)
      feat[((size_t)b * NPIX + pxq + r) * 128 + oc] = (f16)v;
    }
  }
}

// ---------------- depthwise 3x3, pad=1 (fp32 NCHW) ----------------
__global__ __launch_bounds__(256) void dw3x3_k(const float* __restrict__ in,
                                               const float* __restrict__ w,
                                               float* __restrict__ out, int Cc) {
  int idx = blockIdx.x * 256 + threadIdx.x;
  int total = NB * Cc * NPIX;
  if (idx >= total) return;
  int n = idx & (NPIX - 1);
  int bc = idx >> 14;
  int c = bc % Cc;
  int yy = n >> 7, xx = n & 127;
  const float* p = in + (size_t)bc * NPIX;
  const float* wc = w + c * 9;
  float acc = 0.f;
#pragma unroll
  for (int ky = 0; ky < 3; ky++) {
    int iy = yy + ky - 1;
    if (iy < 0 || iy >= HH) continue;
#pragma unroll
    for (int kx = 0; kx < 3; kx++) {
      int ix = xx + kx - 1;
      if (ix < 0 || ix >= WW) continue;
      acc += wc[ky * 3 + kx] * p[iy * WW + ix];
    }
  }
  out[idx] = acc;
}

// ---------------- zero small accumulators ----------------
__global__ void zero_k(float* p, int n) {
  int i = blockIdx.x * 256 + threadIdx.x;
  if (i < n) p[i] = 0.f;
}

// ---------------- attention: partial Gram + sumsq ----------------
__global__ __launch_bounds__(256) void attn_partial_k(const float* __restrict__ qbuf,
                                                      const float* __restrict__ kvbuf,
                                                      float* __restrict__ s_acc,
                                                      float* __restrict__ qss,
                                                      float* __restrict__ kss) {
  __shared__ float qs[16][129];
  __shared__ float ks[16][129];
  int b = blockIdx.z, h = blockIdx.y, seg = blockIdx.x;
  int tid = threadIdx.x;
  int dd = tid & 15, cc = tid >> 4;
  int n_start = seg * (NPIX / 16);
  float acc = 0.f, q2 = 0.f, k2s = 0.f;
  const float* qb = qbuf + ((size_t)b * C1 + h * DH) * NPIX;
  const float* kb = kvbuf + ((size_t)b * C2 + h * DH) * NPIX;
  for (int n0 = n_start; n0 < n_start + NPIX / 16; n0 += 128) {
    for (int e = tid; e < 16 * 128; e += 256) {
      int r = e >> 7, col = e & 127;
      qs[r][col] = qb[(size_t)r * NPIX + n0 + col];
      ks[r][col] = kb[(size_t)r * NPIX + n0 + col];
    }
    __syncthreads();
#pragma unroll 8
    for (int j = 0; j < 128; j++) {
      float qv = qs[cc][j], kv = ks[dd][j];
      acc += qv * kv;
      q2 += qv * qv;
      k2s += kv * kv;
    }
    __syncthreads();
  }
  int bh = b * NHEADS + h;
  atomicAdd(&s_acc[((size_t)bh * 16 + cc) * 16 + dd], acc);
  if (dd == 0) atomicAdd(&qss[bh * 16 + cc], q2);
  if (cc == 0) atomicAdd(&kss[bh * 16 + dd], k2s);
}

// ---------------- attention: fused softmax + (attn @ v) -> NHWC f16 ----------------
__global__ __launch_bounds__(256) void attnout_k(const float* __restrict__ s_acc,
                                                 const float* __restrict__ qss,
                                                 const float* __restrict__ kss,
                                                 const float* __restrict__ temp,
                                                 const float* __restrict__ kvbuf,
                                                 f16* __restrict__ outA) {
  __shared__ float S[16][17];
  __shared__ float A[16][17];
  __shared__ float qn[16], kn[16];
  int b = blockIdx.z, h = blockIdx.y;
  int tid = threadIdx.x;
  int bh = b * NHEADS + h;
  int dd = tid & 15, cc = tid >> 4;
  if (tid < 16) {
    qn[tid] = fmaxf(sqrtf(qss[bh * 16 + tid]), 1e-12f);
    kn[tid] = fmaxf(sqrtf(kss[bh * 16 + tid]), 1e-12f);
  }
  __syncthreads();
  float t = temp[h];
  float s = s_acc[((size_t)bh * 16 + cc) * 16 + dd] / (qn[cc] * kn[dd]) * t;
  S[cc][dd] = s;
  __syncthreads();
  float mx = -1e30f;
#pragma unroll
  for (int j = 0; j < 16; j++) mx = fmaxf(mx, S[cc][j]);
  float sum = 0.f;
#pragma unroll
  for (int j = 0; j < 16; j++) sum += expf(S[cc][j] - mx);
  A[cc][dd] = expf(s - mx) / sum;
  __syncthreads();

  int n = blockIdx.x * 256 + tid;
  const float* vb = kvbuf + ((size_t)b * C2 + C1 + h * DH) * NPIX;
  float acc[16];
#pragma unroll
  for (int c = 0; c < 16; c++) acc[c] = 0.f;
#pragma unroll
  for (int d = 0; d < 16; d++) {
    float vv = vb[(size_t)d * NPIX + n];
#pragma unroll
    for (int c = 0; c < 16; c++) acc[c] += A[c][d] * vv;
  }
  h8_t o0, o1;
#pragma unroll
  for (int c = 0; c < 8; c++) {
    o0[c] = (f16)acc[c];
    o1[c] = (f16)acc[8 + c];
  }
  size_t base = ((size_t)b * NPIX + n) * 128 + h * 16;
  *(h8_t*)(outA + base) = o0;
  *(h8_t*)(outA + base + 8) = o1;
}

extern "C" void kernel_launch(void* const* d_in, const int* in_sizes, int n_in,
                              void* d_out, int out_size, void* d_ws, size_t ws_size,
                              hipStream_t stream) {
  const float* x = (const float*)d_in[0];
  const float* y = (const float*)d_in[1];
  const float* q_w = (const float*)d_in[2];
  const float* qd_w = (const float*)d_in[3];
  const float* kv_w = (const float*)d_in[4];
  const float* kvd_w = (const float*)d_in[5];
  const float* proj_w = (const float*)d_in[6];
  const float* temperature = (const float*)d_in[7];
  const float* k2_w = (const float*)d_in[8];
  const float* k3_w = (const float*)d_in[9];
  const float* k4_w = (const float*)d_in[10];
  const float* dcn_w = (const float*)d_in[11];
  const float* dcn_b = (const float*)d_in[12];
  const float* pw_w = (const float*)d_in[13];
  const float* pw_b = (const float*)d_in[14];
  float* out = (float*)d_out;

  char* ws = (char*)d_ws;
  size_t off = 0;
  auto alloc = [&](size_t nbytes) {
    char* p = ws + off;
    off += (nbytes + 255) & ~(size_t)255;
    return p;
  };
  f16* CATF = (f16*)alloc((size_t)NB * NPIX * C2 * 2);
  u16* CBH = (u16*)alloc((size_t)NB * NPIX * C2 * 2);
  u16* CBL = (u16*)alloc((size_t)NB * NPIX * C2 * 2);
  u16* PH = (u16*)alloc((size_t)NB * 4096 * C2 * 2);
  u16* PL = (u16*)alloc((size_t)NB * 4096 * C2 * 2);
  float* A2 = (float*)alloc((size_t)2 * NB * 3844 * C2 * 4);   // 2 split-K partial planes, NHWC
  u16* OUT3H = (u16*)alloc((size_t)NB * NPIX * C2 * 2);
  u16* OUT3L = (u16*)alloc((size_t)NB * NPIX * C2 * 2);
  float* OF4P = (float*)alloc((size_t)4 * NB * 18 * NPIX * 4); // 4 split-K partial planes, NCHW
  float* OFFS = (float*)alloc((size_t)NB * 18 * NPIX * 4);
  f16* FEAT = (f16*)alloc((size_t)NB * NPIX * C1 * 2);
  f16* AL = (f16*)alloc((size_t)NB * NPIX * C1 * 2);
  float* Qb = (float*)alloc((size_t)NB * C1 * NPIX * 4);
  u16* W2K2 = (u16*)alloc((size_t)72 * 256 * 64 * 2);
  u16* W2K3 = (u16*)alloc((size_t)72 * 256 * 64 * 2);
  u16* W2K4 = (u16*)alloc((size_t)72 * 32 * 64 * 2);
  f16* WD = (f16*)alloc((size_t)128 * 160 * 2);
  f16* WQ = (f16*)alloc((size_t)128 * 128 * 2);
  f16* WPW = (f16*)alloc((size_t)128 * 128 * 2);
  f16* WKV = (f16*)alloc((size_t)256 * 128 * 2);
  f16* WPJ = (f16*)alloc((size_t)128 * 128 * 2);
  float* SACC = (float*)alloc((size_t)(NB * NHEADS * 256 + 512) * 4);
  float* QSS = SACC + NB * NHEADS * 256;
  float* KSS = QSS + 256;

  // region reuse
  float* A2P0 = A2;
  float* A2P1 = A2 + (size_t)NB * 3844 * C2;
  float* QT1 = (float*)OUT3H;   // q 1x1 out, fp32 (dead before k3 writes OUT3)
  float* KV1 = (float*)CBH;     // kv 1x1 out, fp32, spans CBH+CBL (dead after k3)
  float* KVb = (float*)OUT3H;   // kv dw out, fp32, spans OUT3H+OUT3L (dead after k4... after dgemm)
  f16* AO = FEAT;               // attn out (dead after pw)

  dim3 blk(256);

  // fused weight prep (one launch)
  wprep_all_k<<<dim3(5296), blk, 0, stream>>>(q_w, pw_w, kv_w, proj_w, dcn_w, k2_w, k3_w, k4_w,
                                              WQ, WPW, WKV, WPJ, WD, W2K2, W2K3, W2K4);

  // cat split: f16 (gathers/q) + bf16 hi/lo (conv head)
  splitcat_k<<<dim3(NPIX / 64, C2 / 64, NB), blk, 0, stream>>>(y, x, CATF, CBH, CBL);

  // q path: 1x1 MFMA on x-half of catf -> depthwise
  gemm1x1_k<C2, C1, false, false><<<dim3(NPIX / 128, 1, NB), blk, 0, stream>>>(
      CATF, WQ, nullptr, QT1, nullptr);
  dw3x3_k<<<dim3((NB * C1 * NPIX + 255) / 256), blk, 0, stream>>>(QT1, qd_w, Qb, C1);

  // offset head
  avgpool_b_k<<<dim3((NB * 4096 * 32 + 255) / 256), blk, 0, stream>>>(CBH, CBL, PH, PL);
  // k2: split-K=2, OCB=128, partials summed in k3's gate
  convmfma_k<128, 2, 2, 62, 62, 64, 64, 0, 256, 256, false, true>
      <<<dim3(31, 4, NB), blk, 0, stream>>>(PH, PL, W2K2, nullptr, nullptr, nullptr, nullptr,
                                            A2, (size_t)NB * 3844 * C2, nullptr, nullptr);
  // k3: full-K (at structure ceiling), gate reads y/x NCHW + both A2 partials
  convmfma_k<128, 2, 1, 128, 128, 128, 128, 1, 256, 256, true, false>
      <<<dim3(128, 2, NB), blk, 0, stream>>>(CBH, CBL, W2K3, y, x, A2P0, A2P1,
                                             nullptr, 0, OUT3H, OUT3L);
  // k4: split-K=4 -> partials -> reduce
  convmfma_k<32, 1, 4, 128, 128, 128, 128, 1, 18, 32, false, false>
      <<<dim3(128, 4, NB), blk, 0, stream>>>(OUT3H, OUT3L, W2K4, nullptr, nullptr, nullptr, nullptr,
                                             OF4P, (size_t)NB * 18 * NPIX, nullptr, nullptr);
  reduce4_k<<<dim3((NB * 18 * NPIX / 4 + 255) / 256), blk, 0, stream>>>(
      OF4P, OFFS, NB * 18 * NPIX / 4);

  // deformable alignment (gathers from y-half of catf) + pw 1x1
  dgemm_k<<<dim3(NPIX / 128, NG, NB), blk, 0, stream>>>(CATF, OFFS, WD, dcn_b, FEAT);
  gemm1x1_k<C1, 0, true, true><<<dim3(NPIX / 128, 1, NB), blk, 0, stream>>>(
      FEAT, WPW, pw_b, nullptr, AL);

  // kv path
  gemm1x1_k<C1, 0, false, false><<<dim3(NPIX / 128, 2, NB), blk, 0, stream>>>(
      AL, WKV, nullptr, KV1, nullptr);
  dw3x3_k<<<dim3((NB * C2 * NPIX + 255) / 256), blk, 0, stream>>>(KV1, kvd_w, KVb, C2);

  // attention
  zero_k<<<dim3((4608 + 255) / 256), blk, 0, stream>>>(SACC, 4608);
  attn_partial_k<<<dim3(16, NHEADS, NB), blk, 0, stream>>>(Qb, KVb, SACC, QSS, KSS);
  attnout_k<<<dim3(NPIX / 256, NHEADS, NB), blk, 0, stream>>>(SACC, QSS, KSS, temperature, KVb, AO);
  gemm1x1_k<C1, 0, false, false><<<dim3(NPIX / 128, 1, NB), blk, 0, stream>>>(
      AO, WPJ, nullptr, out, nullptr);
}

// Round 9
// 386.373 us; speedup vs baseline: 1.9433x; 1.2101x over previous
//
#include <hip/hip_runtime.h>
#include <math.h>

#define NB 2
#define C1 128
#define C2 256
#define HH 128
#define WW 128
#define NPIX (HH*WW)
#define NHEADS 8
#define DH 16
#define NG 8

typedef unsigned short u16;
typedef _Float16 f16;
typedef __attribute__((ext_vector_type(8))) _Float16 h8_t;
typedef __attribute__((ext_vector_type(8))) short bf8_t;
typedef __attribute__((ext_vector_type(4))) float f4_t;

__device__ __forceinline__ float sigmoidf_(float v) { return 1.f / (1.f + expf(-v)); }
__device__ __forceinline__ u16 f2bf(float f) {
  unsigned u = __float_as_uint(f);
  return (u16)((u + 0x7FFFu + ((u >> 16) & 1u)) >> 16);
}
__device__ __forceinline__ float bf2f(u16 h) { return __uint_as_float(((unsigned)h) << 16); }

// ---------------- NCHW fp32 (y|x) -> NHWC: f16 cat + bf16 hi/lo cat ----------------
__global__ __launch_bounds__(256) void splitcat_k(const float* __restrict__ y,
                                                  const float* __restrict__ x,
                                                  f16* __restrict__ catf,
                                                  u16* __restrict__ cbh,
                                                  u16* __restrict__ cbl) {
  __shared__ float tile[64][65];
  int b = blockIdx.z, c0 = blockIdx.y * 64, p0 = blockIdx.x * 64;
  int tid = threadIdx.x;
  const float* src = (c0 < 128) ? y : x;
  int cc0 = c0 & 127;
  for (int e = tid; e < 4096; e += 256) {
    int c = e >> 6, p = e & 63;
    tile[c][p] = src[((size_t)b * C1 + cc0 + c) * NPIX + p0 + p];
  }
  __syncthreads();
  for (int e = tid; e < 4096; e += 256) {
    int p = e >> 6, c = e & 63;
    float v = tile[c][p];
    size_t o = ((size_t)b * NPIX + p0 + p) * C2 + c0 + c;
    catf[o] = (f16)v;
    u16 h = f2bf(v);
    cbh[o] = h;
    cbl[o] = f2bf(v - bf2f(h));
  }
}

// ---------------- avgpool2 on bf16-pair cat -> PH/PL [b][4096][256] ----------------
__global__ __launch_bounds__(256) void avgpool_b_k(const u16* __restrict__ cbh,
                                                   const u16* __restrict__ cbl,
                                                   u16* __restrict__ ph,
                                                   u16* __restrict__ pl) {
  int idx = blockIdx.x * 256 + threadIdx.x;
  if (idx >= NB * 4096 * 32) return;
  int c8 = idx & 31;
  int p = (idx >> 5) & 4095;
  int b = idx >> 17;
  int yo = p >> 6, xo = p & 63;
  size_t base = ((size_t)b * NPIX + (yo * 2) * WW + xo * 2) * C2 + c8 * 8;
  const size_t d01 = C2, d10 = (size_t)WW * C2, d11 = (size_t)WW * C2 + C2;
  bf8_t h00 = *(const bf8_t*)(cbh + base), l00 = *(const bf8_t*)(cbl + base);
  bf8_t h01 = *(const bf8_t*)(cbh + base + d01), l01 = *(const bf8_t*)(cbl + base + d01);
  bf8_t h10 = *(const bf8_t*)(cbh + base + d10), l10 = *(const bf8_t*)(cbl + base + d10);
  bf8_t h11 = *(const bf8_t*)(cbh + base + d11), l11 = *(const bf8_t*)(cbl + base + d11);
  bf8_t oh, ol;
#pragma unroll
  for (int j = 0; j < 8; j++) {
    float v00 = bf2f((u16)h00[j]) + bf2f((u16)l00[j]);
    float v01 = bf2f((u16)h01[j]) + bf2f((u16)l01[j]);
    float v10 = bf2f((u16)h10[j]) + bf2f((u16)l10[j]);
    float v11 = bf2f((u16)h11[j]) + bf2f((u16)l11[j]);
    float v = 0.25f * (v00 + v01 + v10 + v11);
    u16 h = f2bf(v);
    oh[j] = (short)h;
    ol[j] = (short)f2bf(v - bf2f(h));
  }
  size_t o = ((size_t)b * 4096 + p) * C2 + c8 * 8;
  *(bf8_t*)(ph + o) = oh;
  *(bf8_t*)(pl + o) = ol;
}

// ---------------- fused weight prep + accumulator zero (one launch) ----------------
__device__ __forceinline__ void wtrans_body(const float* __restrict__ w, u16* __restrict__ w2,
                                            int OC, int OCR, int idx) {
  int t = idx / (256 * OCR);
  int rem = idx - t * 256 * OCR;
  int ic = rem / OCR;
  int oc = rem - ic * OCR;
  float v = (oc < OC) ? w[((size_t)oc * 256 + ic) * 9 + t] : 0.f;
  u16 h = f2bf(v);
  u16 l = f2bf(v - bf2f(h));
  size_t row = (size_t)(t * 8 + (ic >> 5)) * OCR + oc;
  w2[row * 64 + (ic & 31)] = h;
  w2[row * 64 + 32 + (ic & 31)] = l;
}

__global__ __launch_bounds__(256) void wprep_all_k(
    const float* __restrict__ q_w, const float* __restrict__ pw_w,
    const float* __restrict__ kv_w, const float* __restrict__ proj_w,
    const float* __restrict__ dcn_w, const float* __restrict__ k2_w,
    const float* __restrict__ k3_w, const float* __restrict__ k4_w,
    f16* __restrict__ WQ, f16* __restrict__ WPW, f16* __restrict__ WKV,
    f16* __restrict__ WPJ, f16* __restrict__ WD,
    u16* __restrict__ W2K2, u16* __restrict__ W2K3, u16* __restrict__ W2K4,
    float* __restrict__ sacc) {
  int idx = blockIdx.x * 256 + threadIdx.x;
  if (idx < 16384) { WQ[idx] = (f16)q_w[idx]; return; }
  idx -= 16384;
  if (idx < 16384) { WPW[idx] = (f16)pw_w[idx]; return; }
  idx -= 16384;
  if (idx < 32768) { WKV[idx] = (f16)kv_w[idx]; return; }
  idx -= 32768;
  if (idx < 16384) { WPJ[idx] = (f16)proj_w[idx]; return; }
  idx -= 16384;
  if (idx < 20480) {
    int oc = idx / 160, k = idx - oc * 160;
    int t = k >> 4, ic = k & 15;
    WD[idx] = (t < 9) ? (f16)dcn_w[((size_t)oc * 16 + ic) * 9 + t] : (f16)0.f;
    return;
  }
  idx -= 20480;
  if (idx < 589824) { wtrans_body(k2_w, W2K2, 256, 256, idx); return; }
  idx -= 589824;
  if (idx < 589824) { wtrans_body(k3_w, W2K3, 256, 256, idx); return; }
  idx -= 589824;
  if (idx < 73728) { wtrans_body(k4_w, W2K4, 18, 32, idx); return; }
  idx -= 73728;
  if (idx < 4608) sacc[idx] = 0.f;
}

// ---------------- implicit-GEMM 3x3 conv, bf16 hi/lo 3-product, dbuf, split-K ----------------
// Block: 128 px x OCB oc, 4 waves. gridDim.y = NPAN * SPLITK (oc-panel minor, kz major).
// GATE epilogue sums NGB split-K partial planes of gB (stride NB*3844*C2).
template<int OCB, int NPAN, int SPLITK, int NGB, int WO, int HO, int WI, int HI, int PAD,
         int OCTOT, int OCR, bool GATE, bool OUTF_NHWC>
__global__ __launch_bounds__(256) void convmfma_k(
    const u16* __restrict__ inH, const u16* __restrict__ inL,
    const u16* __restrict__ w2,
    const float* __restrict__ gy, const float* __restrict__ gx,
    const float* __restrict__ gB,
    float* __restrict__ outFp, size_t pstride,
    u16* __restrict__ outH, u16* __restrict__ outL) {
  constexpr int CIN = 256;
  constexpr int MF = (OCB == 128) ? 4 : 2;
  constexpr int NF = (OCB == 128) ? 4 : 2;
  constexpr int GCN = 72 / SPLITK;
  __shared__ u16 lds_a[2][128 * 64];
  __shared__ u16 lds_w[2][OCB * 64];
  const int b = blockIdx.z;
  const int oc0 = (blockIdx.y % NPAN) * OCB;
  const int kz = blockIdx.y / NPAN;
  const int gbase = kz * GCN;
  float* outF = outFp + (size_t)kz * pstride;
  const int px0 = blockIdx.x * 128;
  const int tid = threadIdx.x;
  const int lane = tid & 63, wid = tid >> 6;
  const int wpx = (OCB == 128) ? ((wid >> 1) * 64) : (wid * 32);
  const int woc = (OCB == 128) ? ((wid & 1) * 64) : 0;

  const int spx = tid >> 1;
  const int shalf = tid & 1;
  const int opx = px0 + spx;
  const int py = opx / WO, pxx = opx % WO;
  const bool prow_ok = (opx < HO * WO);
  const int ar7 = spx & 7;
  const int awo0 = spx * 128 + (((shalf * 2 + 0) ^ ar7) << 4);
  const int awo1 = spx * 128 + (((shalf * 2 + 1) ^ ar7) << 4);
  const int awo2 = spx * 128 + (((shalf * 2 + 4) ^ ar7) << 4);
  const int awo3 = spx * 128 + (((shalf * 2 + 5) ^ ar7) << 4);
  const bool wact = (OCB == 128) ? true : (tid < OCB * 2);
  const int wrow = tid >> 1, whalf = tid & 1;
  int wwo[4];
#pragma unroll
  for (int j = 0; j < 4; j++) wwo[j] = wrow * 128 + (((whalf * 4 + j) ^ (wrow & 7)) << 4);

  int aoh[MF], aol[MF], woh[NF], wol[NF];
#pragma unroll
  for (int mf = 0; mf < MF; mf++) {
    int r = wpx + mf * 16 + (lane & 15);
    int s = lane >> 4;
    aoh[mf] = r * 128 + ((s ^ (r & 7)) << 4);
    aol[mf] = r * 128 + (((s + 4) ^ (r & 7)) << 4);
  }
#pragma unroll
  for (int nf = 0; nf < NF; nf++) {
    int r = woc + nf * 16 + (lane & 15);
    int s = lane >> 4;
    woh[nf] = r * 128 + ((s ^ (r & 7)) << 4);
    wol[nf] = r * 128 + (((s + 4) ^ (r & 7)) << 4);
  }

  f4_t acc[MF][NF];
#pragma unroll
  for (int mf = 0; mf < MF; mf++)
#pragma unroll
    for (int nf = 0; nf < NF; nf++) { f4_t z = {0.f, 0.f, 0.f, 0.f}; acc[mf][nf] = z; }

  const size_t inb = (size_t)b * (HI * WI) * CIN;
  const size_t wg0 = (size_t)(oc0 + wrow) * 64 + (size_t)whalf * 32;
  uint4 rah0, rah1, ral0, ral1, rwv0, rwv1, rwv2, rwv3;

  auto load_gc = [&](int gc) {
    const int t = gc >> 3, c = gc & 7;
    const int iy = py + (t / 3) - PAD;
    const int ix = pxx + (t % 3) - PAD;
    const bool val = prow_ok && iy >= 0 && iy < HI && ix >= 0 && ix < WI;
    uint4 z = {0, 0, 0, 0};
    rah0 = z; rah1 = z; ral0 = z; ral1 = z;
    if (val) {
      size_t a0 = inb + (size_t)(iy * WI + ix) * CIN + c * 32 + shalf * 16;
      const uint4* ph = (const uint4*)(inH + a0);
      const uint4* pl = (const uint4*)(inL + a0);
      rah0 = ph[0]; rah1 = ph[1]; ral0 = pl[0]; ral1 = pl[1];
    }
    if (wact) {
      const uint4* q = (const uint4*)(w2 + (size_t)gc * OCR * 64 + wg0);
      rwv0 = q[0]; rwv1 = q[1]; rwv2 = q[2]; rwv3 = q[3];
    }
  };
  auto store_gc = [&](int nb) {
    char* la = (char*)lds_a[nb];
    char* lw = (char*)lds_w[nb];
    *(uint4*)(la + awo0) = rah0;
    *(uint4*)(la + awo1) = rah1;
    *(uint4*)(la + awo2) = ral0;
    *(uint4*)(la + awo3) = ral1;
    if (wact) {
      *(uint4*)(lw + wwo[0]) = rwv0;
      *(uint4*)(lw + wwo[1]) = rwv1;
      *(uint4*)(lw + wwo[2]) = rwv2;
      *(uint4*)(lw + wwo[3]) = rwv3;
    }
  };

  load_gc(gbase);
  store_gc(0);
  __syncthreads();
  for (int i = 0; i < GCN; ++i) {
    const int cb = i & 1;
    if (i < GCN - 1) load_gc(gbase + i + 1);
    const char* la = (const char*)lds_a[cb];
    const char* lw = (const char*)lds_w[cb];
    bf8_t ah[MF], al[MF], wh[NF], wl[NF];
#pragma unroll
    for (int mf = 0; mf < MF; mf++) {
      ah[mf] = *(const bf8_t*)(la + aoh[mf]);
      al[mf] = *(const bf8_t*)(la + aol[mf]);
    }
#pragma unroll
    for (int nf = 0; nf < NF; nf++) {
      wh[nf] = *(const bf8_t*)(lw + woh[nf]);
      wl[nf] = *(const bf8_t*)(lw + wol[nf]);
    }
#pragma unroll
    for (int mf = 0; mf < MF; mf++)
#pragma unroll
      for (int nf = 0; nf < NF; nf++) {
        acc[mf][nf] = __builtin_amdgcn_mfma_f32_16x16x32_bf16(ah[mf], wh[nf], acc[mf][nf], 0, 0, 0);
        acc[mf][nf] = __builtin_amdgcn_mfma_f32_16x16x32_bf16(al[mf], wh[nf], acc[mf][nf], 0, 0, 0);
        acc[mf][nf] = __builtin_amdgcn_mfma_f32_16x16x32_bf16(ah[mf], wl[nf], acc[mf][nf], 0, 0, 0);
      }
    if (i < GCN - 1) store_gc(cb ^ 1);
    __syncthreads();
  }

  // epilogue: D row=(lane>>4)*4+r = px, col=lane&15 = oc  [m89-verified]
#pragma unroll
  for (int mf = 0; mf < MF; mf++) {
    const int pxb = px0 + wpx + mf * 16 + ((lane >> 4) << 2);
#pragma unroll
    for (int nf = 0; nf < NF; nf++) {
      const int oc = oc0 + woc + nf * 16 + (lane & 15);
      if (GATE) {
        const float* gp = (oc < 128) ? gy : gx;
        const size_t gbse = ((size_t)b * C1 + (oc & 127)) * NPIX;
        constexpr size_t gstride = (size_t)NB * 3844 * C2;
#pragma unroll
        for (int r = 0; r < 4; r++) {
          const int px = pxb + r;
          const int pyy = px >> 7, px2 = px & 127;
          const int iiy = (pyy * 62) >> 7, iix = (px2 * 62) >> 7;
          const size_t gi = ((size_t)b * 3844 + iiy * 62 + iix) * 256 + oc;
          float gv = gp[gbse + px];
#pragma unroll
          for (int pp = 0; pp < NGB; pp++) gv += gB[gi + (size_t)pp * gstride];
          float v = acc[mf][nf][r] * sigmoidf_(gv);
          u16 h = f2bf(v);
          size_t o = ((size_t)b * NPIX + px) * C2 + oc;
          outH[o] = h;
          outL[o] = f2bf(v - bf2f(h));
        }
      } else if (OUTF_NHWC) {
        if (oc < OCTOT) {
#pragma unroll
          for (int r = 0; r < 4; r++) {
            const int px = pxb + r;
            if (px < HO * WO)
              outF[((size_t)b * (HO * WO) + px) * OCTOT + oc] = acc[mf][nf][r];
          }
        }
      } else {
        if (pxb < HO * WO && oc < OCTOT)
          *(f4_t*)&outF[((size_t)b * OCTOT + oc) * (HO * WO) + pxb] = acc[mf][nf];
      }
    }
  }
}

// ---------------- sum NP split-K partial planes ----------------
template<int NP>
__global__ __launch_bounds__(256) void reduceN_k(const float* __restrict__ p,
                                                 float* __restrict__ o, int n4) {
  int i = blockIdx.x * 256 + threadIdx.x;
  if (i >= n4) return;
  const f4_t* v = (const f4_t*)p;
  f4_t r = v[i];
#pragma unroll
  for (int k = 1; k < NP; k++) {
    f4_t a = v[i + (size_t)k * n4];
    r[0] += a[0]; r[1] += a[1]; r[2] += a[2]; r[3] += a[3];
  }
  ((f4_t*)o)[i] = r;
}

// ---------------- 1x1 conv as fp16 MFMA GEMM, direct-global fragments ----------------
template<int AS, int AOFF, bool BIAS, bool SPLIT_OUT>
__global__ __launch_bounds__(256) void gemm1x1_k(const f16* __restrict__ inA,
                                                 const f16* __restrict__ w,
                                                 const float* __restrict__ bias,
                                                 float* __restrict__ outF,
                                                 f16* __restrict__ outH) {
  const int b = blockIdx.z, nb0 = blockIdx.y * 128, px0 = blockIdx.x * 128;
  const int CoutTot = gridDim.y * 128;
  const int tid = threadIdx.x, lane = tid & 63, wid = tid >> 6;
  const int wpx = px0 + wid * 32;
  const int kslot = (lane >> 4) * 8;

  f4_t acc[2][8];
#pragma unroll
  for (int mf = 0; mf < 2; mf++)
#pragma unroll
    for (int nf = 0; nf < 8; nf++) { f4_t z = {0.f, 0.f, 0.f, 0.f}; acc[mf][nf] = z; }

  size_t arow[2];
#pragma unroll
  for (int mf = 0; mf < 2; mf++)
    arow[mf] = ((size_t)b * NPIX + wpx + mf * 16 + (lane & 15)) * AS + AOFF;
  size_t wrow[8];
#pragma unroll
  for (int nf = 0; nf < 8; nf++)
    wrow[nf] = (size_t)(nb0 + nf * 16 + (lane & 15)) * 128;

#pragma unroll
  for (int ks = 0; ks < 4; ks++) {
    const int ko = ks * 32 + kslot;
    h8_t a[2], bw[8];
#pragma unroll
    for (int mf = 0; mf < 2; mf++) a[mf] = *(const h8_t*)(inA + arow[mf] + ko);
#pragma unroll
    for (int nf = 0; nf < 8; nf++) bw[nf] = *(const h8_t*)(w + wrow[nf] + ko);
#pragma unroll
    for (int mf = 0; mf < 2; mf++)
#pragma unroll
      for (int nf = 0; nf < 8; nf++)
        acc[mf][nf] = __builtin_amdgcn_mfma_f32_16x16x32_f16(a[mf], bw[nf], acc[mf][nf], 0, 0, 0);
  }

#pragma unroll
  for (int mf = 0; mf < 2; mf++) {
    const int pxq = wpx + mf * 16 + (lane >> 4) * 4;
#pragma unroll
    for (int nf = 0; nf < 8; nf++) {
      const int oc = nb0 + nf * 16 + (lane & 15);
      f4_t v = acc[mf][nf];
      if (BIAS) {
        float bv = bias[oc];
        v[0] += bv; v[1] += bv; v[2] += bv; v[3] += bv;
      }
      if (SPLIT_OUT) {
#pragma unroll
        for (int r = 0; r < 4; r++)
          outH[((size_t)b * NPIX + pxq + r) * 128 + oc] = (f16)v[r];
      } else {
        *(f4_t*)&outF[((size_t)b * CoutTot + oc) * NPIX + pxq] = v;
      }
    }
  }
}

// ---------------- fused modulated-deform-conv: NHWC f16 gather + grouped MFMA ----------------
__global__ __launch_bounds__(256) void dgemm_k(const f16* __restrict__ catf,
                                               const float* __restrict__ offs,
                                               const f16* __restrict__ wd,
                                               const float* __restrict__ dbias,
                                               f16* __restrict__ feat) {
  const int b = blockIdx.z, g = blockIdx.y;
  const int px0 = blockIdx.x * 128;
  const int tid = threadIdx.x;
  const int lane = tid & 63, wid = tid >> 6;
  const int chunk = lane >> 4;
  const int thalf = chunk >> 1;
  const int ic0 = (chunk & 1) * 8;
  const f16* yb = catf + (size_t)b * NPIX * C2;  // channels 0..127 of cat = y
  const float* ob = offs + (size_t)b * 18 * NPIX;

  int pm[2];
  float pyb[2], pxb2[2];
#pragma unroll
  for (int mf = 0; mf < 2; mf++) {
    pm[mf] = px0 + wid * 32 + mf * 16 + (lane & 15);
    pyb[mf] = (float)(pm[mf] >> 7);
    pxb2[mf] = (float)(pm[mf] & 127);
  }

  f4_t acc[2];
  { f4_t z = {0.f, 0.f, 0.f, 0.f}; acc[0] = z; acc[1] = z; }

  const size_t wbase = (size_t)(g * 16 + (lane & 15)) * 160;
#pragma unroll
  for (int s = 0; s < 5; s++) {
    h8_t ah[2];
#pragma unroll
    for (int mf = 0; mf < 2; mf++) {
      int t = 2 * s + thalf;
      int teff = t > 8 ? 8 : t;
      float dy = ob[(size_t)(2 * teff) * NPIX + pm[mf]];
      float dx = ob[(size_t)(2 * teff + 1) * NPIX + pm[mf]];
      float mk = sigmoidf_(ob[(size_t)teff * NPIX + pm[mf]]);
      int ky = teff / 3, kx = teff - 3 * ky;
      float pyf = pyb[mf] - 1.f + (float)ky + dy;
      float pxf = pxb2[mf] - 1.f + (float)kx + dx;
      float y0f = floorf(pyf), x0f = floorf(pxf);
      float fy = pyf - y0f, fx = pxf - x0f;
      int y0 = (int)y0f, x0 = (int)x0f;
      int y1 = y0 + 1, x1 = x0 + 1;
      float w00 = (1.f - fy) * (1.f - fx) * mk;
      float w01 = (1.f - fy) * fx * mk;
      float w10 = fy * (1.f - fx) * mk;
      float w11 = fy * fx * mk;
      bool vy0 = (y0 >= 0 && y0 < HH), vy1 = (y1 >= 0 && y1 < HH);
      bool vx0 = (x0 >= 0 && x0 < WW), vx1 = (x1 >= 0 && x1 < WW);
      if (!(vy0 && vx0)) w00 = 0.f;
      if (!(vy0 && vx1)) w01 = 0.f;
      if (!(vy1 && vx0)) w10 = 0.f;
      if (!(vy1 && vx1)) w11 = 0.f;
      int cy0 = min(max(y0, 0), HH - 1), cy1 = min(max(y1, 0), HH - 1);
      int cx0 = min(max(x0, 0), WW - 1), cx1 = min(max(x1, 0), WW - 1);
      const f16* p00 = yb + (size_t)(cy0 * WW + cx0) * C2 + g * 16 + ic0;
      const f16* p01 = yb + (size_t)(cy0 * WW + cx1) * C2 + g * 16 + ic0;
      const f16* p10 = yb + (size_t)(cy1 * WW + cx0) * C2 + g * 16 + ic0;
      const f16* p11 = yb + (size_t)(cy1 * WW + cx1) * C2 + g * 16 + ic0;
      h8_t a00 = *(const h8_t*)p00;
      h8_t a01 = *(const h8_t*)p01;
      h8_t a10 = *(const h8_t*)p10;
      h8_t a11 = *(const h8_t*)p11;
      h8_t hh;
#pragma unroll
      for (int j = 0; j < 8; j++) {
        float sv = w00 * (float)a00[j] + w01 * (float)a01[j] +
                   w10 * (float)a10[j] + w11 * (float)a11[j];
        hh[j] = (f16)sv;
      }
      ah[mf] = hh;
    }
    h8_t wv = *(const h8_t*)(wd + wbase + s * 32 + chunk * 8);
#pragma unroll
    for (int mf = 0; mf < 2; mf++)
      acc[mf] = __builtin_amdgcn_mfma_f32_16x16x32_f16(ah[mf], wv, acc[mf], 0, 0, 0);
  }

  const int oc = g * 16 + (lane & 15);
  const float bv = dbias[oc];
#pragma unroll
  for (int mf = 0; mf < 2; mf++) {
    const int pxq = px0 + wid * 32 + mf * 16 + (lane >> 4) * 4;
#pragma unroll
    for (int r = 0; r < 4; r++) {
      float v = fmaxf(acc[mf][r] + bv, 0.f);  // bias + relu (pw input)
      feat[((size_t)b * NPIX + pxq + r) * 128 + oc] = (f16)v;
    }
  }
}

// ---------------- depthwise 3x3, pad=1 (fp32 NCHW), float4-vectorized ----------------
__global__ __launch_bounds__(256) void dw3x3_k(const float* __restrict__ in,
                                               const float* __restrict__ w,
                                               float* __restrict__ out, int Cc) {
  int i4 = blockIdx.x * 256 + threadIdx.x;
  int total4 = NB * Cc * (NPIX / 4);
  if (i4 >= total4) return;
  int n4 = i4 & (NPIX / 4 - 1);
  int bc = i4 >> 12;               // NPIX/4 = 4096 = 2^12
  int c = bc % Cc;
  int n = n4 << 2;
  int yy = n >> 7, xx = n & 127;   // xx multiple of 4
  const float* p = in + (size_t)bc * NPIX;
  const float* wc = w + c * 9;
  float acc[4] = {0.f, 0.f, 0.f, 0.f};
#pragma unroll
  for (int ky = 0; ky < 3; ky++) {
    int iy = yy + ky - 1;
    if (iy < 0 || iy >= HH) continue;
    const float* row = p + iy * WW;
    float v[6];
    v[0] = (xx > 0) ? row[xx - 1] : 0.f;
    float4 m = *(const float4*)(row + xx);
    v[1] = m.x; v[2] = m.y; v[3] = m.z; v[4] = m.w;
    v[5] = (xx + 4 < WW) ? row[xx + 4] : 0.f;
#pragma unroll
    for (int kx = 0; kx < 3; kx++) {
      float wv = wc[ky * 3 + kx];
#pragma unroll
      for (int j = 0; j < 4; j++) acc[j] += wv * v[j + kx];
    }
  }
  *(float4*)&out[(size_t)bc * NPIX + n] = make_float4(acc[0], acc[1], acc[2], acc[3]);
}

// ---------------- attention Gram (Q·K^T 16x16 over N=16384) via bf16 hi/lo MFMA ----------------
// grid (8, NHEADS, NB), 4 waves; wave handles one 512-wide n-segment; fragments mirror gemm1x1.
__global__ __launch_bounds__(256) void gram_k(const float* __restrict__ qbuf,
                                              const float* __restrict__ kvbuf,
                                              float* __restrict__ s_acc,
                                              float* __restrict__ qss,
                                              float* __restrict__ kss) {
  int b = blockIdx.z, h = blockIdx.y;
  int tid = threadIdx.x, lane = tid & 63, wid = tid >> 6;
  int r = lane & 15, ks = lane >> 4;
  const float* qb = qbuf + ((size_t)b * C1 + h * DH + r) * NPIX;
  const float* kb = kvbuf + ((size_t)b * C2 + h * DH + r) * NPIX;
  int n0 = (blockIdx.x * 4 + wid) * 512;
  f4_t acc = {0.f, 0.f, 0.f, 0.f};
  float q2 = 0.f, k2 = 0.f;
  for (int s = 0; s < 16; s++) {
    int k = n0 + s * 32 + ks * 8;
    float4 qa = *(const float4*)(qb + k), qb4 = *(const float4*)(qb + k + 4);
    float4 ka = *(const float4*)(kb + k), kb4 = *(const float4*)(kb + k + 4);
    float qv[8] = {qa.x, qa.y, qa.z, qa.w, qb4.x, qb4.y, qb4.z, qb4.w};
    float kv[8] = {ka.x, ka.y, ka.z, ka.w, kb4.x, kb4.y, kb4.z, kb4.w};
    bf8_t qh, ql, kh, kl;
#pragma unroll
    for (int j = 0; j < 8; j++) {
      u16 hq = f2bf(qv[j]);
      qh[j] = (short)hq;
      ql[j] = (short)f2bf(qv[j] - bf2f(hq));
      u16 hk = f2bf(kv[j]);
      kh[j] = (short)hk;
      kl[j] = (short)f2bf(kv[j] - bf2f(hk));
      q2 += qv[j] * qv[j];
      k2 += kv[j] * kv[j];
    }
    acc = __builtin_amdgcn_mfma_f32_16x16x32_bf16(qh, kh, acc, 0, 0, 0);
    acc = __builtin_amdgcn_mfma_f32_16x16x32_bf16(ql, kh, acc, 0, 0, 0);
    acc = __builtin_amdgcn_mfma_f32_16x16x32_bf16(qh, kl, acc, 0, 0, 0);
  }
  int bh = b * NHEADS + h;
  // D: row (cq) = ks*4 + rr, col (ck) = r  [mirrors verified gemm1x1 mapping]
#pragma unroll
  for (int rr = 0; rr < 4; rr++)
    atomicAdd(&s_acc[((size_t)bh * 16 + ks * 4 + rr) * 16 + r], acc[rr]);
  // qss/kss: reduce the 4 k-slot lanes of row r (lanes r, r+16, r+32, r+48)
  q2 += __shfl_xor(q2, 16);
  q2 += __shfl_xor(q2, 32);
  k2 += __shfl_xor(k2, 16);
  k2 += __shfl_xor(k2, 32);
  if (ks == 0) {
    atomicAdd(&qss[bh * 16 + r], q2);
    atomicAdd(&kss[bh * 16 + r], k2);
  }
}

// ---------------- attention: fused softmax + (attn @ v) -> NHWC f16 ----------------
__global__ __launch_bounds__(256) void attnout_k(const float* __restrict__ s_acc,
                                                 const float* __restrict__ qss,
                                                 const float* __restrict__ kss,
                                                 const float* __restrict__ temp,
                                                 const float* __restrict__ kvbuf,
                                                 f16* __restrict__ outA) {
  __shared__ float S[16][17];
  __shared__ float A[16][17];
  __shared__ float qn[16], kn[16];
  int b = blockIdx.z, h = blockIdx.y;
  int tid = threadIdx.x;
  int bh = b * NHEADS + h;
  int dd = tid & 15, cc = tid >> 4;
  if (tid < 16) {
    qn[tid] = fmaxf(sqrtf(qss[bh * 16 + tid]), 1e-12f);
    kn[tid] = fmaxf(sqrtf(kss[bh * 16 + tid]), 1e-12f);
  }
  __syncthreads();
  float t = temp[h];
  float s = s_acc[((size_t)bh * 16 + cc) * 16 + dd] / (qn[cc] * kn[dd]) * t;
  S[cc][dd] = s;
  __syncthreads();
  float mx = -1e30f;
#pragma unroll
  for (int j = 0; j < 16; j++) mx = fmaxf(mx, S[cc][j]);
  float sum = 0.f;
#pragma unroll
  for (int j = 0; j < 16; j++) sum += expf(S[cc][j] - mx);
  A[cc][dd] = expf(s - mx) / sum;
  __syncthreads();

  int n = blockIdx.x * 256 + tid;
  const float* vb = kvbuf + ((size_t)b * C2 + C1 + h * DH) * NPIX;
  float acc[16];
#pragma unroll
  for (int c = 0; c < 16; c++) acc[c] = 0.f;
#pragma unroll
  for (int d = 0; d < 16; d++) {
    float vv = vb[(size_t)d * NPIX + n];
#pragma unroll
    for (int c = 0; c < 16; c++) acc[c] += A[c][d] * vv;
  }
  h8_t o0, o1;
#pragma unroll
  for (int c = 0; c < 8; c++) {
    o0[c] = (f16)acc[c];
    o1[c] = (f16)acc[8 + c];
  }
  size_t base = ((size_t)b * NPIX + n) * 128 + h * 16;
  *(h8_t*)(outA + base) = o0;
  *(h8_t*)(outA + base + 8) = o1;
}

extern "C" void kernel_launch(void* const* d_in, const int* in_sizes, int n_in,
                              void* d_out, int out_size, void* d_ws, size_t ws_size,
                              hipStream_t stream) {
  const float* x = (const float*)d_in[0];
  const float* y = (const float*)d_in[1];
  const float* q_w = (const float*)d_in[2];
  const float* qd_w = (const float*)d_in[3];
  const float* kv_w = (const float*)d_in[4];
  const float* kvd_w = (const float*)d_in[5];
  const float* proj_w = (const float*)d_in[6];
  const float* temperature = (const float*)d_in[7];
  const float* k2_w = (const float*)d_in[8];
  const float* k3_w = (const float*)d_in[9];
  const float* k4_w = (const float*)d_in[10];
  const float* dcn_w = (const float*)d_in[11];
  const float* dcn_b = (const float*)d_in[12];
  const float* pw_w = (const float*)d_in[13];
  const float* pw_b = (const float*)d_in[14];
  float* out = (float*)d_out;

  char* ws = (char*)d_ws;
  size_t off = 0;
  auto alloc = [&](size_t nbytes) {
    char* p = ws + off;
    off += (nbytes + 255) & ~(size_t)255;
    return p;
  };
  f16* CATF = (f16*)alloc((size_t)NB * NPIX * C2 * 2);
  u16* CBH = (u16*)alloc((size_t)NB * NPIX * C2 * 2);
  u16* CBL = (u16*)alloc((size_t)NB * NPIX * C2 * 2);
  u16* PH = (u16*)alloc((size_t)NB * 4096 * C2 * 2);
  u16* PL = (u16*)alloc((size_t)NB * 4096 * C2 * 2);
  float* A2 = (float*)alloc((size_t)4 * NB * 3844 * C2 * 4);   // 4 split-K partial planes, NHWC
  u16* OUT3H = (u16*)alloc((size_t)NB * NPIX * C2 * 2);
  u16* OUT3L = (u16*)alloc((size_t)NB * NPIX * C2 * 2);
  float* OF8P = (float*)alloc((size_t)8 * NB * 18 * NPIX * 4); // 8 split-K partial planes, NCHW
  float* OFFS = (float*)alloc((size_t)NB * 18 * NPIX * 4);
  f16* FEAT = (f16*)alloc((size_t)NB * NPIX * C1 * 2);
  f16* AL = (f16*)alloc((size_t)NB * NPIX * C1 * 2);
  float* Qb = (float*)alloc((size_t)NB * C1 * NPIX * 4);
  u16* W2K2 = (u16*)alloc((size_t)72 * 256 * 64 * 2);
  u16* W2K3 = (u16*)alloc((size_t)72 * 256 * 64 * 2);
  u16* W2K4 = (u16*)alloc((size_t)72 * 32 * 64 * 2);
  f16* WD = (f16*)alloc((size_t)128 * 160 * 2);
  f16* WQ = (f16*)alloc((size_t)128 * 128 * 2);
  f16* WPW = (f16*)alloc((size_t)128 * 128 * 2);
  f16* WKV = (f16*)alloc((size_t)256 * 128 * 2);
  f16* WPJ = (f16*)alloc((size_t)128 * 128 * 2);
  float* SACC = (float*)alloc((size_t)(NB * NHEADS * 256 + 512) * 4);
  float* QSS = SACC + NB * NHEADS * 256;
  float* KSS = QSS + 256;

  // region reuse
  float* QT1 = (float*)OUT3H;   // q 1x1 out, fp32 (dead before k3 writes OUT3)
  float* KV1 = (float*)CBH;     // kv 1x1 out, fp32, spans CBH+CBL (dead after k3)
  float* KVb = (float*)OUT3H;   // kv dw out, fp32, spans OUT3H+OUT3L (dead after k4/dgemm)
  f16* AO = FEAT;               // attn out (dead after pw)

  dim3 blk(256);

  // fused weight prep + SACC/QSS/KSS zero (one launch)
  wprep_all_k<<<dim3(5314), blk, 0, stream>>>(q_w, pw_w, kv_w, proj_w, dcn_w, k2_w, k3_w, k4_w,
                                              WQ, WPW, WKV, WPJ, WD, W2K2, W2K3, W2K4, SACC);

  // cat split: f16 (gathers/q) + bf16 hi/lo (conv head)
  splitcat_k<<<dim3(NPIX / 64, C2 / 64, NB), blk, 0, stream>>>(y, x, CATF, CBH, CBL);

  // q path: 1x1 MFMA on x-half of catf -> depthwise
  gemm1x1_k<C2, C1, false, false><<<dim3(NPIX / 128, 1, NB), blk, 0, stream>>>(
      CATF, WQ, nullptr, QT1, nullptr);
  dw3x3_k<<<dim3((NB * C1 * NPIX / 4 + 255) / 256), blk, 0, stream>>>(QT1, qd_w, Qb, C1);

  // offset head
  avgpool_b_k<<<dim3((NB * 4096 * 32 + 255) / 256), blk, 0, stream>>>(CBH, CBL, PH, PL);
  // k2: split-K=4, OCB=128; partials summed in k3's gate
  convmfma_k<128, 2, 4, 0, 62, 62, 64, 64, 0, 256, 256, false, true>
      <<<dim3(31, 8, NB), blk, 0, stream>>>(PH, PL, W2K2, nullptr, nullptr, nullptr,
                                            A2, (size_t)NB * 3844 * C2, nullptr, nullptr);
  // k3: full-K (at structure ceiling), gate reads y/x NCHW + 4 A2 partials
  convmfma_k<128, 2, 1, 4, 128, 128, 128, 128, 1, 256, 256, true, false>
      <<<dim3(128, 2, NB), blk, 0, stream>>>(CBH, CBL, W2K3, y, x, A2,
                                             nullptr, 0, OUT3H, OUT3L);
  // k4: split-K=8 -> partials -> reduce
  convmfma_k<32, 1, 8, 0, 128, 128, 128, 128, 1, 18, 32, false, false>
      <<<dim3(128, 8, NB), blk, 0, stream>>>(OUT3H, OUT3L, W2K4, nullptr, nullptr, nullptr,
                                             OF8P, (size_t)NB * 18 * NPIX, nullptr, nullptr);
  reduceN_k<8><<<dim3((NB * 18 * NPIX / 4 + 255) / 256), blk, 0, stream>>>(
      OF8P, OFFS, NB * 18 * NPIX / 4);

  // deformable alignment (gathers from y-half of catf) + pw 1x1
  dgemm_k<<<dim3(NPIX / 128, NG, NB), blk, 0, stream>>>(CATF, OFFS, WD, dcn_b, FEAT);
  gemm1x1_k<C1, 0, true, true><<<dim3(NPIX / 128, 1, NB), blk, 0, stream>>>(
      FEAT, WPW, pw_b, nullptr, AL);

  // kv path
  gemm1x1_k<C1, 0, false, false><<<dim3(NPIX / 128, 2, NB), blk, 0, stream>>>(
      AL, WKV, nullptr, KV1, nullptr);
  dw3x3_k<<<dim3((NB * C2 * NPIX / 4 + 255) / 256), blk, 0, stream>>>(KV1, kvd_w, KVb, C2);

  // attention: MFMA Gram + fused softmax/PV
  gram_k<<<dim3(8, NHEADS, NB), blk, 0, stream>>>(Qb, KVb, SACC, QSS, KSS);
  attnout_k<<<dim3(NPIX / 256, NHEADS, NB), blk, 0, stream>>>(SACC, QSS, KSS, temperature, KVb, AO);
  gemm1x1_k<C1, 0, false, false><<<dim3(NPIX / 128, 1, NB), blk, 0, stream>>>(
      AO, WPJ, nullptr, out, nullptr);
}

// Round 10
// 365.637 us; speedup vs baseline: 2.0535x; 1.0567x over previous
//
#include <hip/hip_runtime.h>
#include <math.h>

#define NB 2
#define C1 128
#define C2 256
#define HH 128
#define WW 128
#define NPIX (HH*WW)
#define NHEADS 8
#define DH 16
#define NG 8

typedef unsigned short u16;
typedef _Float16 f16;
typedef __attribute__((ext_vector_type(8))) _Float16 h8_t;
typedef __attribute__((ext_vector_type(4))) _Float16 h4_t;
typedef __attribute__((ext_vector_type(8))) short bf8_t;
typedef __attribute__((ext_vector_type(4))) float f4_t;

__device__ __forceinline__ float sigmoidf_(float v) { return 1.f / (1.f + expf(-v)); }
__device__ __forceinline__ u16 f2bf(float f) {
  unsigned u = __float_as_uint(f);
  return (u16)((u + 0x7FFFu + ((u >> 16) & 1u)) >> 16);
}
__device__ __forceinline__ float bf2f(u16 h) { return __uint_as_float(((unsigned)h) << 16); }

// ---------------- NCHW fp32 (y|x) -> NHWC: f16 cat + bf16 hi/lo cat ----------------
__global__ __launch_bounds__(256) void splitcat_k(const float* __restrict__ y,
                                                  const float* __restrict__ x,
                                                  f16* __restrict__ catf,
                                                  u16* __restrict__ cbh,
                                                  u16* __restrict__ cbl) {
  __shared__ float tile[64][65];
  int b = blockIdx.z, c0 = blockIdx.y * 64, p0 = blockIdx.x * 64;
  int tid = threadIdx.x;
  const float* src = (c0 < 128) ? y : x;
  int cc0 = c0 & 127;
  for (int e = tid; e < 4096; e += 256) {
    int c = e >> 6, p = e & 63;
    tile[c][p] = src[((size_t)b * C1 + cc0 + c) * NPIX + p0 + p];
  }
  __syncthreads();
  for (int e = tid; e < 4096; e += 256) {
    int p = e >> 6, c = e & 63;
    float v = tile[c][p];
    size_t o = ((size_t)b * NPIX + p0 + p) * C2 + c0 + c;
    catf[o] = (f16)v;
    u16 h = f2bf(v);
    cbh[o] = h;
    cbl[o] = f2bf(v - bf2f(h));
  }
}

// ---------------- avgpool2 on bf16-pair cat -> PH/PL [b][4096][256] ----------------
__global__ __launch_bounds__(256) void avgpool_b_k(const u16* __restrict__ cbh,
                                                   const u16* __restrict__ cbl,
                                                   u16* __restrict__ ph,
                                                   u16* __restrict__ pl) {
  int idx = blockIdx.x * 256 + threadIdx.x;
  if (idx >= NB * 4096 * 32) return;
  int c8 = idx & 31;
  int p = (idx >> 5) & 4095;
  int b = idx >> 17;
  int yo = p >> 6, xo = p & 63;
  size_t base = ((size_t)b * NPIX + (yo * 2) * WW + xo * 2) * C2 + c8 * 8;
  const size_t d01 = C2, d10 = (size_t)WW * C2, d11 = (size_t)WW * C2 + C2;
  bf8_t h00 = *(const bf8_t*)(cbh + base), l00 = *(const bf8_t*)(cbl + base);
  bf8_t h01 = *(const bf8_t*)(cbh + base + d01), l01 = *(const bf8_t*)(cbl + base + d01);
  bf8_t h10 = *(const bf8_t*)(cbh + base + d10), l10 = *(const bf8_t*)(cbl + base + d10);
  bf8_t h11 = *(const bf8_t*)(cbh + base + d11), l11 = *(const bf8_t*)(cbl + base + d11);
  bf8_t oh, ol;
#pragma unroll
  for (int j = 0; j < 8; j++) {
    float v00 = bf2f((u16)h00[j]) + bf2f((u16)l00[j]);
    float v01 = bf2f((u16)h01[j]) + bf2f((u16)l01[j]);
    float v10 = bf2f((u16)h10[j]) + bf2f((u16)l10[j]);
    float v11 = bf2f((u16)h11[j]) + bf2f((u16)l11[j]);
    float v = 0.25f * (v00 + v01 + v10 + v11);
    u16 h = f2bf(v);
    oh[j] = (short)h;
    ol[j] = (short)f2bf(v - bf2f(h));
  }
  size_t o = ((size_t)b * 4096 + p) * C2 + c8 * 8;
  *(bf8_t*)(ph + o) = oh;
  *(bf8_t*)(pl + o) = ol;
}

// ---------------- fused weight prep + accumulator zero (one launch) ----------------
__device__ __forceinline__ void wtrans_body(const float* __restrict__ w, u16* __restrict__ w2,
                                            int OC, int OCR, int idx) {
  int t = idx / (256 * OCR);
  int rem = idx - t * 256 * OCR;
  int ic = rem / OCR;
  int oc = rem - ic * OCR;
  float v = (oc < OC) ? w[((size_t)oc * 256 + ic) * 9 + t] : 0.f;
  u16 h = f2bf(v);
  u16 l = f2bf(v - bf2f(h));
  size_t row = (size_t)(t * 8 + (ic >> 5)) * OCR + oc;
  w2[row * 64 + (ic & 31)] = h;
  w2[row * 64 + 32 + (ic & 31)] = l;
}

__global__ __launch_bounds__(256) void wprep_all_k(
    const float* __restrict__ q_w, const float* __restrict__ pw_w,
    const float* __restrict__ kv_w, const float* __restrict__ proj_w,
    const float* __restrict__ dcn_w, const float* __restrict__ k2_w,
    const float* __restrict__ k3_w, const float* __restrict__ k4_w,
    f16* __restrict__ WQ, f16* __restrict__ WPW, f16* __restrict__ WKV,
    f16* __restrict__ WPJ, f16* __restrict__ WD,
    u16* __restrict__ W2K2, u16* __restrict__ W2K3, u16* __restrict__ W2K4,
    float* __restrict__ sacc) {
  int idx = blockIdx.x * 256 + threadIdx.x;
  if (idx < 16384) { WQ[idx] = (f16)q_w[idx]; return; }
  idx -= 16384;
  if (idx < 16384) { WPW[idx] = (f16)pw_w[idx]; return; }
  idx -= 16384;
  if (idx < 32768) { WKV[idx] = (f16)kv_w[idx]; return; }
  idx -= 32768;
  if (idx < 16384) { WPJ[idx] = (f16)proj_w[idx]; return; }
  idx -= 16384;
  if (idx < 20480) {
    int oc = idx / 160, k = idx - oc * 160;
    int t = k >> 4, ic = k & 15;
    WD[idx] = (t < 9) ? (f16)dcn_w[((size_t)oc * 16 + ic) * 9 + t] : (f16)0.f;
    return;
  }
  idx -= 20480;
  if (idx < 589824) { wtrans_body(k2_w, W2K2, 256, 256, idx); return; }
  idx -= 589824;
  if (idx < 589824) { wtrans_body(k3_w, W2K3, 256, 256, idx); return; }
  idx -= 589824;
  if (idx < 73728) { wtrans_body(k4_w, W2K4, 18, 32, idx); return; }
  idx -= 73728;
  if (idx < 4608) sacc[idx] = 0.f;
}

// ---------------- implicit-GEMM 3x3 conv, bf16 hi/lo 3-product, dbuf, split-K ----------------
template<int OCB, int NPAN, int SPLITK, int NGB, int WO, int HO, int WI, int HI, int PAD,
         int OCTOT, int OCR, bool GATE, bool OUTF_NHWC>
__global__ __launch_bounds__(256) void convmfma_k(
    const u16* __restrict__ inH, const u16* __restrict__ inL,
    const u16* __restrict__ w2,
    const float* __restrict__ gy, const float* __restrict__ gx,
    const float* __restrict__ gB,
    float* __restrict__ outFp, size_t pstride,
    u16* __restrict__ outH, u16* __restrict__ outL) {
  constexpr int CIN = 256;
  constexpr int MF = (OCB == 128) ? 4 : 2;
  constexpr int NF = (OCB == 128) ? 4 : 2;
  constexpr int GCN = 72 / SPLITK;
  __shared__ u16 lds_a[2][128 * 64];
  __shared__ u16 lds_w[2][OCB * 64];
  const int b = blockIdx.z;
  const int oc0 = (blockIdx.y % NPAN) * OCB;
  const int kz = blockIdx.y / NPAN;
  const int gbase = kz * GCN;
  float* outF = outFp + (size_t)kz * pstride;
  const int px0 = blockIdx.x * 128;
  const int tid = threadIdx.x;
  const int lane = tid & 63, wid = tid >> 6;
  const int wpx = (OCB == 128) ? ((wid >> 1) * 64) : (wid * 32);
  const int woc = (OCB == 128) ? ((wid & 1) * 64) : 0;

  const int spx = tid >> 1;
  const int shalf = tid & 1;
  const int opx = px0 + spx;
  const int py = opx / WO, pxx = opx % WO;
  const bool prow_ok = (opx < HO * WO);
  const int ar7 = spx & 7;
  const int awo0 = spx * 128 + (((shalf * 2 + 0) ^ ar7) << 4);
  const int awo1 = spx * 128 + (((shalf * 2 + 1) ^ ar7) << 4);
  const int awo2 = spx * 128 + (((shalf * 2 + 4) ^ ar7) << 4);
  const int awo3 = spx * 128 + (((shalf * 2 + 5) ^ ar7) << 4);
  const bool wact = (OCB == 128) ? true : (tid < OCB * 2);
  const int wrow = tid >> 1, whalf = tid & 1;
  int wwo[4];
#pragma unroll
  for (int j = 0; j < 4; j++) wwo[j] = wrow * 128 + (((whalf * 4 + j) ^ (wrow & 7)) << 4);

  int aoh[MF], aol[MF], woh[NF], wol[NF];
#pragma unroll
  for (int mf = 0; mf < MF; mf++) {
    int r = wpx + mf * 16 + (lane & 15);
    int s = lane >> 4;
    aoh[mf] = r * 128 + ((s ^ (r & 7)) << 4);
    aol[mf] = r * 128 + (((s + 4) ^ (r & 7)) << 4);
  }
#pragma unroll
  for (int nf = 0; nf < NF; nf++) {
    int r = woc + nf * 16 + (lane & 15);
    int s = lane >> 4;
    woh[nf] = r * 128 + ((s ^ (r & 7)) << 4);
    wol[nf] = r * 128 + (((s + 4) ^ (r & 7)) << 4);
  }

  f4_t acc[MF][NF];
#pragma unroll
  for (int mf = 0; mf < MF; mf++)
#pragma unroll
    for (int nf = 0; nf < NF; nf++) { f4_t z = {0.f, 0.f, 0.f, 0.f}; acc[mf][nf] = z; }

  const size_t inb = (size_t)b * (HI * WI) * CIN;
  const size_t wg0 = (size_t)(oc0 + wrow) * 64 + (size_t)whalf * 32;
  uint4 rah0, rah1, ral0, ral1, rwv0, rwv1, rwv2, rwv3;

  auto load_gc = [&](int gc) {
    const int t = gc >> 3, c = gc & 7;
    const int iy = py + (t / 3) - PAD;
    const int ix = pxx + (t % 3) - PAD;
    const bool val = prow_ok && iy >= 0 && iy < HI && ix >= 0 && ix < WI;
    uint4 z = {0, 0, 0, 0};
    rah0 = z; rah1 = z; ral0 = z; ral1 = z;
    if (val) {
      size_t a0 = inb + (size_t)(iy * WI + ix) * CIN + c * 32 + shalf * 16;
      const uint4* ph = (const uint4*)(inH + a0);
      const uint4* pl = (const uint4*)(inL + a0);
      rah0 = ph[0]; rah1 = ph[1]; ral0 = pl[0]; ral1 = pl[1];
    }
    if (wact) {
      const uint4* q = (const uint4*)(w2 + (size_t)gc * OCR * 64 + wg0);
      rwv0 = q[0]; rwv1 = q[1]; rwv2 = q[2]; rwv3 = q[3];
    }
  };
  auto store_gc = [&](int nb) {
    char* la = (char*)lds_a[nb];
    char* lw = (char*)lds_w[nb];
    *(uint4*)(la + awo0) = rah0;
    *(uint4*)(la + awo1) = rah1;
    *(uint4*)(la + awo2) = ral0;
    *(uint4*)(la + awo3) = ral1;
    if (wact) {
      *(uint4*)(lw + wwo[0]) = rwv0;
      *(uint4*)(lw + wwo[1]) = rwv1;
      *(uint4*)(lw + wwo[2]) = rwv2;
      *(uint4*)(lw + wwo[3]) = rwv3;
    }
  };

  load_gc(gbase);
  store_gc(0);
  __syncthreads();
  for (int i = 0; i < GCN; ++i) {
    const int cb = i & 1;
    if (i < GCN - 1) load_gc(gbase + i + 1);
    const char* la = (const char*)lds_a[cb];
    const char* lw = (const char*)lds_w[cb];
    bf8_t ah[MF], al[MF], wh[NF], wl[NF];
#pragma unroll
    for (int mf = 0; mf < MF; mf++) {
      ah[mf] = *(const bf8_t*)(la + aoh[mf]);
      al[mf] = *(const bf8_t*)(la + aol[mf]);
    }
#pragma unroll
    for (int nf = 0; nf < NF; nf++) {
      wh[nf] = *(const bf8_t*)(lw + woh[nf]);
      wl[nf] = *(const bf8_t*)(lw + wol[nf]);
    }
#pragma unroll
    for (int mf = 0; mf < MF; mf++)
#pragma unroll
      for (int nf = 0; nf < NF; nf++) {
        acc[mf][nf] = __builtin_amdgcn_mfma_f32_16x16x32_bf16(ah[mf], wh[nf], acc[mf][nf], 0, 0, 0);
        acc[mf][nf] = __builtin_amdgcn_mfma_f32_16x16x32_bf16(al[mf], wh[nf], acc[mf][nf], 0, 0, 0);
        acc[mf][nf] = __builtin_amdgcn_mfma_f32_16x16x32_bf16(ah[mf], wl[nf], acc[mf][nf], 0, 0, 0);
      }
    if (i < GCN - 1) store_gc(cb ^ 1);
    __syncthreads();
  }

  // epilogue: D row=(lane>>4)*4+r = px, col=lane&15 = oc  [m89-verified]
#pragma unroll
  for (int mf = 0; mf < MF; mf++) {
    const int pxb = px0 + wpx + mf * 16 + ((lane >> 4) << 2);
#pragma unroll
    for (int nf = 0; nf < NF; nf++) {
      const int oc = oc0 + woc + nf * 16 + (lane & 15);
      if (GATE) {
        const float* gp = (oc < 128) ? gy : gx;
        const size_t gbse = ((size_t)b * C1 + (oc & 127)) * NPIX;
        constexpr size_t gstride = (size_t)NB * 3844 * C2;
#pragma unroll
        for (int r = 0; r < 4; r++) {
          const int px = pxb + r;
          const int pyy = px >> 7, px2 = px & 127;
          const int iiy = (pyy * 62) >> 7, iix = (px2 * 62) >> 7;
          const size_t gi = ((size_t)b * 3844 + iiy * 62 + iix) * 256 + oc;
          float gv = gp[gbse + px];
#pragma unroll
          for (int pp = 0; pp < NGB; pp++) gv += gB[gi + (size_t)pp * gstride];
          float v = acc[mf][nf][r] * sigmoidf_(gv);
          u16 h = f2bf(v);
          size_t o = ((size_t)b * NPIX + px) * C2 + oc;
          outH[o] = h;
          outL[o] = f2bf(v - bf2f(h));
        }
      } else if (OUTF_NHWC) {
        if (oc < OCTOT) {
#pragma unroll
          for (int r = 0; r < 4; r++) {
            const int px = pxb + r;
            if (px < HO * WO)
              outF[((size_t)b * (HO * WO) + px) * OCTOT + oc] = acc[mf][nf][r];
          }
        }
      } else {
        if (pxb < HO * WO && oc < OCTOT)
          *(f4_t*)&outF[((size_t)b * OCTOT + oc) * (HO * WO) + pxb] = acc[mf][nf];
      }
    }
  }
}

// ---------------- sum NP split-K partial planes ----------------
template<int NP>
__global__ __launch_bounds__(256) void reduceN_k(const float* __restrict__ p,
                                                 float* __restrict__ o, int n4) {
  int i = blockIdx.x * 256 + threadIdx.x;
  if (i >= n4) return;
  const f4_t* v = (const f4_t*)p;
  f4_t r = v[i];
#pragma unroll
  for (int k = 1; k < NP; k++) {
    f4_t a = v[i + (size_t)k * n4];
    r[0] += a[0]; r[1] += a[1]; r[2] += a[2]; r[3] += a[3];
  }
  ((f4_t*)o)[i] = r;
}

// ---------------- 1x1 conv as fp16 MFMA GEMM, direct-global fragments ----------------
// OUTM: 0 = fp32 NCHW, 1 = f16 NHWC[128], 2 = f16 NCHW
template<int AS, int AOFF, bool BIAS, int OUTM>
__global__ __launch_bounds__(256) void gemm1x1_k(const f16* __restrict__ inA,
                                                 const f16* __restrict__ w,
                                                 const float* __restrict__ bias,
                                                 float* __restrict__ outF,
                                                 f16* __restrict__ outH) {
  const int b = blockIdx.z, nb0 = blockIdx.y * 128, px0 = blockIdx.x * 128;
  const int CoutTot = gridDim.y * 128;
  const int tid = threadIdx.x, lane = tid & 63, wid = tid >> 6;
  const int wpx = px0 + wid * 32;
  const int kslot = (lane >> 4) * 8;

  f4_t acc[2][8];
#pragma unroll
  for (int mf = 0; mf < 2; mf++)
#pragma unroll
    for (int nf = 0; nf < 8; nf++) { f4_t z = {0.f, 0.f, 0.f, 0.f}; acc[mf][nf] = z; }

  size_t arow[2];
#pragma unroll
  for (int mf = 0; mf < 2; mf++)
    arow[mf] = ((size_t)b * NPIX + wpx + mf * 16 + (lane & 15)) * AS + AOFF;
  size_t wrow[8];
#pragma unroll
  for (int nf = 0; nf < 8; nf++)
    wrow[nf] = (size_t)(nb0 + nf * 16 + (lane & 15)) * 128;

#pragma unroll
  for (int ks = 0; ks < 4; ks++) {
    const int ko = ks * 32 + kslot;
    h8_t a[2], bw[8];
#pragma unroll
    for (int mf = 0; mf < 2; mf++) a[mf] = *(const h8_t*)(inA + arow[mf] + ko);
#pragma unroll
    for (int nf = 0; nf < 8; nf++) bw[nf] = *(const h8_t*)(w + wrow[nf] + ko);
#pragma unroll
    for (int mf = 0; mf < 2; mf++)
#pragma unroll
      for (int nf = 0; nf < 8; nf++)
        acc[mf][nf] = __builtin_amdgcn_mfma_f32_16x16x32_f16(a[mf], bw[nf], acc[mf][nf], 0, 0, 0);
  }

#pragma unroll
  for (int mf = 0; mf < 2; mf++) {
    const int pxq = wpx + mf * 16 + (lane >> 4) * 4;
#pragma unroll
    for (int nf = 0; nf < 8; nf++) {
      const int oc = nb0 + nf * 16 + (lane & 15);
      f4_t v = acc[mf][nf];
      if (BIAS) {
        float bv = bias[oc];
        v[0] += bv; v[1] += bv; v[2] += bv; v[3] += bv;
      }
      if (OUTM == 1) {
#pragma unroll
        for (int r = 0; r < 4; r++)
          outH[((size_t)b * NPIX + pxq + r) * 128 + oc] = (f16)v[r];
      } else if (OUTM == 2) {
        h4_t o;
#pragma unroll
        for (int r = 0; r < 4; r++) o[r] = (f16)v[r];
        *(h4_t*)&outH[((size_t)b * CoutTot + oc) * NPIX + pxq] = o;
      } else {
        *(f4_t*)&outF[((size_t)b * CoutTot + oc) * NPIX + pxq] = v;
      }
    }
  }
}

// ---------------- fused modulated-deform-conv: NHWC f16 gather + grouped MFMA ----------------
__global__ __launch_bounds__(256) void dgemm_k(const f16* __restrict__ catf,
                                               const float* __restrict__ offs,
                                               const f16* __restrict__ wd,
                                               const float* __restrict__ dbias,
                                               f16* __restrict__ feat) {
  const int b = blockIdx.z, g = blockIdx.y;
  const int px0 = blockIdx.x * 128;
  const int tid = threadIdx.x;
  const int lane = tid & 63, wid = tid >> 6;
  const int chunk = lane >> 4;
  const int thalf = chunk >> 1;
  const int ic0 = (chunk & 1) * 8;
  const f16* yb = catf + (size_t)b * NPIX * C2;  // channels 0..127 of cat = y
  const float* ob = offs + (size_t)b * 18 * NPIX;

  int pm[2];
  float pyb[2], pxb2[2];
#pragma unroll
  for (int mf = 0; mf < 2; mf++) {
    pm[mf] = px0 + wid * 32 + mf * 16 + (lane & 15);
    pyb[mf] = (float)(pm[mf] >> 7);
    pxb2[mf] = (float)(pm[mf] & 127);
  }

  f4_t acc[2];
  { f4_t z = {0.f, 0.f, 0.f, 0.f}; acc[0] = z; acc[1] = z; }

  const size_t wbase = (size_t)(g * 16 + (lane & 15)) * 160;
#pragma unroll
  for (int s = 0; s < 5; s++) {
    h8_t ah[2];
#pragma unroll
    for (int mf = 0; mf < 2; mf++) {
      int t = 2 * s + thalf;
      int teff = t > 8 ? 8 : t;
      float dy = ob[(size_t)(2 * teff) * NPIX + pm[mf]];
      float dx = ob[(size_t)(2 * teff + 1) * NPIX + pm[mf]];
      float mk = sigmoidf_(ob[(size_t)teff * NPIX + pm[mf]]);
      int ky = teff / 3, kx = teff - 3 * ky;
      float pyf = pyb[mf] - 1.f + (float)ky + dy;
      float pxf = pxb2[mf] - 1.f + (float)kx + dx;
      float y0f = floorf(pyf), x0f = floorf(pxf);
      float fy = pyf - y0f, fx = pxf - x0f;
      int y0 = (int)y0f, x0 = (int)x0f;
      int y1 = y0 + 1, x1 = x0 + 1;
      float w00 = (1.f - fy) * (1.f - fx) * mk;
      float w01 = (1.f - fy) * fx * mk;
      float w10 = fy * (1.f - fx) * mk;
      float w11 = fy * fx * mk;
      bool vy0 = (y0 >= 0 && y0 < HH), vy1 = (y1 >= 0 && y1 < HH);
      bool vx0 = (x0 >= 0 && x0 < WW), vx1 = (x1 >= 0 && x1 < WW);
      if (!(vy0 && vx0)) w00 = 0.f;
      if (!(vy0 && vx1)) w01 = 0.f;
      if (!(vy1 && vx0)) w10 = 0.f;
      if (!(vy1 && vx1)) w11 = 0.f;
      int cy0 = min(max(y0, 0), HH - 1), cy1 = min(max(y1, 0), HH - 1);
      int cx0 = min(max(x0, 0), WW - 1), cx1 = min(max(x1, 0), WW - 1);
      const f16* p00 = yb + (size_t)(cy0 * WW + cx0) * C2 + g * 16 + ic0;
      const f16* p01 = yb + (size_t)(cy0 * WW + cx1) * C2 + g * 16 + ic0;
      const f16* p10 = yb + (size_t)(cy1 * WW + cx0) * C2 + g * 16 + ic0;
      const f16* p11 = yb + (size_t)(cy1 * WW + cx1) * C2 + g * 16 + ic0;
      h8_t a00 = *(const h8_t*)p00;
      h8_t a01 = *(const h8_t*)p01;
      h8_t a10 = *(const h8_t*)p10;
      h8_t a11 = *(const h8_t*)p11;
      h8_t hh;
#pragma unroll
      for (int j = 0; j < 8; j++) {
        float sv = w00 * (float)a00[j] + w01 * (float)a01[j] +
                   w10 * (float)a10[j] + w11 * (float)a11[j];
        hh[j] = (f16)sv;
      }
      ah[mf] = hh;
    }
    h8_t wv = *(const h8_t*)(wd + wbase + s * 32 + chunk * 8);
#pragma unroll
    for (int mf = 0; mf < 2; mf++)
      acc[mf] = __builtin_amdgcn_mfma_f32_16x16x32_f16(ah[mf], wv, acc[mf], 0, 0, 0);
  }

  const int oc = g * 16 + (lane & 15);
  const float bv = dbias[oc];
#pragma unroll
  for (int mf = 0; mf < 2; mf++) {
    const int pxq = px0 + wid * 32 + mf * 16 + (lane >> 4) * 4;
#pragma unroll
    for (int r = 0; r < 4; r++) {
      float v = fmaxf(acc[mf][r] + bv, 0.f);  // bias + relu (pw input)
      feat[((size_t)b * NPIX + pxq + r) * 128 + oc] = (f16)v;
    }
  }
}

// ---------------- depthwise 3x3, pad=1, f16 NCHW in/out, x8 vectorized ----------------
__global__ __launch_bounds__(256) void dw3x3h_k(const f16* __restrict__ in,
                                                const float* __restrict__ w,
                                                f16* __restrict__ out, int Cc) {
  int i8 = blockIdx.x * 256 + threadIdx.x;
  int total8 = NB * Cc * (NPIX / 8);
  if (i8 >= total8) return;
  int n8 = i8 & (NPIX / 8 - 1);
  int bc = i8 >> 11;               // NPIX/8 = 2048 = 2^11
  int c = bc % Cc;
  int n = n8 << 3;
  int yy = n >> 7, xx = n & 127;   // xx multiple of 8
  const f16* p = in + (size_t)bc * NPIX;
  const float* wc = w + c * 9;
  float acc[8] = {0.f, 0.f, 0.f, 0.f, 0.f, 0.f, 0.f, 0.f};
#pragma unroll
  for (int ky = 0; ky < 3; ky++) {
    int iy = yy + ky - 1;
    if (iy < 0 || iy >= HH) continue;
    const f16* row = p + iy * WW;
    float v[10];
    v[0] = (xx > 0) ? (float)row[xx - 1] : 0.f;
    h8_t m = *(const h8_t*)(row + xx);
#pragma unroll
    for (int j = 0; j < 8; j++) v[j + 1] = (float)m[j];
    v[9] = (xx + 8 < WW) ? (float)row[xx + 8] : 0.f;
#pragma unroll
    for (int kx = 0; kx < 3; kx++) {
      float wv = wc[ky * 3 + kx];
#pragma unroll
      for (int j = 0; j < 8; j++) acc[j] += wv * v[j + kx];
    }
  }
  h8_t o;
#pragma unroll
  for (int j = 0; j < 8; j++) o[j] = (f16)acc[j];
  *(h8_t*)&out[(size_t)bc * NPIX + n] = o;
}

// ---------------- attention Gram (Q·K^T 16x16 over N=16384) via fp16 MFMA ----------------
// grid (8, NHEADS, NB), 4 waves; wave handles one 512-wide n-segment.
__global__ __launch_bounds__(256) void gram_k(const f16* __restrict__ qbuf,
                                              const f16* __restrict__ kvbuf,
                                              float* __restrict__ s_acc,
                                              float* __restrict__ qss,
                                              float* __restrict__ kss) {
  int b = blockIdx.z, h = blockIdx.y;
  int tid = threadIdx.x, lane = tid & 63, wid = tid >> 6;
  int r = lane & 15, ks = lane >> 4;
  const f16* qb = qbuf + ((size_t)b * C1 + h * DH + r) * NPIX;
  const f16* kb = kvbuf + ((size_t)b * C2 + h * DH + r) * NPIX;
  int n0 = (blockIdx.x * 4 + wid) * 512;
  f4_t acc = {0.f, 0.f, 0.f, 0.f};
  float q2 = 0.f, k2 = 0.f;
  for (int s = 0; s < 16; s++) {
    int k = n0 + s * 32 + ks * 8;
    h8_t qv = *(const h8_t*)(qb + k);
    h8_t kv = *(const h8_t*)(kb + k);
#pragma unroll
    for (int j = 0; j < 8; j++) {
      float qf = (float)qv[j], kf = (float)kv[j];
      q2 += qf * qf;
      k2 += kf * kf;
    }
    acc = __builtin_amdgcn_mfma_f32_16x16x32_f16(qv, kv, acc, 0, 0, 0);
  }
  int bh = b * NHEADS + h;
  // D: row (cq) = ks*4 + rr, col (ck) = r
#pragma unroll
  for (int rr = 0; rr < 4; rr++)
    atomicAdd(&s_acc[((size_t)bh * 16 + ks * 4 + rr) * 16 + r], acc[rr]);
  q2 += __shfl_xor(q2, 16);
  q2 += __shfl_xor(q2, 32);
  k2 += __shfl_xor(k2, 16);
  k2 += __shfl_xor(k2, 32);
  if (ks == 0) {
    atomicAdd(&qss[bh * 16 + r], q2);
    atomicAdd(&kss[bh * 16 + r], k2);
  }
}

// ---------------- attention: fused softmax + (attn @ v) -> NHWC f16 ----------------
__global__ __launch_bounds__(256) void attnout_k(const float* __restrict__ s_acc,
                                                 const float* __restrict__ qss,
                                                 const float* __restrict__ kss,
                                                 const float* __restrict__ temp,
                                                 const f16* __restrict__ kvbuf,
                                                 f16* __restrict__ outA) {
  __shared__ float S[16][17];
  __shared__ float A[16][17];
  __shared__ float qn[16], kn[16];
  int b = blockIdx.z, h = blockIdx.y;
  int tid = threadIdx.x;
  int bh = b * NHEADS + h;
  int dd = tid & 15, cc = tid >> 4;
  if (tid < 16) {
    qn[tid] = fmaxf(sqrtf(qss[bh * 16 + tid]), 1e-12f);
    kn[tid] = fmaxf(sqrtf(kss[bh * 16 + tid]), 1e-12f);
  }
  __syncthreads();
  float t = temp[h];
  float s = s_acc[((size_t)bh * 16 + cc) * 16 + dd] / (qn[cc] * kn[dd]) * t;
  S[cc][dd] = s;
  __syncthreads();
  float mx = -1e30f;
#pragma unroll
  for (int j = 0; j < 16; j++) mx = fmaxf(mx, S[cc][j]);
  float sum = 0.f;
#pragma unroll
  for (int j = 0; j < 16; j++) sum += expf(S[cc][j] - mx);
  A[cc][dd] = expf(s - mx) / sum;
  __syncthreads();

  int n = blockIdx.x * 256 + tid;
  const f16* vb = kvbuf + ((size_t)b * C2 + C1 + h * DH) * NPIX;
  float acc[16];
#pragma unroll
  for (int c = 0; c < 16; c++) acc[c] = 0.f;
#pragma unroll
  for (int d = 0; d < 16; d++) {
    float vv = (float)vb[(size_t)d * NPIX + n];
#pragma unroll
    for (int c = 0; c < 16; c++) acc[c] += A[c][d] * vv;
  }
  h8_t o0, o1;
#pragma unroll
  for (int c = 0; c < 8; c++) {
    o0[c] = (f16)acc[c];
    o1[c] = (f16)acc[8 + c];
  }
  size_t base = ((size_t)b * NPIX + n) * 128 + h * 16;
  *(h8_t*)(outA + base) = o0;
  *(h8_t*)(outA + base + 8) = o1;
}

extern "C" void kernel_launch(void* const* d_in, const int* in_sizes, int n_in,
                              void* d_out, int out_size, void* d_ws, size_t ws_size,
                              hipStream_t stream) {
  const float* x = (const float*)d_in[0];
  const float* y = (const float*)d_in[1];
  const float* q_w = (const float*)d_in[2];
  const float* qd_w = (const float*)d_in[3];
  const float* kv_w = (const float*)d_in[4];
  const float* kvd_w = (const float*)d_in[5];
  const float* proj_w = (const float*)d_in[6];
  const float* temperature = (const float*)d_in[7];
  const float* k2_w = (const float*)d_in[8];
  const float* k3_w = (const float*)d_in[9];
  const float* k4_w = (const float*)d_in[10];
  const float* dcn_w = (const float*)d_in[11];
  const float* dcn_b = (const float*)d_in[12];
  const float* pw_w = (const float*)d_in[13];
  const float* pw_b = (const float*)d_in[14];
  float* out = (float*)d_out;

  char* ws = (char*)d_ws;
  size_t off = 0;
  auto alloc = [&](size_t nbytes) {
    char* p = ws + off;
    off += (nbytes + 255) & ~(size_t)255;
    return p;
  };
  f16* CATF = (f16*)alloc((size_t)NB * NPIX * C2 * 2);
  u16* CBH = (u16*)alloc((size_t)NB * NPIX * C2 * 2);
  u16* CBL = (u16*)alloc((size_t)NB * NPIX * C2 * 2);
  u16* PH = (u16*)alloc((size_t)NB * 4096 * C2 * 2);
  u16* PL = (u16*)alloc((size_t)NB * 4096 * C2 * 2);
  float* A2 = (float*)alloc((size_t)4 * NB * 3844 * C2 * 4);   // 4 split-K partial planes, NHWC
  u16* OUT3H = (u16*)alloc((size_t)NB * NPIX * C2 * 2);
  u16* OUT3L = (u16*)alloc((size_t)NB * NPIX * C2 * 2);
  float* OF8P = (float*)alloc((size_t)8 * NB * 18 * NPIX * 4); // 8 split-K partial planes, NCHW
  float* OFFS = (float*)alloc((size_t)NB * 18 * NPIX * 4);
  f16* FEAT = (f16*)alloc((size_t)NB * NPIX * C1 * 2);
  f16* AL = (f16*)alloc((size_t)NB * NPIX * C1 * 2);
  f16* QbH = (f16*)alloc((size_t)NB * C1 * NPIX * 2);
  u16* W2K2 = (u16*)alloc((size_t)72 * 256 * 64 * 2);
  u16* W2K3 = (u16*)alloc((size_t)72 * 256 * 64 * 2);
  u16* W2K4 = (u16*)alloc((size_t)72 * 32 * 64 * 2);
  f16* WD = (f16*)alloc((size_t)128 * 160 * 2);
  f16* WQ = (f16*)alloc((size_t)128 * 128 * 2);
  f16* WPW = (f16*)alloc((size_t)128 * 128 * 2);
  f16* WKV = (f16*)alloc((size_t)256 * 128 * 2);
  f16* WPJ = (f16*)alloc((size_t)128 * 128 * 2);
  float* SACC = (float*)alloc((size_t)(NB * NHEADS * 256 + 512) * 4);
  float* QSS = SACC + NB * NHEADS * 256;
  float* KSS = QSS + 256;

  // region reuse (lifetimes)
  f16* QT1H = (f16*)OUT3H;      // q 1x1 out, f16 NCHW (dead before k3 writes OUT3)
  f16* KV1H = (f16*)CBH;        // kv 1x1 out, f16 NCHW (CBH dead after k3)
  f16* KVbH = (f16*)OUT3H;      // kv dw out, f16 NCHW (OUT3 dead after k4)
  f16* AO = FEAT;               // attn out (FEAT dead after pw)

  dim3 blk(256);

  // fused weight prep + SACC/QSS/KSS zero (one launch)
  wprep_all_k<<<dim3(5314), blk, 0, stream>>>(q_w, pw_w, kv_w, proj_w, dcn_w, k2_w, k3_w, k4_w,
                                              WQ, WPW, WKV, WPJ, WD, W2K2, W2K3, W2K4, SACC);

  // cat split: f16 (gathers/q) + bf16 hi/lo (conv head)
  splitcat_k<<<dim3(NPIX / 64, C2 / 64, NB), blk, 0, stream>>>(y, x, CATF, CBH, CBL);

  // q path: 1x1 MFMA on x-half of catf -> depthwise (all f16)
  gemm1x1_k<C2, C1, false, 2><<<dim3(NPIX / 128, 1, NB), blk, 0, stream>>>(
      CATF, WQ, nullptr, nullptr, QT1H);
  dw3x3h_k<<<dim3(NB * C1 * (NPIX / 8) / 256), blk, 0, stream>>>(QT1H, qd_w, QbH, C1);

  // offset head
  avgpool_b_k<<<dim3((NB * 4096 * 32 + 255) / 256), blk, 0, stream>>>(CBH, CBL, PH, PL);
  convmfma_k<128, 2, 4, 0, 62, 62, 64, 64, 0, 256, 256, false, true>
      <<<dim3(31, 8, NB), blk, 0, stream>>>(PH, PL, W2K2, nullptr, nullptr, nullptr,
                                            A2, (size_t)NB * 3844 * C2, nullptr, nullptr);
  convmfma_k<128, 2, 1, 4, 128, 128, 128, 128, 1, 256, 256, true, false>
      <<<dim3(128, 2, NB), blk, 0, stream>>>(CBH, CBL, W2K3, y, x, A2,
                                             nullptr, 0, OUT3H, OUT3L);
  convmfma_k<32, 1, 8, 0, 128, 128, 128, 128, 1, 18, 32, false, false>
      <<<dim3(128, 8, NB), blk, 0, stream>>>(OUT3H, OUT3L, W2K4, nullptr, nullptr, nullptr,
                                             OF8P, (size_t)NB * 18 * NPIX, nullptr, nullptr);
  reduceN_k<8><<<dim3((NB * 18 * NPIX / 4 + 255) / 256), blk, 0, stream>>>(
      OF8P, OFFS, NB * 18 * NPIX / 4);

  // deformable alignment (gathers from y-half of catf) + pw 1x1
  dgemm_k<<<dim3(NPIX / 128, NG, NB), blk, 0, stream>>>(CATF, OFFS, WD, dcn_b, FEAT);
  gemm1x1_k<C1, 0, true, 1><<<dim3(NPIX / 128, 1, NB), blk, 0, stream>>>(
      FEAT, WPW, pw_b, nullptr, AL);

  // kv path (all f16)
  gemm1x1_k<C1, 0, false, 2><<<dim3(NPIX / 128, 2, NB), blk, 0, stream>>>(
      AL, WKV, nullptr, nullptr, KV1H);
  dw3x3h_k<<<dim3(NB * C2 * (NPIX / 8) / 256), blk, 0, stream>>>(KV1H, kvd_w, KVbH, C2);

  // attention: fp16 MFMA Gram + fused softmax/PV
  gram_k<<<dim3(8, NHEADS, NB), blk, 0, stream>>>(QbH, KVbH, SACC, QSS, KSS);
  attnout_k<<<dim3(NPIX / 256, NHEADS, NB), blk, 0, stream>>>(SACC, QSS, KSS, temperature, KVbH, AO);
  gemm1x1_k<C1, 0, false, 0><<<dim3(NPIX / 128, 1, NB), blk, 0, stream>>>(
      AO, WPJ, nullptr, out, nullptr);
}

// Round 11
// 364.405 us; speedup vs baseline: 2.0604x; 1.0034x over previous
//
#include <hip/hip_runtime.h>
#include <math.h>

#define NB 2
#define C1 128
#define C2 256
#define HH 128
#define WW 128
#define NPIX (HH*WW)
#define NHEADS 8
#define DH 16
#define NG 8

typedef unsigned short u16;
typedef _Float16 f16;
typedef __attribute__((ext_vector_type(8))) _Float16 h8_t;
typedef __attribute__((ext_vector_type(4))) _Float16 h4_t;
typedef __attribute__((ext_vector_type(8))) short bf8_t;
typedef __attribute__((ext_vector_type(4))) float f4_t;

__device__ __forceinline__ float sigmoidf_(float v) { return 1.f / (1.f + expf(-v)); }
__device__ __forceinline__ u16 f2bf(float f) {
  unsigned u = __float_as_uint(f);
  return (u16)((u + 0x7FFFu + ((u >> 16) & 1u)) >> 16);
}
__device__ __forceinline__ float bf2f(u16 h) { return __uint_as_float(((unsigned)h) << 16); }

// ---- NCHW fp32 (y|x) -> NHWC f16 cat + bf16 hi/lo cat + fused 2x2 avgpool ----
// Block: 2 rows x 128 cols (256 consecutive px) x 32 channels. p-major LDS, pad 33.
__global__ __launch_bounds__(256) void splitcat2_k(const float* __restrict__ y,
                                                   const float* __restrict__ x,
                                                   f16* __restrict__ catf,
                                                   u16* __restrict__ cbh,
                                                   u16* __restrict__ cbl,
                                                   u16* __restrict__ ph,
                                                   u16* __restrict__ pl) {
  __shared__ float tile[256][33];
  int b = blockIdx.z, c0 = blockIdx.y * 32, rp = blockIdx.x;
  int tid = threadIdx.x;
  const float* src = (c0 < 128) ? y : x;
  int cc0 = c0 & 127;
  const int pbase = rp * 256;
  for (int e = tid; e < 8192; e += 256) {
    int c = e >> 8, p = e & 255;
    tile[p][c] = src[((size_t)b * C1 + cc0 + c) * NPIX + pbase + p];
  }
  __syncthreads();
  for (int e = tid; e < 8192; e += 256) {
    int p = e >> 5, c = e & 31;
    float v = tile[p][c];
    size_t o = ((size_t)b * NPIX + pbase + p) * C2 + c0 + c;
    catf[o] = (f16)v;
    u16 h = f2bf(v);
    cbh[o] = h;
    cbl[o] = f2bf(v - bf2f(h));
  }
  for (int e = tid; e < 2048; e += 256) {
    int pp = e >> 5, c = e & 31;
    float v = 0.25f * (tile[2 * pp][c] + tile[2 * pp + 1][c] +
                       tile[128 + 2 * pp][c] + tile[128 + 2 * pp + 1][c]);
    u16 h = f2bf(v);
    size_t o = ((size_t)b * 4096 + rp * 64 + pp) * C2 + c0 + c;
    ph[o] = h;
    pl[o] = f2bf(v - bf2f(h));
  }
}

// ---------------- fused weight prep + accumulator zero (one launch) ----------------
__device__ __forceinline__ void wtrans_body(const float* __restrict__ w, u16* __restrict__ w2,
                                            int OC, int OCR, int idx) {
  int t = idx / (256 * OCR);
  int rem = idx - t * 256 * OCR;
  int ic = rem / OCR;
  int oc = rem - ic * OCR;
  float v = (oc < OC) ? w[((size_t)oc * 256 + ic) * 9 + t] : 0.f;
  u16 h = f2bf(v);
  u16 l = f2bf(v - bf2f(h));
  size_t row = (size_t)(t * 8 + (ic >> 5)) * OCR + oc;
  w2[row * 64 + (ic & 31)] = h;
  w2[row * 64 + 32 + (ic & 31)] = l;
}

__global__ __launch_bounds__(256) void wprep_all_k(
    const float* __restrict__ q_w, const float* __restrict__ pw_w,
    const float* __restrict__ kv_w, const float* __restrict__ proj_w,
    const float* __restrict__ dcn_w, const float* __restrict__ k2_w,
    const float* __restrict__ k3_w, const float* __restrict__ k4_w,
    f16* __restrict__ WQ, f16* __restrict__ WPW, f16* __restrict__ WKV,
    f16* __restrict__ WPJ, f16* __restrict__ WD,
    u16* __restrict__ W2K2, u16* __restrict__ W2K3, u16* __restrict__ W2K4,
    float* __restrict__ sacc) {
  int idx = blockIdx.x * 256 + threadIdx.x;
  if (idx < 16384) { WQ[idx] = (f16)q_w[idx]; return; }
  idx -= 16384;
  if (idx < 16384) { WPW[idx] = (f16)pw_w[idx]; return; }
  idx -= 16384;
  if (idx < 32768) { WKV[idx] = (f16)kv_w[idx]; return; }
  idx -= 32768;
  if (idx < 16384) { WPJ[idx] = (f16)proj_w[idx]; return; }
  idx -= 16384;
  if (idx < 20480) {
    int oc = idx / 160, k = idx - oc * 160;
    int t = k >> 4, ic = k & 15;
    WD[idx] = (t < 9) ? (f16)dcn_w[((size_t)oc * 16 + ic) * 9 + t] : (f16)0.f;
    return;
  }
  idx -= 20480;
  if (idx < 589824) { wtrans_body(k2_w, W2K2, 256, 256, idx); return; }
  idx -= 589824;
  if (idx < 589824) { wtrans_body(k3_w, W2K3, 256, 256, idx); return; }
  idx -= 589824;
  if (idx < 73728) { wtrans_body(k4_w, W2K4, 18, 32, idx); return; }
  idx -= 73728;
  if (idx < 4608) sacc[idx] = 0.f;
}

// ---------------- implicit-GEMM 3x3 conv, bf16 hi/lo 3-product, dbuf, split-K ----------------
template<int OCB, int NPAN, int SPLITK, int NGB, int WO, int HO, int WI, int HI, int PAD,
         int OCTOT, int OCR, bool GATE, bool OUTF_NHWC>
__global__ __launch_bounds__(256) void convmfma_k(
    const u16* __restrict__ inH, const u16* __restrict__ inL,
    const u16* __restrict__ w2,
    const float* __restrict__ gy, const float* __restrict__ gx,
    const float* __restrict__ gB,
    float* __restrict__ outFp, size_t pstride,
    u16* __restrict__ outH, u16* __restrict__ outL) {
  constexpr int CIN = 256;
  constexpr int MF = (OCB == 128) ? 4 : 2;
  constexpr int NF = (OCB == 128) ? 4 : 2;
  constexpr int GCN = 72 / SPLITK;
  __shared__ u16 lds_a[2][128 * 64];
  __shared__ u16 lds_w[2][OCB * 64];
  const int b = blockIdx.z;
  const int oc0 = (blockIdx.y % NPAN) * OCB;
  const int kz = blockIdx.y / NPAN;
  const int gbase = kz * GCN;
  float* outF = outFp + (size_t)kz * pstride;
  const int px0 = blockIdx.x * 128;
  const int tid = threadIdx.x;
  const int lane = tid & 63, wid = tid >> 6;
  const int wpx = (OCB == 128) ? ((wid >> 1) * 64) : (wid * 32);
  const int woc = (OCB == 128) ? ((wid & 1) * 64) : 0;

  const int spx = tid >> 1;
  const int shalf = tid & 1;
  const int opx = px0 + spx;
  const int py = opx / WO, pxx = opx % WO;
  const bool prow_ok = (opx < HO * WO);
  const int ar7 = spx & 7;
  const int awo0 = spx * 128 + (((shalf * 2 + 0) ^ ar7) << 4);
  const int awo1 = spx * 128 + (((shalf * 2 + 1) ^ ar7) << 4);
  const int awo2 = spx * 128 + (((shalf * 2 + 4) ^ ar7) << 4);
  const int awo3 = spx * 128 + (((shalf * 2 + 5) ^ ar7) << 4);
  const bool wact = (OCB == 128) ? true : (tid < OCB * 2);
  const int wrow = tid >> 1, whalf = tid & 1;
  int wwo[4];
#pragma unroll
  for (int j = 0; j < 4; j++) wwo[j] = wrow * 128 + (((whalf * 4 + j) ^ (wrow & 7)) << 4);

  int aoh[MF], aol[MF], woh[NF], wol[NF];
#pragma unroll
  for (int mf = 0; mf < MF; mf++) {
    int r = wpx + mf * 16 + (lane & 15);
    int s = lane >> 4;
    aoh[mf] = r * 128 + ((s ^ (r & 7)) << 4);
    aol[mf] = r * 128 + (((s + 4) ^ (r & 7)) << 4);
  }
#pragma unroll
  for (int nf = 0; nf < NF; nf++) {
    int r = woc + nf * 16 + (lane & 15);
    int s = lane >> 4;
    woh[nf] = r * 128 + ((s ^ (r & 7)) << 4);
    wol[nf] = r * 128 + (((s + 4) ^ (r & 7)) << 4);
  }

  f4_t acc[MF][NF];
#pragma unroll
  for (int mf = 0; mf < MF; mf++)
#pragma unroll
    for (int nf = 0; nf < NF; nf++) { f4_t z = {0.f, 0.f, 0.f, 0.f}; acc[mf][nf] = z; }

  const size_t inb = (size_t)b * (HI * WI) * CIN;
  const size_t wg0 = (size_t)(oc0 + wrow) * 64 + (size_t)whalf * 32;
  uint4 rah0, rah1, ral0, ral1, rwv0, rwv1, rwv2, rwv3;

  auto load_gc = [&](int gc) {
    const int t = gc >> 3, c = gc & 7;
    const int iy = py + (t / 3) - PAD;
    const int ix = pxx + (t % 3) - PAD;
    const bool val = prow_ok && iy >= 0 && iy < HI && ix >= 0 && ix < WI;
    uint4 z = {0, 0, 0, 0};
    rah0 = z; rah1 = z; ral0 = z; ral1 = z;
    if (val) {
      size_t a0 = inb + (size_t)(iy * WI + ix) * CIN + c * 32 + shalf * 16;
      const uint4* ph = (const uint4*)(inH + a0);
      const uint4* pl = (const uint4*)(inL + a0);
      rah0 = ph[0]; rah1 = ph[1]; ral0 = pl[0]; ral1 = pl[1];
    }
    if (wact) {
      const uint4* q = (const uint4*)(w2 + (size_t)gc * OCR * 64 + wg0);
      rwv0 = q[0]; rwv1 = q[1]; rwv2 = q[2]; rwv3 = q[3];
    }
  };
  auto store_gc = [&](int nb) {
    char* la = (char*)lds_a[nb];
    char* lw = (char*)lds_w[nb];
    *(uint4*)(la + awo0) = rah0;
    *(uint4*)(la + awo1) = rah1;
    *(uint4*)(la + awo2) = ral0;
    *(uint4*)(la + awo3) = ral1;
    if (wact) {
      *(uint4*)(lw + wwo[0]) = rwv0;
      *(uint4*)(lw + wwo[1]) = rwv1;
      *(uint4*)(lw + wwo[2]) = rwv2;
      *(uint4*)(lw + wwo[3]) = rwv3;
    }
  };

  load_gc(gbase);
  store_gc(0);
  __syncthreads();
  for (int i = 0; i < GCN; ++i) {
    const int cb = i & 1;
    if (i < GCN - 1) load_gc(gbase + i + 1);
    const char* la = (const char*)lds_a[cb];
    const char* lw = (const char*)lds_w[cb];
    bf8_t ah[MF], al[MF], wh[NF], wl[NF];
#pragma unroll
    for (int mf = 0; mf < MF; mf++) {
      ah[mf] = *(const bf8_t*)(la + aoh[mf]);
      al[mf] = *(const bf8_t*)(la + aol[mf]);
    }
#pragma unroll
    for (int nf = 0; nf < NF; nf++) {
      wh[nf] = *(const bf8_t*)(lw + woh[nf]);
      wl[nf] = *(const bf8_t*)(lw + wol[nf]);
    }
#pragma unroll
    for (int mf = 0; mf < MF; mf++)
#pragma unroll
      for (int nf = 0; nf < NF; nf++) {
        acc[mf][nf] = __builtin_amdgcn_mfma_f32_16x16x32_bf16(ah[mf], wh[nf], acc[mf][nf], 0, 0, 0);
        acc[mf][nf] = __builtin_amdgcn_mfma_f32_16x16x32_bf16(al[mf], wh[nf], acc[mf][nf], 0, 0, 0);
        acc[mf][nf] = __builtin_amdgcn_mfma_f32_16x16x32_bf16(ah[mf], wl[nf], acc[mf][nf], 0, 0, 0);
      }
    if (i < GCN - 1) store_gc(cb ^ 1);
    __syncthreads();
  }

  // epilogue: D row=(lane>>4)*4+r = px, col=lane&15 = oc  [m89-verified]
#pragma unroll
  for (int mf = 0; mf < MF; mf++) {
    const int pxb = px0 + wpx + mf * 16 + ((lane >> 4) << 2);
#pragma unroll
    for (int nf = 0; nf < NF; nf++) {
      const int oc = oc0 + woc + nf * 16 + (lane & 15);
      if (GATE) {
        const float* gp = (oc < 128) ? gy : gx;
        const size_t gbse = ((size_t)b * C1 + (oc & 127)) * NPIX;
        constexpr size_t gstride = (size_t)NB * 3844 * C2;
#pragma unroll
        for (int r = 0; r < 4; r++) {
          const int px = pxb + r;
          const int pyy = px >> 7, px2 = px & 127;
          const int iiy = (pyy * 62) >> 7, iix = (px2 * 62) >> 7;
          const size_t gi = ((size_t)b * 3844 + iiy * 62 + iix) * 256 + oc;
          float gv = gp[gbse + px];
#pragma unroll
          for (int pp = 0; pp < NGB; pp++) gv += gB[gi + (size_t)pp * gstride];
          float v = acc[mf][nf][r] * sigmoidf_(gv);
          u16 h = f2bf(v);
          size_t o = ((size_t)b * NPIX + px) * C2 + oc;
          outH[o] = h;
          outL[o] = f2bf(v - bf2f(h));
        }
      } else if (OUTF_NHWC) {
        if (oc < OCTOT) {
#pragma unroll
          for (int r = 0; r < 4; r++) {
            const int px = pxb + r;
            if (px < HO * WO)
              outF[((size_t)b * (HO * WO) + px) * OCTOT + oc] = acc[mf][nf][r];
          }
        }
      } else {
        if (pxb < HO * WO && oc < OCTOT)
          *(f4_t*)&outF[((size_t)b * OCTOT + oc) * (HO * WO) + pxb] = acc[mf][nf];
      }
    }
  }
}

// ---------------- sum NP split-K partial planes ----------------
template<int NP>
__global__ __launch_bounds__(256) void reduceN_k(const float* __restrict__ p,
                                                 float* __restrict__ o, int n4) {
  int i = blockIdx.x * 256 + threadIdx.x;
  if (i >= n4) return;
  const f4_t* v = (const f4_t*)p;
  f4_t r = v[i];
#pragma unroll
  for (int k = 1; k < NP; k++) {
    f4_t a = v[i + (size_t)k * n4];
    r[0] += a[0]; r[1] += a[1]; r[2] += a[2]; r[3] += a[3];
  }
  ((f4_t*)o)[i] = r;
}

// ---------------- 1x1 conv as fp16 MFMA GEMM, direct-global fragments ----------------
// OUTM: 0 = fp32 NCHW, 1 = f16 NHWC[128], 2 = f16 NCHW
template<int AS, int AOFF, bool BIAS, int OUTM>
__global__ __launch_bounds__(256) void gemm1x1_k(const f16* __restrict__ inA,
                                                 const f16* __restrict__ w,
                                                 const float* __restrict__ bias,
                                                 float* __restrict__ outF,
                                                 f16* __restrict__ outH) {
  const int b = blockIdx.z, nb0 = blockIdx.y * 128, px0 = blockIdx.x * 128;
  const int CoutTot = gridDim.y * 128;
  const int tid = threadIdx.x, lane = tid & 63, wid = tid >> 6;
  const int wpx = px0 + wid * 32;
  const int kslot = (lane >> 4) * 8;

  f4_t acc[2][8];
#pragma unroll
  for (int mf = 0; mf < 2; mf++)
#pragma unroll
    for (int nf = 0; nf < 8; nf++) { f4_t z = {0.f, 0.f, 0.f, 0.f}; acc[mf][nf] = z; }

  size_t arow[2];
#pragma unroll
  for (int mf = 0; mf < 2; mf++)
    arow[mf] = ((size_t)b * NPIX + wpx + mf * 16 + (lane & 15)) * AS + AOFF;
  size_t wrow[8];
#pragma unroll
  for (int nf = 0; nf < 8; nf++)
    wrow[nf] = (size_t)(nb0 + nf * 16 + (lane & 15)) * 128;

#pragma unroll
  for (int ks = 0; ks < 4; ks++) {
    const int ko = ks * 32 + kslot;
    h8_t a[2], bw[8];
#pragma unroll
    for (int mf = 0; mf < 2; mf++) a[mf] = *(const h8_t*)(inA + arow[mf] + ko);
#pragma unroll
    for (int nf = 0; nf < 8; nf++) bw[nf] = *(const h8_t*)(w + wrow[nf] + ko);
#pragma unroll
    for (int mf = 0; mf < 2; mf++)
#pragma unroll
      for (int nf = 0; nf < 8; nf++)
        acc[mf][nf] = __builtin_amdgcn_mfma_f32_16x16x32_f16(a[mf], bw[nf], acc[mf][nf], 0, 0, 0);
  }

#pragma unroll
  for (int mf = 0; mf < 2; mf++) {
    const int pxq = wpx + mf * 16 + (lane >> 4) * 4;
#pragma unroll
    for (int nf = 0; nf < 8; nf++) {
      const int oc = nb0 + nf * 16 + (lane & 15);
      f4_t v = acc[mf][nf];
      if (BIAS) {
        float bv = bias[oc];
        v[0] += bv; v[1] += bv; v[2] += bv; v[3] += bv;
      }
      if (OUTM == 1) {
#pragma unroll
        for (int r = 0; r < 4; r++)
          outH[((size_t)b * NPIX + pxq + r) * 128 + oc] = (f16)v[r];
      } else if (OUTM == 2) {
        h4_t o;
#pragma unroll
        for (int r = 0; r < 4; r++) o[r] = (f16)v[r];
        *(h4_t*)&outH[((size_t)b * CoutTot + oc) * NPIX + pxq] = o;
      } else {
        *(f4_t*)&outF[((size_t)b * CoutTot + oc) * NPIX + pxq] = v;
      }
    }
  }
}

// ---------------- fused modulated-deform-conv: NHWC f16 gather + grouped MFMA ----------------
__global__ __launch_bounds__(256) void dgemm_k(const f16* __restrict__ catf,
                                               const float* __restrict__ offs,
                                               const f16* __restrict__ wd,
                                               const float* __restrict__ dbias,
                                               f16* __restrict__ feat) {
  const int b = blockIdx.z, g = blockIdx.y;
  const int px0 = blockIdx.x * 128;
  const int tid = threadIdx.x;
  const int lane = tid & 63, wid = tid >> 6;
  const int chunk = lane >> 4;
  const int thalf = chunk >> 1;
  const int ic0 = (chunk & 1) * 8;
  const f16* yb = catf + (size_t)b * NPIX * C2;  // channels 0..127 of cat = y
  const float* ob = offs + (size_t)b * 18 * NPIX;

  int pm[2];
  float pyb[2], pxb2[2];
#pragma unroll
  for (int mf = 0; mf < 2; mf++) {
    pm[mf] = px0 + wid * 32 + mf * 16 + (lane & 15);
    pyb[mf] = (float)(pm[mf] >> 7);
    pxb2[mf] = (float)(pm[mf] & 127);
  }

  f4_t acc[2];
  { f4_t z = {0.f, 0.f, 0.f, 0.f}; acc[0] = z; acc[1] = z; }

  const size_t wbase = (size_t)(g * 16 + (lane & 15)) * 160;
#pragma unroll
  for (int s = 0; s < 5; s++) {
    h8_t ah[2];
#pragma unroll
    for (int mf = 0; mf < 2; mf++) {
      int t = 2 * s + thalf;
      int teff = t > 8 ? 8 : t;
      float dy = ob[(size_t)(2 * teff) * NPIX + pm[mf]];
      float dx = ob[(size_t)(2 * teff + 1) * NPIX + pm[mf]];
      float mk = sigmoidf_(ob[(size_t)teff * NPIX + pm[mf]]);
      int ky = teff / 3, kx = teff - 3 * ky;
      float pyf = pyb[mf] - 1.f + (float)ky + dy;
      float pxf = pxb2[mf] - 1.f + (float)kx + dx;
      float y0f = floorf(pyf), x0f = floorf(pxf);
      float fy = pyf - y0f, fx = pxf - x0f;
      int y0 = (int)y0f, x0 = (int)x0f;
      int y1 = y0 + 1, x1 = x0 + 1;
      float w00 = (1.f - fy) * (1.f - fx) * mk;
      float w01 = (1.f - fy) * fx * mk;
      float w10 = fy * (1.f - fx) * mk;
      float w11 = fy * fx * mk;
      bool vy0 = (y0 >= 0 && y0 < HH), vy1 = (y1 >= 0 && y1 < HH);
      bool vx0 = (x0 >= 0 && x0 < WW), vx1 = (x1 >= 0 && x1 < WW);
      if (!(vy0 && vx0)) w00 = 0.f;
      if (!(vy0 && vx1)) w01 = 0.f;
      if (!(vy1 && vx0)) w10 = 0.f;
      if (!(vy1 && vx1)) w11 = 0.f;
      int cy0 = min(max(y0, 0), HH - 1), cy1 = min(max(y1, 0), HH - 1);
      int cx0 = min(max(x0, 0), WW - 1), cx1 = min(max(x1, 0), WW - 1);
      const f16* p00 = yb + (size_t)(cy0 * WW + cx0) * C2 + g * 16 + ic0;
      const f16* p01 = yb + (size_t)(cy0 * WW + cx1) * C2 + g * 16 + ic0;
      const f16* p10 = yb + (size_t)(cy1 * WW + cx0) * C2 + g * 16 + ic0;
      const f16* p11 = yb + (size_t)(cy1 * WW + cx1) * C2 + g * 16 + ic0;
      h8_t a00 = *(const h8_t*)p00;
      h8_t a01 = *(const h8_t*)p01;
      h8_t a10 = *(const h8_t*)p10;
      h8_t a11 = *(const h8_t*)p11;
      h8_t hh;
#pragma unroll
      for (int j = 0; j < 8; j++) {
        float sv = w00 * (float)a00[j] + w01 * (float)a01[j] +
                   w10 * (float)a10[j] + w11 * (float)a11[j];
        hh[j] = (f16)sv;
      }
      ah[mf] = hh;
    }
    h8_t wv = *(const h8_t*)(wd + wbase + s * 32 + chunk * 8);
#pragma unroll
    for (int mf = 0; mf < 2; mf++)
      acc[mf] = __builtin_amdgcn_mfma_f32_16x16x32_f16(ah[mf], wv, acc[mf], 0, 0, 0);
  }

  const int oc = g * 16 + (lane & 15);
  const float bv = dbias[oc];
#pragma unroll
  for (int mf = 0; mf < 2; mf++) {
    const int pxq = px0 + wid * 32 + mf * 16 + (lane >> 4) * 4;
#pragma unroll
    for (int r = 0; r < 4; r++) {
      float v = fmaxf(acc[mf][r] + bv, 0.f);  // bias + relu (pw input)
      feat[((size_t)b * NPIX + pxq + r) * 128 + oc] = (f16)v;
    }
  }
}

// ---------------- depthwise 3x3, pad=1, f16 NCHW in/out, x8 vectorized ----------------
__global__ __launch_bounds__(256) void dw3x3h_k(const f16* __restrict__ in,
                                                const float* __restrict__ w,
                                                f16* __restrict__ out, int Cc) {
  int i8 = blockIdx.x * 256 + threadIdx.x;
  int total8 = NB * Cc * (NPIX / 8);
  if (i8 >= total8) return;
  int n8 = i8 & (NPIX / 8 - 1);
  int bc = i8 >> 11;               // NPIX/8 = 2048 = 2^11
  int c = bc % Cc;
  int n = n8 << 3;
  int yy = n >> 7, xx = n & 127;   // xx multiple of 8
  const f16* p = in + (size_t)bc * NPIX;
  const float* wc = w + c * 9;
  float acc[8] = {0.f, 0.f, 0.f, 0.f, 0.f, 0.f, 0.f, 0.f};
#pragma unroll
  for (int ky = 0; ky < 3; ky++) {
    int iy = yy + ky - 1;
    if (iy < 0 || iy >= HH) continue;
    const f16* row = p + iy * WW;
    float v[10];
    v[0] = (xx > 0) ? (float)row[xx - 1] : 0.f;
    h8_t m = *(const h8_t*)(row + xx);
#pragma unroll
    for (int j = 0; j < 8; j++) v[j + 1] = (float)m[j];
    v[9] = (xx + 8 < WW) ? (float)row[xx + 8] : 0.f;
#pragma unroll
    for (int kx = 0; kx < 3; kx++) {
      float wv = wc[ky * 3 + kx];
#pragma unroll
      for (int j = 0; j < 8; j++) acc[j] += wv * v[j + kx];
    }
  }
  h8_t o;
#pragma unroll
  for (int j = 0; j < 8; j++) o[j] = (f16)acc[j];
  *(h8_t*)&out[(size_t)bc * NPIX + n] = o;
}

// ---------------- attention Gram (Q·K^T 16x16 over N=16384) via fp16 MFMA ----------------
__global__ __launch_bounds__(256) void gram_k(const f16* __restrict__ qbuf,
                                              const f16* __restrict__ kvbuf,
                                              float* __restrict__ s_acc,
                                              float* __restrict__ qss,
                                              float* __restrict__ kss) {
  int b = blockIdx.z, h = blockIdx.y;
  int tid = threadIdx.x, lane = tid & 63, wid = tid >> 6;
  int r = lane & 15, ks = lane >> 4;
  const f16* qb = qbuf + ((size_t)b * C1 + h * DH + r) * NPIX;
  const f16* kb = kvbuf + ((size_t)b * C2 + h * DH + r) * NPIX;
  int n0 = (blockIdx.x * 4 + wid) * 512;
  f4_t acc = {0.f, 0.f, 0.f, 0.f};
  float q2 = 0.f, k2 = 0.f;
  for (int s = 0; s < 16; s++) {
    int k = n0 + s * 32 + ks * 8;
    h8_t qv = *(const h8_t*)(qb + k);
    h8_t kv = *(const h8_t*)(kb + k);
#pragma unroll
    for (int j = 0; j < 8; j++) {
      float qf = (float)qv[j], kf = (float)kv[j];
      q2 += qf * qf;
      k2 += kf * kf;
    }
    acc = __builtin_amdgcn_mfma_f32_16x16x32_f16(qv, kv, acc, 0, 0, 0);
  }
  int bh = b * NHEADS + h;
#pragma unroll
  for (int rr = 0; rr < 4; rr++)
    atomicAdd(&s_acc[((size_t)bh * 16 + ks * 4 + rr) * 16 + r], acc[rr]);
  q2 += __shfl_xor(q2, 16);
  q2 += __shfl_xor(q2, 32);
  k2 += __shfl_xor(k2, 16);
  k2 += __shfl_xor(k2, 32);
  if (ks == 0) {
    atomicAdd(&qss[bh * 16 + r], q2);
    atomicAdd(&kss[bh * 16 + r], k2);
  }
}

// ---------------- attention: fused softmax + (attn @ v) -> NHWC f16 ----------------
__global__ __launch_bounds__(256) void attnout_k(const float* __restrict__ s_acc,
                                                 const float* __restrict__ qss,
                                                 const float* __restrict__ kss,
                                                 const float* __restrict__ temp,
                                                 const f16* __restrict__ kvbuf,
                                                 f16* __restrict__ outA) {
  __shared__ float S[16][17];
  __shared__ float A[16][17];
  __shared__ float qn[16], kn[16];
  int b = blockIdx.z, h = blockIdx.y;
  int tid = threadIdx.x;
  int bh = b * NHEADS + h;
  int dd = tid & 15, cc = tid >> 4;
  if (tid < 16) {
    qn[tid] = fmaxf(sqrtf(qss[bh * 16 + tid]), 1e-12f);
    kn[tid] = fmaxf(sqrtf(kss[bh * 16 + tid]), 1e-12f);
  }
  __syncthreads();
  float t = temp[h];
  float s = s_acc[((size_t)bh * 16 + cc) * 16 + dd] / (qn[cc] * kn[dd]) * t;
  S[cc][dd] = s;
  __syncthreads();
  float mx = -1e30f;
#pragma unroll
  for (int j = 0; j < 16; j++) mx = fmaxf(mx, S[cc][j]);
  float sum = 0.f;
#pragma unroll
  for (int j = 0; j < 16; j++) sum += expf(S[cc][j] - mx);
  A[cc][dd] = expf(s - mx) / sum;
  __syncthreads();

  int n = blockIdx.x * 256 + tid;
  const f16* vb = kvbuf + ((size_t)b * C2 + C1 + h * DH) * NPIX;
  float acc[16];
#pragma unroll
  for (int c = 0; c < 16; c++) acc[c] = 0.f;
#pragma unroll
  for (int d = 0; d < 16; d++) {
    float vv = (float)vb[(size_t)d * NPIX + n];
#pragma unroll
    for (int c = 0; c < 16; c++) acc[c] += A[c][d] * vv;
  }
  h8_t o0, o1;
#pragma unroll
  for (int c = 0; c < 8; c++) {
    o0[c] = (f16)acc[c];
    o1[c] = (f16)acc[8 + c];
  }
  size_t base = ((size_t)b * NPIX + n) * 128 + h * 16;
  *(h8_t*)(outA + base) = o0;
  *(h8_t*)(outA + base + 8) = o1;
}

extern "C" void kernel_launch(void* const* d_in, const int* in_sizes, int n_in,
                              void* d_out, int out_size, void* d_ws, size_t ws_size,
                              hipStream_t stream) {
  const float* x = (const float*)d_in[0];
  const float* y = (const float*)d_in[1];
  const float* q_w = (const float*)d_in[2];
  const float* qd_w = (const float*)d_in[3];
  const float* kv_w = (const float*)d_in[4];
  const float* kvd_w = (const float*)d_in[5];
  const float* proj_w = (const float*)d_in[6];
  const float* temperature = (const float*)d_in[7];
  const float* k2_w = (const float*)d_in[8];
  const float* k3_w = (const float*)d_in[9];
  const float* k4_w = (const float*)d_in[10];
  const float* dcn_w = (const float*)d_in[11];
  const float* dcn_b = (const float*)d_in[12];
  const float* pw_w = (const float*)d_in[13];
  const float* pw_b = (const float*)d_in[14];
  float* out = (float*)d_out;

  char* ws = (char*)d_ws;
  size_t off = 0;
  auto alloc = [&](size_t nbytes) {
    char* p = ws + off;
    off += (nbytes + 255) & ~(size_t)255;
    return p;
  };
  f16* CATF = (f16*)alloc((size_t)NB * NPIX * C2 * 2);
  u16* CBH = (u16*)alloc((size_t)NB * NPIX * C2 * 2);
  u16* CBL = (u16*)alloc((size_t)NB * NPIX * C2 * 2);
  u16* PH = (u16*)alloc((size_t)NB * 4096 * C2 * 2);
  u16* PL = (u16*)alloc((size_t)NB * 4096 * C2 * 2);
  float* A2 = (float*)alloc((size_t)4 * NB * 3844 * C2 * 4);   // 4 split-K partial planes, NHWC
  u16* OUT3H = (u16*)alloc((size_t)NB * NPIX * C2 * 2);
  u16* OUT3L = (u16*)alloc((size_t)NB * NPIX * C2 * 2);
  float* OF8P = (float*)alloc((size_t)8 * NB * 18 * NPIX * 4); // 8 split-K partial planes, NCHW
  float* OFFS = (float*)alloc((size_t)NB * 18 * NPIX * 4);
  f16* FEAT = (f16*)alloc((size_t)NB * NPIX * C1 * 2);
  f16* AL = (f16*)alloc((size_t)NB * NPIX * C1 * 2);
  f16* QbH = (f16*)alloc((size_t)NB * C1 * NPIX * 2);
  u16* W2K2 = (u16*)alloc((size_t)72 * 256 * 64 * 2);
  u16* W2K3 = (u16*)alloc((size_t)72 * 256 * 64 * 2);
  u16* W2K4 = (u16*)alloc((size_t)72 * 32 * 64 * 2);
  f16* WD = (f16*)alloc((size_t)128 * 160 * 2);
  f16* WQ = (f16*)alloc((size_t)128 * 128 * 2);
  f16* WPW = (f16*)alloc((size_t)128 * 128 * 2);
  f16* WKV = (f16*)alloc((size_t)256 * 128 * 2);
  f16* WPJ = (f16*)alloc((size_t)128 * 128 * 2);
  float* SACC = (float*)alloc((size_t)(NB * NHEADS * 256 + 512) * 4);
  float* QSS = SACC + NB * NHEADS * 256;
  float* KSS = QSS + 256;

  // region reuse (lifetimes)
  f16* QT1H = (f16*)OUT3H;      // q 1x1 out, f16 NCHW (dead before k3 writes OUT3)
  f16* KV1H = (f16*)CBH;        // kv 1x1 out, f16 NCHW (CBH dead after k3)
  f16* KVbH = (f16*)OUT3H;      // kv dw out, f16 NCHW (OUT3 dead after k4)
  f16* AO = FEAT;               // attn out (FEAT dead after pw)

  dim3 blk(256);

  // fused weight prep + SACC/QSS/KSS zero (one launch)
  wprep_all_k<<<dim3(5314), blk, 0, stream>>>(q_w, pw_w, kv_w, proj_w, dcn_w, k2_w, k3_w, k4_w,
                                              WQ, WPW, WKV, WPJ, WD, W2K2, W2K3, W2K4, SACC);

  // cat split + fused avgpool: f16 cat + bf16 hi/lo cat + pooled hi/lo
  splitcat2_k<<<dim3(64, C2 / 32, NB), blk, 0, stream>>>(y, x, CATF, CBH, CBL, PH, PL);

  // q path: 1x1 MFMA on x-half of catf -> depthwise (all f16)
  gemm1x1_k<C2, C1, false, 2><<<dim3(NPIX / 128, 1, NB), blk, 0, stream>>>(
      CATF, WQ, nullptr, nullptr, QT1H);
  dw3x3h_k<<<dim3(NB * C1 * (NPIX / 8) / 256), blk, 0, stream>>>(QT1H, qd_w, QbH, C1);

  // offset head
  convmfma_k<128, 2, 4, 0, 62, 62, 64, 64, 0, 256, 256, false, true>
      <<<dim3(31, 8, NB), blk, 0, stream>>>(PH, PL, W2K2, nullptr, nullptr, nullptr,
                                            A2, (size_t)NB * 3844 * C2, nullptr, nullptr);
  convmfma_k<128, 2, 1, 4, 128, 128, 128, 128, 1, 256, 256, true, false>
      <<<dim3(128, 2, NB), blk, 0, stream>>>(CBH, CBL, W2K3, y, x, A2,
                                             nullptr, 0, OUT3H, OUT3L);
  convmfma_k<32, 1, 8, 0, 128, 128, 128, 128, 1, 18, 32, false, false>
      <<<dim3(128, 8, NB), blk, 0, stream>>>(OUT3H, OUT3L, W2K4, nullptr, nullptr, nullptr,
                                             OF8P, (size_t)NB * 18 * NPIX, nullptr, nullptr);
  reduceN_k<8><<<dim3((NB * 18 * NPIX / 4 + 255) / 256), blk, 0, stream>>>(
      OF8P, OFFS, NB * 18 * NPIX / 4);

  // deformable alignment (gathers from y-half of catf) + pw 1x1
  dgemm_k<<<dim3(NPIX / 128, NG, NB), blk, 0, stream>>>(CATF, OFFS, WD, dcn_b, FEAT);
  gemm1x1_k<C1, 0, true, 1><<<dim3(NPIX / 128, 1, NB), blk, 0, stream>>>(
      FEAT, WPW, pw_b, nullptr, AL);

  // kv path (all f16)
  gemm1x1_k<C1, 0, false, 2><<<dim3(NPIX / 128, 2, NB), blk, 0, stream>>>(
      AL, WKV, nullptr, nullptr, KV1H);
  dw3x3h_k<<<dim3(NB * C2 * (NPIX / 8) / 256), blk, 0, stream>>>(KV1H, kvd_w, KVbH, C2);

  // attention: fp16 MFMA Gram + fused softmax/PV
  gram_k<<<dim3(8, NHEADS, NB), blk, 0, stream>>>(QbH, KVbH, SACC, QSS, KSS);
  attnout_k<<<dim3(NPIX / 256, NHEADS, NB), blk, 0, stream>>>(SACC, QSS, KSS, temperature, KVbH, AO);
  gemm1x1_k<C1, 0, false, 0><<<dim3(NPIX / 128, 1, NB), blk, 0, stream>>>(
      AO, WPJ, nullptr, out, nullptr);
}

// Round 12
// 270.943 us; speedup vs baseline: 2.7712x; 1.3449x over previous
//
#include <hip/hip_runtime.h>
#include <math.h>

#define NB 2
#define C1 128
#define C2 256
#define HH 128
#define WW 128
#define NPIX (HH*WW)
#define NHEADS 8
#define DH 16
#define NG 8

typedef unsigned short u16;
typedef _Float16 f16;
typedef __attribute__((ext_vector_type(8))) _Float16 h8_t;
typedef __attribute__((ext_vector_type(4))) _Float16 h4_t;
typedef __attribute__((ext_vector_type(4))) float f4_t;

__device__ __forceinline__ float sigmoidf_(float v) { return 1.f / (1.f + expf(-v)); }

// ---- NCHW fp32 (y|x) -> NHWC f16 cat + fused 2x2 avgpool (f16 NHWC) ----
__global__ __launch_bounds__(256) void splitcat2_k(const float* __restrict__ y,
                                                   const float* __restrict__ x,
                                                   f16* __restrict__ catf,
                                                   f16* __restrict__ ph) {
  __shared__ float tile[256][33];
  int b = blockIdx.z, c0 = blockIdx.y * 32, rp = blockIdx.x;
  int tid = threadIdx.x;
  const float* src = (c0 < 128) ? y : x;
  int cc0 = c0 & 127;
  const int pbase = rp * 256;
  for (int e = tid; e < 8192; e += 256) {
    int c = e >> 8, p = e & 255;
    tile[p][c] = src[((size_t)b * C1 + cc0 + c) * NPIX + pbase + p];
  }
  __syncthreads();
  for (int e = tid; e < 8192; e += 256) {
    int p = e >> 5, c = e & 31;
    catf[((size_t)b * NPIX + pbase + p) * C2 + c0 + c] = (f16)tile[p][c];
  }
  for (int e = tid; e < 2048; e += 256) {
    int pp = e >> 5, c = e & 31;
    float v = 0.25f * (tile[2 * pp][c] + tile[2 * pp + 1][c] +
                       tile[128 + 2 * pp][c] + tile[128 + 2 * pp + 1][c]);
    ph[((size_t)b * 4096 + rp * 64 + pp) * C2 + c0 + c] = (f16)v;
  }
}

// ---------------- fused weight prep + accumulator zero (one launch) ----------------
__device__ __forceinline__ void wtrans_h(const float* __restrict__ w, f16* __restrict__ w2,
                                         int OC, int OCR, int idx) {
  int t = idx / (256 * OCR);
  int rem = idx - t * 256 * OCR;
  int ic = rem / OCR;
  int oc = rem - ic * OCR;
  float v = (oc < OC) ? w[((size_t)oc * 256 + ic) * 9 + t] : 0.f;
  w2[((size_t)(t * 8 + (ic >> 5)) * OCR + oc) * 32 + (ic & 31)] = (f16)v;
}

__global__ __launch_bounds__(256) void wprep_all_k(
    const float* __restrict__ q_w, const float* __restrict__ pw_w,
    const float* __restrict__ kv_w, const float* __restrict__ proj_w,
    const float* __restrict__ dcn_w, const float* __restrict__ k2_w,
    const float* __restrict__ k3_w, const float* __restrict__ k4_w,
    f16* __restrict__ WQ, f16* __restrict__ WPW, f16* __restrict__ WKV,
    f16* __restrict__ WPJ, f16* __restrict__ WD,
    f16* __restrict__ W2K2, f16* __restrict__ W2K3, f16* __restrict__ W2K4,
    float* __restrict__ sacc) {
  int idx = blockIdx.x * 256 + threadIdx.x;
  if (idx < 16384) { WQ[idx] = (f16)q_w[idx]; return; }
  idx -= 16384;
  if (idx < 16384) { WPW[idx] = (f16)pw_w[idx]; return; }
  idx -= 16384;
  if (idx < 32768) { WKV[idx] = (f16)kv_w[idx]; return; }
  idx -= 32768;
  if (idx < 16384) { WPJ[idx] = (f16)proj_w[idx]; return; }
  idx -= 16384;
  if (idx < 20480) {
    int oc = idx / 160, k = idx - oc * 160;
    int t = k >> 4, ic = k & 15;
    WD[idx] = (t < 9) ? (f16)dcn_w[((size_t)oc * 16 + ic) * 9 + t] : (f16)0.f;
    return;
  }
  idx -= 20480;
  if (idx < 589824) { wtrans_h(k2_w, W2K2, 256, 256, idx); return; }
  idx -= 589824;
  if (idx < 589824) { wtrans_h(k3_w, W2K3, 256, 256, idx); return; }
  idx -= 589824;
  if (idx < 73728) { wtrans_h(k4_w, W2K4, 18, 32, idx); return; }
  idx -= 73728;
  if (idx < 4608) sacc[idx] = 0.f;
}

// ---------------- implicit-GEMM 3x3 conv, fp16 single-product MFMA, dbuf, split-K ----------------
// Block: 128 px x OCB oc, 4 waves. K-chunk = 32 f16 (64B rows, 4 slots, XOR key (row>>1)&3).
template<int OCB, int NPAN, int SPLITK, int NGB, int WO, int HO, int WI, int HI, int PAD,
         int OCTOT, int OCR, bool GATE, bool OUTF_NHWC>
__global__ __launch_bounds__(256) void convh_k(
    const f16* __restrict__ inA, const f16* __restrict__ w2,
    const float* __restrict__ gy, const float* __restrict__ gx,
    const float* __restrict__ gB,
    float* __restrict__ outFp, size_t pstride,
    f16* __restrict__ outC) {
  constexpr int CIN = 256;
  constexpr int MF = (OCB == 128) ? 4 : 2;
  constexpr int NF = (OCB == 128) ? 4 : 2;
  constexpr int GCN = 72 / SPLITK;
  __shared__ f16 lds_a[2][128 * 32];
  __shared__ f16 lds_w[2][OCB * 32];
  const int b = blockIdx.z;
  const int oc0 = (blockIdx.y % NPAN) * OCB;
  const int kz = blockIdx.y / NPAN;
  const int gbase = kz * GCN;
  float* outF = outFp + (size_t)kz * pstride;
  const int px0 = blockIdx.x * 128;
  const int tid = threadIdx.x;
  const int lane = tid & 63, wid = tid >> 6;
  const int wpx = (OCB == 128) ? ((wid >> 1) * 64) : (wid * 32);
  const int woc = (OCB == 128) ? ((wid & 1) * 64) : 0;

  // A stager: thread -> (row=tid>>1, half=tid&1), 32B each
  const int spx = tid >> 1;
  const int shalf = tid & 1;
  const int opx = px0 + spx;
  const int py = opx / WO, pxx = opx % WO;
  const bool prow_ok = (opx < HO * WO);
  const int akey = (spx >> 1) & 3;
  const int awo0 = spx * 64 + (((shalf * 2 + 0) ^ akey) << 4);
  const int awo1 = spx * 64 + (((shalf * 2 + 1) ^ akey) << 4);
  // W stager
  const bool wact = (OCB == 128) ? true : (tid < OCB * 2);
  const int wrow = tid >> 1, whalf = tid & 1;
  const int wkey = (wrow >> 1) & 3;
  const int wwo0 = wrow * 64 + (((whalf * 2 + 0) ^ wkey) << 4);
  const int wwo1 = wrow * 64 + (((whalf * 2 + 1) ^ wkey) << 4);

  // fragment read offsets (bytes)
  int aof[MF], wof[NF];
#pragma unroll
  for (int mf = 0; mf < MF; mf++) {
    int r = wpx + mf * 16 + (lane & 15);
    aof[mf] = r * 64 + (((lane >> 4) ^ ((r >> 1) & 3)) << 4);
  }
#pragma unroll
  for (int nf = 0; nf < NF; nf++) {
    int r = woc + nf * 16 + (lane & 15);
    wof[nf] = r * 64 + (((lane >> 4) ^ ((r >> 1) & 3)) << 4);
  }

  f4_t acc[MF][NF];
#pragma unroll
  for (int mf = 0; mf < MF; mf++)
#pragma unroll
    for (int nf = 0; nf < NF; nf++) { f4_t z = {0.f, 0.f, 0.f, 0.f}; acc[mf][nf] = z; }

  const size_t inb = (size_t)b * (HI * WI) * CIN;
  const size_t wg0 = (size_t)(oc0 + wrow) * 32 + (size_t)whalf * 16;
  uint4 ra0, ra1, rw0, rw1;

  auto load_gc = [&](int gc) {
    const int t = gc >> 3, c = gc & 7;
    const int iy = py + (t / 3) - PAD;
    const int ix = pxx + (t % 3) - PAD;
    const bool val = prow_ok && iy >= 0 && iy < HI && ix >= 0 && ix < WI;
    uint4 z = {0, 0, 0, 0};
    ra0 = z; ra1 = z;
    if (val) {
      const uint4* p = (const uint4*)(inA + inb + (size_t)(iy * WI + ix) * CIN + c * 32 + shalf * 16);
      ra0 = p[0];
      ra1 = p[1];
    }
    if (wact) {
      const uint4* q = (const uint4*)(w2 + (size_t)gc * OCR * 32 + wg0);
      rw0 = q[0];
      rw1 = q[1];
    }
  };
  auto store_gc = [&](int nb) {
    char* la = (char*)lds_a[nb];
    char* lw = (char*)lds_w[nb];
    *(uint4*)(la + awo0) = ra0;
    *(uint4*)(la + awo1) = ra1;
    if (wact) {
      *(uint4*)(lw + wwo0) = rw0;
      *(uint4*)(lw + wwo1) = rw1;
    }
  };

  load_gc(gbase);
  store_gc(0);
  __syncthreads();
  for (int i = 0; i < GCN; ++i) {
    const int cb = i & 1;
    if (i < GCN - 1) load_gc(gbase + i + 1);
    const char* la = (const char*)lds_a[cb];
    const char* lw = (const char*)lds_w[cb];
    h8_t af[MF], wf[NF];
#pragma unroll
    for (int mf = 0; mf < MF; mf++) af[mf] = *(const h8_t*)(la + aof[mf]);
#pragma unroll
    for (int nf = 0; nf < NF; nf++) wf[nf] = *(const h8_t*)(lw + wof[nf]);
#pragma unroll
    for (int mf = 0; mf < MF; mf++)
#pragma unroll
      for (int nf = 0; nf < NF; nf++)
        acc[mf][nf] = __builtin_amdgcn_mfma_f32_16x16x32_f16(af[mf], wf[nf], acc[mf][nf], 0, 0, 0);
    if (i < GCN - 1) store_gc(cb ^ 1);
    __syncthreads();
  }

  // epilogue: D row=(lane>>4)*4+r = px, col=lane&15 = oc  [m89-verified]
#pragma unroll
  for (int mf = 0; mf < MF; mf++) {
    const int pxb = px0 + wpx + mf * 16 + ((lane >> 4) << 2);
#pragma unroll
    for (int nf = 0; nf < NF; nf++) {
      const int oc = oc0 + woc + nf * 16 + (lane & 15);
      if (GATE) {
        const float* gp = (oc < 128) ? gy : gx;
        const size_t gbse = ((size_t)b * C1 + (oc & 127)) * NPIX;
        constexpr size_t gstride = (size_t)NB * 3844 * C2;
#pragma unroll
        for (int r = 0; r < 4; r++) {
          const int px = pxb + r;
          const int pyy = px >> 7, px2 = px & 127;
          const int iiy = (pyy * 62) >> 7, iix = (px2 * 62) >> 7;
          const size_t gi = ((size_t)b * 3844 + iiy * 62 + iix) * 256 + oc;
          float gv = gp[gbse + px];
#pragma unroll
          for (int pp = 0; pp < NGB; pp++) gv += gB[gi + (size_t)pp * gstride];
          float v = acc[mf][nf][r] * sigmoidf_(gv);
          outC[((size_t)b * NPIX + px) * C2 + oc] = (f16)v;
        }
      } else if (OUTF_NHWC) {
        if (oc < OCTOT) {
#pragma unroll
          for (int r = 0; r < 4; r++) {
            const int px = pxb + r;
            if (px < HO * WO)
              outF[((size_t)b * (HO * WO) + px) * OCTOT + oc] = acc[mf][nf][r];
          }
        }
      } else {
        if (pxb < HO * WO && oc < OCTOT)
          *(f4_t*)&outF[((size_t)b * OCTOT + oc) * (HO * WO) + pxb] = acc[mf][nf];
      }
    }
  }
}

// ---------------- sum NP split-K partial planes ----------------
template<int NP>
__global__ __launch_bounds__(256) void reduceN_k(const float* __restrict__ p,
                                                 float* __restrict__ o, int n4) {
  int i = blockIdx.x * 256 + threadIdx.x;
  if (i >= n4) return;
  const f4_t* v = (const f4_t*)p;
  f4_t r = v[i];
#pragma unroll
  for (int k = 1; k < NP; k++) {
    f4_t a = v[i + (size_t)k * n4];
    r[0] += a[0]; r[1] += a[1]; r[2] += a[2]; r[3] += a[3];
  }
  ((f4_t*)o)[i] = r;
}

// ---------------- 1x1 conv as fp16 MFMA GEMM, direct-global fragments ----------------
// OUTM: 0 = fp32 NCHW, 1 = f16 NHWC[128], 2 = f16 NCHW
template<int AS, int AOFF, bool BIAS, int OUTM>
__global__ __launch_bounds__(256) void gemm1x1_k(const f16* __restrict__ inA,
                                                 const f16* __restrict__ w,
                                                 const float* __restrict__ bias,
                                                 float* __restrict__ outF,
                                                 f16* __restrict__ outH) {
  const int b = blockIdx.z, nb0 = blockIdx.y * 128, px0 = blockIdx.x * 128;
  const int CoutTot = gridDim.y * 128;
  const int tid = threadIdx.x, lane = tid & 63, wid = tid >> 6;
  const int wpx = px0 + wid * 32;
  const int kslot = (lane >> 4) * 8;

  f4_t acc[2][8];
#pragma unroll
  for (int mf = 0; mf < 2; mf++)
#pragma unroll
    for (int nf = 0; nf < 8; nf++) { f4_t z = {0.f, 0.f, 0.f, 0.f}; acc[mf][nf] = z; }

  size_t arow[2];
#pragma unroll
  for (int mf = 0; mf < 2; mf++)
    arow[mf] = ((size_t)b * NPIX + wpx + mf * 16 + (lane & 15)) * AS + AOFF;
  size_t wrow[8];
#pragma unroll
  for (int nf = 0; nf < 8; nf++)
    wrow[nf] = (size_t)(nb0 + nf * 16 + (lane & 15)) * 128;

#pragma unroll
  for (int ks = 0; ks < 4; ks++) {
    const int ko = ks * 32 + kslot;
    h8_t a[2], bw[8];
#pragma unroll
    for (int mf = 0; mf < 2; mf++) a[mf] = *(const h8_t*)(inA + arow[mf] + ko);
#pragma unroll
    for (int nf = 0; nf < 8; nf++) bw[nf] = *(const h8_t*)(w + wrow[nf] + ko);
#pragma unroll
    for (int mf = 0; mf < 2; mf++)
#pragma unroll
      for (int nf = 0; nf < 8; nf++)
        acc[mf][nf] = __builtin_amdgcn_mfma_f32_16x16x32_f16(a[mf], bw[nf], acc[mf][nf], 0, 0, 0);
  }

#pragma unroll
  for (int mf = 0; mf < 2; mf++) {
    const int pxq = wpx + mf * 16 + (lane >> 4) * 4;
#pragma unroll
    for (int nf = 0; nf < 8; nf++) {
      const int oc = nb0 + nf * 16 + (lane & 15);
      f4_t v = acc[mf][nf];
      if (BIAS) {
        float bv = bias[oc];
        v[0] += bv; v[1] += bv; v[2] += bv; v[3] += bv;
      }
      if (OUTM == 1) {
#pragma unroll
        for (int r = 0; r < 4; r++)
          outH[((size_t)b * NPIX + pxq + r) * 128 + oc] = (f16)v[r];
      } else if (OUTM == 2) {
        h4_t o;
#pragma unroll
        for (int r = 0; r < 4; r++) o[r] = (f16)v[r];
        *(h4_t*)&outH[((size_t)b * CoutTot + oc) * NPIX + pxq] = o;
      } else {
        *(f4_t*)&outF[((size_t)b * CoutTot + oc) * NPIX + pxq] = v;
      }
    }
  }
}

// ---------------- fused modulated-deform-conv: NHWC f16 gather + grouped MFMA ----------------
__global__ __launch_bounds__(256) void dgemm_k(const f16* __restrict__ catf,
                                               const float* __restrict__ offs,
                                               const f16* __restrict__ wd,
                                               const float* __restrict__ dbias,
                                               f16* __restrict__ feat) {
  const int b = blockIdx.z, g = blockIdx.y;
  const int px0 = blockIdx.x * 128;
  const int tid = threadIdx.x;
  const int lane = tid & 63, wid = tid >> 6;
  const int chunk = lane >> 4;
  const int thalf = chunk >> 1;
  const int ic0 = (chunk & 1) * 8;
  const f16* yb = catf + (size_t)b * NPIX * C2;  // channels 0..127 of cat = y
  const float* ob = offs + (size_t)b * 18 * NPIX;

  int pm[2];
  float pyb[2], pxb2[2];
#pragma unroll
  for (int mf = 0; mf < 2; mf++) {
    pm[mf] = px0 + wid * 32 + mf * 16 + (lane & 15);
    pyb[mf] = (float)(pm[mf] >> 7);
    pxb2[mf] = (float)(pm[mf] & 127);
  }

  f4_t acc[2];
  { f4_t z = {0.f, 0.f, 0.f, 0.f}; acc[0] = z; acc[1] = z; }

  const size_t wbase = (size_t)(g * 16 + (lane & 15)) * 160;
#pragma unroll
  for (int s = 0; s < 5; s++) {
    h8_t ah[2];
#pragma unroll
    for (int mf = 0; mf < 2; mf++) {
      int t = 2 * s + thalf;
      int teff = t > 8 ? 8 : t;
      float dy = ob[(size_t)(2 * teff) * NPIX + pm[mf]];
      float dx = ob[(size_t)(2 * teff + 1) * NPIX + pm[mf]];
      float mk = sigmoidf_(ob[(size_t)teff * NPIX + pm[mf]]);
      int ky = teff / 3, kx = teff - 3 * ky;
      float pyf = pyb[mf] - 1.f + (float)ky + dy;
      float pxf = pxb2[mf] - 1.f + (float)kx + dx;
      float y0f = floorf(pyf), x0f = floorf(pxf);
      float fy = pyf - y0f, fx = pxf - x0f;
      int y0 = (int)y0f, x0 = (int)x0f;
      int y1 = y0 + 1, x1 = x0 + 1;
      float w00 = (1.f - fy) * (1.f - fx) * mk;
      float w01 = (1.f - fy) * fx * mk;
      float w10 = fy * (1.f - fx) * mk;
      float w11 = fy * fx * mk;
      bool vy0 = (y0 >= 0 && y0 < HH), vy1 = (y1 >= 0 && y1 < HH);
      bool vx0 = (x0 >= 0 && x0 < WW), vx1 = (x1 >= 0 && x1 < WW);
      if (!(vy0 && vx0)) w00 = 0.f;
      if (!(vy0 && vx1)) w01 = 0.f;
      if (!(vy1 && vx0)) w10 = 0.f;
      if (!(vy1 && vx1)) w11 = 0.f;
      int cy0 = min(max(y0, 0), HH - 1), cy1 = min(max(y1, 0), HH - 1);
      int cx0 = min(max(x0, 0), WW - 1), cx1 = min(max(x1, 0), WW - 1);
      const f16* p00 = yb + (size_t)(cy0 * WW + cx0) * C2 + g * 16 + ic0;
      const f16* p01 = yb + (size_t)(cy0 * WW + cx1) * C2 + g * 16 + ic0;
      const f16* p10 = yb + (size_t)(cy1 * WW + cx0) * C2 + g * 16 + ic0;
      const f16* p11 = yb + (size_t)(cy1 * WW + cx1) * C2 + g * 16 + ic0;
      h8_t a00 = *(const h8_t*)p00;
      h8_t a01 = *(const h8_t*)p01;
      h8_t a10 = *(const h8_t*)p10;
      h8_t a11 = *(const h8_t*)p11;
      h8_t hh;
#pragma unroll
      for (int j = 0; j < 8; j++) {
        float sv = w00 * (float)a00[j] + w01 * (float)a01[j] +
                   w10 * (float)a10[j] + w11 * (float)a11[j];
        hh[j] = (f16)sv;
      }
      ah[mf] = hh;
    }
    h8_t wv = *(const h8_t*)(wd + wbase + s * 32 + chunk * 8);
#pragma unroll
    for (int mf = 0; mf < 2; mf++)
      acc[mf] = __builtin_amdgcn_mfma_f32_16x16x32_f16(ah[mf], wv, acc[mf], 0, 0, 0);
  }

  const int oc = g * 16 + (lane & 15);
  const float bv = dbias[oc];
#pragma unroll
  for (int mf = 0; mf < 2; mf++) {
    const int pxq = px0 + wid * 32 + mf * 16 + (lane >> 4) * 4;
#pragma unroll
    for (int r = 0; r < 4; r++) {
      float v = fmaxf(acc[mf][r] + bv, 0.f);  // bias + relu (pw input)
      feat[((size_t)b * NPIX + pxq + r) * 128 + oc] = (f16)v;
    }
  }
}

// ---------------- depthwise 3x3, pad=1, f16 NCHW in/out, x8 vectorized ----------------
__global__ __launch_bounds__(256) void dw3x3h_k(const f16* __restrict__ in,
                                                const float* __restrict__ w,
                                                f16* __restrict__ out, int Cc) {
  int i8 = blockIdx.x * 256 + threadIdx.x;
  int total8 = NB * Cc * (NPIX / 8);
  if (i8 >= total8) return;
  int n8 = i8 & (NPIX / 8 - 1);
  int bc = i8 >> 11;
  int c = bc % Cc;
  int n = n8 << 3;
  int yy = n >> 7, xx = n & 127;
  const f16* p = in + (size_t)bc * NPIX;
  const float* wc = w + c * 9;
  float acc[8] = {0.f, 0.f, 0.f, 0.f, 0.f, 0.f, 0.f, 0.f};
#pragma unroll
  for (int ky = 0; ky < 3; ky++) {
    int iy = yy + ky - 1;
    if (iy < 0 || iy >= HH) continue;
    const f16* row = p + iy * WW;
    float v[10];
    v[0] = (xx > 0) ? (float)row[xx - 1] : 0.f;
    h8_t m = *(const h8_t*)(row + xx);
#pragma unroll
    for (int j = 0; j < 8; j++) v[j + 1] = (float)m[j];
    v[9] = (xx + 8 < WW) ? (float)row[xx + 8] : 0.f;
#pragma unroll
    for (int kx = 0; kx < 3; kx++) {
      float wv = wc[ky * 3 + kx];
#pragma unroll
      for (int j = 0; j < 8; j++) acc[j] += wv * v[j + kx];
    }
  }
  h8_t o;
#pragma unroll
  for (int j = 0; j < 8; j++) o[j] = (f16)acc[j];
  *(h8_t*)&out[(size_t)bc * NPIX + n] = o;
}

// ---------------- attention Gram (Q·K^T 16x16 over N=16384) via fp16 MFMA ----------------
__global__ __launch_bounds__(256) void gram_k(const f16* __restrict__ qbuf,
                                              const f16* __restrict__ kvbuf,
                                              float* __restrict__ s_acc,
                                              float* __restrict__ qss,
                                              float* __restrict__ kss) {
  int b = blockIdx.z, h = blockIdx.y;
  int tid = threadIdx.x, lane = tid & 63, wid = tid >> 6;
  int r = lane & 15, ks = lane >> 4;
  const f16* qb = qbuf + ((size_t)b * C1 + h * DH + r) * NPIX;
  const f16* kb = kvbuf + ((size_t)b * C2 + h * DH + r) * NPIX;
  int n0 = (blockIdx.x * 4 + wid) * 512;
  f4_t acc = {0.f, 0.f, 0.f, 0.f};
  float q2 = 0.f, k2 = 0.f;
  for (int s = 0; s < 16; s++) {
    int k = n0 + s * 32 + ks * 8;
    h8_t qv = *(const h8_t*)(qb + k);
    h8_t kv = *(const h8_t*)(kb + k);
#pragma unroll
    for (int j = 0; j < 8; j++) {
      float qf = (float)qv[j], kf = (float)kv[j];
      q2 += qf * qf;
      k2 += kf * kf;
    }
    acc = __builtin_amdgcn_mfma_f32_16x16x32_f16(qv, kv, acc, 0, 0, 0);
  }
  int bh = b * NHEADS + h;
#pragma unroll
  for (int rr = 0; rr < 4; rr++)
    atomicAdd(&s_acc[((size_t)bh * 16 + ks * 4 + rr) * 16 + r], acc[rr]);
  q2 += __shfl_xor(q2, 16);
  q2 += __shfl_xor(q2, 32);
  k2 += __shfl_xor(k2, 16);
  k2 += __shfl_xor(k2, 32);
  if (ks == 0) {
    atomicAdd(&qss[bh * 16 + r], q2);
    atomicAdd(&kss[bh * 16 + r], k2);
  }
}

// ---------------- attention: fused softmax + (attn @ v) -> NHWC f16 ----------------
__global__ __launch_bounds__(256) void attnout_k(const float* __restrict__ s_acc,
                                                 const float* __restrict__ qss,
                                                 const float* __restrict__ kss,
                                                 const float* __restrict__ temp,
                                                 const f16* __restrict__ kvbuf,
                                                 f16* __restrict__ outA) {
  __shared__ float S[16][17];
  __shared__ float A[16][17];
  __shared__ float qn[16], kn[16];
  int b = blockIdx.z, h = blockIdx.y;
  int tid = threadIdx.x;
  int bh = b * NHEADS + h;
  int dd = tid & 15, cc = tid >> 4;
  if (tid < 16) {
    qn[tid] = fmaxf(sqrtf(qss[bh * 16 + tid]), 1e-12f);
    kn[tid] = fmaxf(sqrtf(kss[bh * 16 + tid]), 1e-12f);
  }
  __syncthreads();
  float t = temp[h];
  float s = s_acc[((size_t)bh * 16 + cc) * 16 + dd] / (qn[cc] * kn[dd]) * t;
  S[cc][dd] = s;
  __syncthreads();
  float mx = -1e30f;
#pragma unroll
  for (int j = 0; j < 16; j++) mx = fmaxf(mx, S[cc][j]);
  float sum = 0.f;
#pragma unroll
  for (int j = 0; j < 16; j++) sum += expf(S[cc][j] - mx);
  A[cc][dd] = expf(s - mx) / sum;
  __syncthreads();

  int n = blockIdx.x * 256 + tid;
  const f16* vb = kvbuf + ((size_t)b * C2 + C1 + h * DH) * NPIX;
  float acc[16];
#pragma unroll
  for (int c = 0; c < 16; c++) acc[c] = 0.f;
#pragma unroll
  for (int d = 0; d < 16; d++) {
    float vv = (float)vb[(size_t)d * NPIX + n];
#pragma unroll
    for (int c = 0; c < 16; c++) acc[c] += A[c][d] * vv;
  }
  h8_t o0, o1;
#pragma unroll
  for (int c = 0; c < 8; c++) {
    o0[c] = (f16)acc[c];
    o1[c] = (f16)acc[8 + c];
  }
  size_t base = ((size_t)b * NPIX + n) * 128 + h * 16;
  *(h8_t*)(outA + base) = o0;
  *(h8_t*)(outA + base + 8) = o1;
}

extern "C" void kernel_launch(void* const* d_in, const int* in_sizes, int n_in,
                              void* d_out, int out_size, void* d_ws, size_t ws_size,
                              hipStream_t stream) {
  const float* x = (const float*)d_in[0];
  const float* y = (const float*)d_in[1];
  const float* q_w = (const float*)d_in[2];
  const float* qd_w = (const float*)d_in[3];
  const float* kv_w = (const float*)d_in[4];
  const float* kvd_w = (const float*)d_in[5];
  const float* proj_w = (const float*)d_in[6];
  const float* temperature = (const float*)d_in[7];
  const float* k2_w = (const float*)d_in[8];
  const float* k3_w = (const float*)d_in[9];
  const float* k4_w = (const float*)d_in[10];
  const float* dcn_w = (const float*)d_in[11];
  const float* dcn_b = (const float*)d_in[12];
  const float* pw_w = (const float*)d_in[13];
  const float* pw_b = (const float*)d_in[14];
  float* out = (float*)d_out;

  char* ws = (char*)d_ws;
  size_t off = 0;
  auto alloc = [&](size_t nbytes) {
    char* p = ws + off;
    off += (nbytes + 255) & ~(size_t)255;
    return p;
  };
  f16* CATF = (f16*)alloc((size_t)NB * NPIX * C2 * 2);
  f16* PH = (f16*)alloc((size_t)NB * 4096 * C2 * 2);
  float* A2 = (float*)alloc((size_t)4 * NB * 3844 * C2 * 4);   // 4 split-K partials, NHWC fp32
  f16* OUT3 = (f16*)alloc((size_t)NB * NPIX * C2 * 2);         // f16 NHWC
  float* OF8P = (float*)alloc((size_t)8 * NB * 18 * NPIX * 4); // 8 split-K partials, NCHW fp32
  float* OFFS = (float*)alloc((size_t)NB * 18 * NPIX * 4);
  f16* FEAT = (f16*)alloc((size_t)NB * NPIX * C1 * 2);
  f16* AL = (f16*)alloc((size_t)NB * NPIX * C1 * 2);
  f16* QbH = (f16*)alloc((size_t)NB * C1 * NPIX * 2);
  f16* W2K2 = (f16*)alloc((size_t)72 * 256 * 32 * 2);
  f16* W2K3 = (f16*)alloc((size_t)72 * 256 * 32 * 2);
  f16* W2K4 = (f16*)alloc((size_t)72 * 32 * 32 * 2);
  f16* WD = (f16*)alloc((size_t)128 * 160 * 2);
  f16* WQ = (f16*)alloc((size_t)128 * 128 * 2);
  f16* WPW = (f16*)alloc((size_t)128 * 128 * 2);
  f16* WKV = (f16*)alloc((size_t)256 * 128 * 2);
  f16* WPJ = (f16*)alloc((size_t)128 * 128 * 2);
  float* SACC = (float*)alloc((size_t)(NB * NHEADS * 256 + 512) * 4);
  float* QSS = SACC + NB * NHEADS * 256;
  float* KSS = QSS + 256;

  // region reuse (lifetimes)
  f16* QT1H = OUT3;             // q 1x1 out, f16 NCHW (dead before k3 writes OUT3)
  f16* KV1H = (f16*)A2;         // kv 1x1 out, f16 NCHW (A2 dead after k3's gate)
  f16* KVbH = OUT3;             // kv dw out, f16 NCHW (OUT3 dead after k4)
  f16* AO = FEAT;               // attn out (FEAT dead after pw)

  dim3 blk(256);

  // fused weight prep + SACC/QSS/KSS zero
  wprep_all_k<<<dim3(5314), blk, 0, stream>>>(q_w, pw_w, kv_w, proj_w, dcn_w, k2_w, k3_w, k4_w,
                                              WQ, WPW, WKV, WPJ, WD, W2K2, W2K3, W2K4, SACC);

  // cat split + fused avgpool (all f16)
  splitcat2_k<<<dim3(64, C2 / 32, NB), blk, 0, stream>>>(y, x, CATF, PH);

  // q path: 1x1 MFMA on x-half of catf -> depthwise (all f16)
  gemm1x1_k<C2, C1, false, 2><<<dim3(NPIX / 128, 1, NB), blk, 0, stream>>>(
      CATF, WQ, nullptr, nullptr, QT1H);
  dw3x3h_k<<<dim3(NB * C1 * (NPIX / 8) / 256), blk, 0, stream>>>(QT1H, qd_w, QbH, C1);

  // offset head (fp16 single-product MFMA)
  convh_k<128, 2, 4, 0, 62, 62, 64, 64, 0, 256, 256, false, true>
      <<<dim3(31, 8, NB), blk, 0, stream>>>(PH, W2K2, nullptr, nullptr, nullptr,
                                            A2, (size_t)NB * 3844 * C2, nullptr);
  convh_k<128, 2, 1, 4, 128, 128, 128, 128, 1, 256, 256, true, false>
      <<<dim3(128, 2, NB), blk, 0, stream>>>(CATF, W2K3, y, x, A2, nullptr, 0, OUT3);
  convh_k<32, 1, 8, 0, 128, 128, 128, 128, 1, 18, 32, false, false>
      <<<dim3(128, 8, NB), blk, 0, stream>>>(OUT3, W2K4, nullptr, nullptr, nullptr,
                                             OF8P, (size_t)NB * 18 * NPIX, nullptr);
  reduceN_k<8><<<dim3((NB * 18 * NPIX / 4 + 255) / 256), blk, 0, stream>>>(
      OF8P, OFFS, NB * 18 * NPIX / 4);

  // deformable alignment (gathers from y-half of catf) + pw 1x1
  dgemm_k<<<dim3(NPIX / 128, NG, NB), blk, 0, stream>>>(CATF, OFFS, WD, dcn_b, FEAT);
  gemm1x1_k<C1, 0, true, 1><<<dim3(NPIX / 128, 1, NB), blk, 0, stream>>>(
      FEAT, WPW, pw_b, nullptr, AL);

  // kv path (all f16)
  gemm1x1_k<C1, 0, false, 2><<<dim3(NPIX / 128, 2, NB), blk, 0, stream>>>(
      AL, WKV, nullptr, nullptr, KV1H);
  dw3x3h_k<<<dim3(NB * C2 * (NPIX / 8) / 256), blk, 0, stream>>>(KV1H, kvd_w, KVbH, C2);

  // attention: fp16 MFMA Gram + fused softmax/PV
  gram_k<<<dim3(8, NHEADS, NB), blk, 0, stream>>>(QbH, KVbH, SACC, QSS, KSS);
  attnout_k<<<dim3(NPIX / 256, NHEADS, NB), blk, 0, stream>>>(SACC, QSS, KSS, temperature, KVbH, AO);
  gemm1x1_k<C1, 0, false, 0><<<dim3(NPIX / 128, 1, NB), blk, 0, stream>>>(
      AO, WPJ, nullptr, out, nullptr);
}

// Round 13
// 261.150 us; speedup vs baseline: 2.8751x; 1.0375x over previous
//
#include <hip/hip_runtime.h>
#include <math.h>

#define NB 2
#define C1 128
#define C2 256
#define HH 128
#define WW 128
#define NPIX (HH*WW)
#define NHEADS 8
#define DH 16
#define NG 8

typedef unsigned short u16;
typedef _Float16 f16;
typedef __attribute__((ext_vector_type(8))) _Float16 h8_t;
typedef __attribute__((ext_vector_type(4))) _Float16 h4_t;
typedef __attribute__((ext_vector_type(4))) float f4_t;

__device__ __forceinline__ float sigmoidf_(float v) { return 1.f / (1.f + expf(-v)); }

// ---- NCHW fp32 (y|x) -> NHWC f16 cat + fused 2x2 avgpool (f16 NHWC) ----
__global__ __launch_bounds__(256) void splitcat2_k(const float* __restrict__ y,
                                                   const float* __restrict__ x,
                                                   f16* __restrict__ catf,
                                                   f16* __restrict__ ph) {
  __shared__ float tile[256][33];
  int b = blockIdx.z, c0 = blockIdx.y * 32, rp = blockIdx.x;
  int tid = threadIdx.x;
  const float* src = (c0 < 128) ? y : x;
  int cc0 = c0 & 127;
  const int pbase = rp * 256;
  for (int e = tid; e < 8192; e += 256) {
    int c = e >> 8, p = e & 255;
    tile[p][c] = src[((size_t)b * C1 + cc0 + c) * NPIX + pbase + p];
  }
  __syncthreads();
  for (int e = tid; e < 8192; e += 256) {
    int p = e >> 5, c = e & 31;
    catf[((size_t)b * NPIX + pbase + p) * C2 + c0 + c] = (f16)tile[p][c];
  }
  for (int e = tid; e < 2048; e += 256) {
    int pp = e >> 5, c = e & 31;
    float v = 0.25f * (tile[2 * pp][c] + tile[2 * pp + 1][c] +
                       tile[128 + 2 * pp][c] + tile[128 + 2 * pp + 1][c]);
    ph[((size_t)b * 4096 + rp * 64 + pp) * C2 + c0 + c] = (f16)v;
  }
}

// ---------------- fused weight prep + accumulator zero (one launch) ----------------
__device__ __forceinline__ void wtrans_h(const float* __restrict__ w, f16* __restrict__ w2,
                                         int OC, int OCR, int idx) {
  int t = idx / (256 * OCR);
  int rem = idx - t * 256 * OCR;
  int ic = rem / OCR;
  int oc = rem - ic * OCR;
  float v = (oc < OC) ? w[((size_t)oc * 256 + ic) * 9 + t] : 0.f;
  w2[((size_t)(t * 8 + (ic >> 5)) * OCR + oc) * 32 + (ic & 31)] = (f16)v;
}

__global__ __launch_bounds__(256) void wprep_all_k(
    const float* __restrict__ q_w, const float* __restrict__ pw_w,
    const float* __restrict__ kv_w, const float* __restrict__ proj_w,
    const float* __restrict__ dcn_w, const float* __restrict__ k2_w,
    const float* __restrict__ k3_w, const float* __restrict__ k4_w,
    f16* __restrict__ WQ, f16* __restrict__ WPW, f16* __restrict__ WKV,
    f16* __restrict__ WPJ, f16* __restrict__ WD,
    f16* __restrict__ W2K2, f16* __restrict__ W2K3, f16* __restrict__ W2K4,
    float* __restrict__ sacc) {
  int idx = blockIdx.x * 256 + threadIdx.x;
  if (idx < 16384) { WQ[idx] = (f16)q_w[idx]; return; }
  idx -= 16384;
  if (idx < 16384) { WPW[idx] = (f16)pw_w[idx]; return; }
  idx -= 16384;
  if (idx < 32768) { WKV[idx] = (f16)kv_w[idx]; return; }
  idx -= 32768;
  if (idx < 16384) { WPJ[idx] = (f16)proj_w[idx]; return; }
  idx -= 16384;
  if (idx < 20480) {
    int oc = idx / 160, k = idx - oc * 160;
    int t = k >> 4, ic = k & 15;
    WD[idx] = (t < 9) ? (f16)dcn_w[((size_t)oc * 16 + ic) * 9 + t] : (f16)0.f;
    return;
  }
  idx -= 20480;
  if (idx < 589824) { wtrans_h(k2_w, W2K2, 256, 256, idx); return; }
  idx -= 589824;
  if (idx < 589824) { wtrans_h(k3_w, W2K3, 256, 256, idx); return; }
  idx -= 589824;
  if (idx < 73728) { wtrans_h(k4_w, W2K4, 18, 32, idx); return; }
  idx -= 73728;
  if (idx < 4608) sacc[idx] = 0.f;
}

// ---------------- implicit-GEMM 3x3 conv, fp16 MFMA, dbuf, split-K, PXB px tile ----------------
template<int PXB, int OCB, int NPAN, int SPLITK, int NGB, int WO, int HO, int WI, int HI, int PAD,
         int OCTOT, int OCR, bool GATE, bool OUTF_NHWC, bool SWZ>
__global__ __launch_bounds__(256) void convh_k(
    const f16* __restrict__ inA, const f16* __restrict__ w2,
    const float* __restrict__ gy, const float* __restrict__ gx,
    const float* __restrict__ gB,
    float* __restrict__ outFp, size_t pstride,
    f16* __restrict__ outC) {
  constexpr int CIN = 256;
  constexpr int MF = (PXB == 64) ? 2 : ((OCB == 128) ? 4 : 2);
  constexpr int NF = (OCB == 128) ? 4 : 2;
  constexpr int GCN = 72 / SPLITK;
  __shared__ f16 lds_a[2][PXB * 32];
  __shared__ f16 lds_w[2][OCB * 32];
  const int b = blockIdx.z;
  const int oc0 = (blockIdx.y % NPAN) * OCB;
  const int kz = blockIdx.y / NPAN;
  const int gbase = kz * GCN;
  float* outF = outFp + (size_t)kz * pstride;
  int bidx = blockIdx.x;
  if (SWZ) bidx = (bidx & 7) * ((int)gridDim.x >> 3) + (bidx >> 3);  // XCD-chunked (gridDim.x%8==0)
  const int px0 = bidx * PXB;
  const int tid = threadIdx.x;
  const int lane = tid & 63, wid = tid >> 6;
  const int wpx = (PXB == 64) ? ((wid & 1) * 32)
                              : ((OCB == 128) ? ((wid >> 1) * 64) : (wid * 32));
  const int woc = (PXB == 64) ? ((wid >> 1) * 64)
                              : ((OCB == 128) ? ((wid & 1) * 64) : 0);

  // A stager
  const int art = (PXB == 64) ? (tid >> 2) : (tid >> 1);
  const int aq = (PXB == 64) ? (tid & 3) : 0;      // PXB==64: one 16B slot
  const int shalf = (PXB == 64) ? 0 : (tid & 1);   // PXB==128: two 16B slots
  const int aopx = px0 + art;
  const int apy = aopx / WO, apxx = aopx % WO;
  const bool prow_ok = (aopx < HO * WO);
  int awo0, awo1;
  if (PXB == 64) {
    awo0 = art * 64 + ((aq ^ ((art >> 1) & 3)) << 4);
    awo1 = 0;
  } else {
    const int akey = (art >> 1) & 3;
    awo0 = art * 64 + (((shalf * 2 + 0) ^ akey) << 4);
    awo1 = art * 64 + (((shalf * 2 + 1) ^ akey) << 4);
  }
  // W stager
  const bool wact = (OCB == 128) ? true : (tid < OCB * 2);
  const int wrow = tid >> 1, whalf = tid & 1;
  const int wkey = (wrow >> 1) & 3;
  const int wwo0 = wrow * 64 + (((whalf * 2 + 0) ^ wkey) << 4);
  const int wwo1 = wrow * 64 + (((whalf * 2 + 1) ^ wkey) << 4);

  int aof[MF], wof[NF];
#pragma unroll
  for (int mf = 0; mf < MF; mf++) {
    int r = wpx + mf * 16 + (lane & 15);
    aof[mf] = r * 64 + (((lane >> 4) ^ ((r >> 1) & 3)) << 4);
  }
#pragma unroll
  for (int nf = 0; nf < NF; nf++) {
    int r = woc + nf * 16 + (lane & 15);
    wof[nf] = r * 64 + (((lane >> 4) ^ ((r >> 1) & 3)) << 4);
  }

  f4_t acc[MF][NF];
#pragma unroll
  for (int mf = 0; mf < MF; mf++)
#pragma unroll
    for (int nf = 0; nf < NF; nf++) { f4_t z = {0.f, 0.f, 0.f, 0.f}; acc[mf][nf] = z; }

  const size_t inb = (size_t)b * (HI * WI) * CIN;
  const size_t wg0 = (size_t)(oc0 + wrow) * 32 + (size_t)whalf * 16;
  uint4 ra0, ra1, rw0, rw1;

  auto load_gc = [&](int gc) {
    const int t = gc >> 3, c = gc & 7;
    const int iy = apy + (t / 3) - PAD;
    const int ix = apxx + (t % 3) - PAD;
    const bool val = prow_ok && iy >= 0 && iy < HI && ix >= 0 && ix < WI;
    uint4 z = {0, 0, 0, 0};
    ra0 = z; ra1 = z;
    if (val) {
      if (PXB == 64) {
        ra0 = *(const uint4*)(inA + inb + (size_t)(iy * WI + ix) * CIN + c * 32 + aq * 8);
      } else {
        const uint4* p = (const uint4*)(inA + inb + (size_t)(iy * WI + ix) * CIN + c * 32 + shalf * 16);
        ra0 = p[0];
        ra1 = p[1];
      }
    }
    if (wact) {
      const uint4* q = (const uint4*)(w2 + (size_t)gc * OCR * 32 + wg0);
      rw0 = q[0];
      rw1 = q[1];
    }
  };
  auto store_gc = [&](int nb) {
    char* la = (char*)lds_a[nb];
    char* lw = (char*)lds_w[nb];
    *(uint4*)(la + awo0) = ra0;
    if (PXB == 128) *(uint4*)(la + awo1) = ra1;
    if (wact) {
      *(uint4*)(lw + wwo0) = rw0;
      *(uint4*)(lw + wwo1) = rw1;
    }
  };

  load_gc(gbase);
  store_gc(0);
  __syncthreads();
  for (int i = 0; i < GCN; ++i) {
    const int cb = i & 1;
    if (i < GCN - 1) load_gc(gbase + i + 1);
    const char* la = (const char*)lds_a[cb];
    const char* lw = (const char*)lds_w[cb];
    h8_t af[MF], wf[NF];
#pragma unroll
    for (int mf = 0; mf < MF; mf++) af[mf] = *(const h8_t*)(la + aof[mf]);
#pragma unroll
    for (int nf = 0; nf < NF; nf++) wf[nf] = *(const h8_t*)(lw + wof[nf]);
#pragma unroll
    for (int mf = 0; mf < MF; mf++)
#pragma unroll
      for (int nf = 0; nf < NF; nf++)
        acc[mf][nf] = __builtin_amdgcn_mfma_f32_16x16x32_f16(af[mf], wf[nf], acc[mf][nf], 0, 0, 0);
    if (i < GCN - 1) store_gc(cb ^ 1);
    __syncthreads();
  }

  // epilogue: D row=(lane>>4)*4+r = px, col=lane&15 = oc  [m89-verified]
#pragma unroll
  for (int mf = 0; mf < MF; mf++) {
    const int pxb = px0 + wpx + mf * 16 + ((lane >> 4) << 2);
#pragma unroll
    for (int nf = 0; nf < NF; nf++) {
      const int oc = oc0 + woc + nf * 16 + (lane & 15);
      if (GATE) {
        const float* gp = (oc < 128) ? gy : gx;
        const size_t gbse = ((size_t)b * C1 + (oc & 127)) * NPIX;
        constexpr size_t gstride = (size_t)NB * 3844 * C2;
#pragma unroll
        for (int r = 0; r < 4; r++) {
          const int px = pxb + r;
          const int pyy = px >> 7, px2 = px & 127;
          const int iiy = (pyy * 62) >> 7, iix = (px2 * 62) >> 7;
          const size_t gi = ((size_t)b * 3844 + iiy * 62 + iix) * 256 + oc;
          float gv = gp[gbse + px];
#pragma unroll
          for (int pp = 0; pp < NGB; pp++) gv += gB[gi + (size_t)pp * gstride];
          float v = acc[mf][nf][r] * sigmoidf_(gv);
          outC[((size_t)b * NPIX + px) * C2 + oc] = (f16)v;
        }
      } else if (OUTF_NHWC) {
        if (oc < OCTOT) {
#pragma unroll
          for (int r = 0; r < 4; r++) {
            const int px = pxb + r;
            if (px < HO * WO)
              outF[((size_t)b * (HO * WO) + px) * OCTOT + oc] = acc[mf][nf][r];
          }
        }
      } else {
        if (pxb < HO * WO && oc < OCTOT)
          *(f4_t*)&outF[((size_t)b * OCTOT + oc) * (HO * WO) + pxb] = acc[mf][nf];
      }
    }
  }
}

// ---------------- sum NP split-K partial planes ----------------
template<int NP>
__global__ __launch_bounds__(256) void reduceN_k(const float* __restrict__ p,
                                                 float* __restrict__ o, int n4) {
  int i = blockIdx.x * 256 + threadIdx.x;
  if (i >= n4) return;
  const f4_t* v = (const f4_t*)p;
  f4_t r = v[i];
#pragma unroll
  for (int k = 1; k < NP; k++) {
    f4_t a = v[i + (size_t)k * n4];
    r[0] += a[0]; r[1] += a[1]; r[2] += a[2]; r[3] += a[3];
  }
  ((f4_t*)o)[i] = r;
}

// ---------------- 1x1 conv as fp16 MFMA GEMM, direct-global fragments ----------------
// OUTM: 0 = fp32 NCHW, 1 = f16 NHWC[128], 2 = f16 NCHW
template<int AS, int AOFF, bool BIAS, int OUTM>
__global__ __launch_bounds__(256) void gemm1x1_k(const f16* __restrict__ inA,
                                                 const f16* __restrict__ w,
                                                 const float* __restrict__ bias,
                                                 float* __restrict__ outF,
                                                 f16* __restrict__ outH) {
  const int b = blockIdx.z, nb0 = blockIdx.y * 128, px0 = blockIdx.x * 128;
  const int CoutTot = gridDim.y * 128;
  const int tid = threadIdx.x, lane = tid & 63, wid = tid >> 6;
  const int wpx = px0 + wid * 32;
  const int kslot = (lane >> 4) * 8;

  f4_t acc[2][8];
#pragma unroll
  for (int mf = 0; mf < 2; mf++)
#pragma unroll
    for (int nf = 0; nf < 8; nf++) { f4_t z = {0.f, 0.f, 0.f, 0.f}; acc[mf][nf] = z; }

  size_t arow[2];
#pragma unroll
  for (int mf = 0; mf < 2; mf++)
    arow[mf] = ((size_t)b * NPIX + wpx + mf * 16 + (lane & 15)) * AS + AOFF;
  size_t wrow[8];
#pragma unroll
  for (int nf = 0; nf < 8; nf++)
    wrow[nf] = (size_t)(nb0 + nf * 16 + (lane & 15)) * 128;

#pragma unroll
  for (int ks = 0; ks < 4; ks++) {
    const int ko = ks * 32 + kslot;
    h8_t a[2], bw[8];
#pragma unroll
    for (int mf = 0; mf < 2; mf++) a[mf] = *(const h8_t*)(inA + arow[mf] + ko);
#pragma unroll
    for (int nf = 0; nf < 8; nf++) bw[nf] = *(const h8_t*)(w + wrow[nf] + ko);
#pragma unroll
    for (int mf = 0; mf < 2; mf++)
#pragma unroll
      for (int nf = 0; nf < 8; nf++)
        acc[mf][nf] = __builtin_amdgcn_mfma_f32_16x16x32_f16(a[mf], bw[nf], acc[mf][nf], 0, 0, 0);
  }

#pragma unroll
  for (int mf = 0; mf < 2; mf++) {
    const int pxq = wpx + mf * 16 + (lane >> 4) * 4;
#pragma unroll
    for (int nf = 0; nf < 8; nf++) {
      const int oc = nb0 + nf * 16 + (lane & 15);
      f4_t v = acc[mf][nf];
      if (BIAS) {
        float bv = bias[oc];
        v[0] += bv; v[1] += bv; v[2] += bv; v[3] += bv;
      }
      if (OUTM == 1) {
#pragma unroll
        for (int r = 0; r < 4; r++)
          outH[((size_t)b * NPIX + pxq + r) * 128 + oc] = (f16)v[r];
      } else if (OUTM == 2) {
        h4_t o;
#pragma unroll
        for (int r = 0; r < 4; r++) o[r] = (f16)v[r];
        *(h4_t*)&outH[((size_t)b * CoutTot + oc) * NPIX + pxq] = o;
      } else {
        *(f4_t*)&outF[((size_t)b * CoutTot + oc) * NPIX + pxq] = v;
      }
    }
  }
}

// ---------------- fused modulated-deform-conv: NHWC f16 gather + grouped MFMA ----------------
__global__ __launch_bounds__(256) void dgemm_k(const f16* __restrict__ catf,
                                               const float* __restrict__ offs,
                                               const f16* __restrict__ wd,
                                               const float* __restrict__ dbias,
                                               f16* __restrict__ feat) {
  const int b = blockIdx.z, g = blockIdx.y;
  const int px0 = blockIdx.x * 128;
  const int tid = threadIdx.x;
  const int lane = tid & 63, wid = tid >> 6;
  const int chunk = lane >> 4;
  const int thalf = chunk >> 1;
  const int ic0 = (chunk & 1) * 8;
  const f16* yb = catf + (size_t)b * NPIX * C2;
  const float* ob = offs + (size_t)b * 18 * NPIX;

  int pm[2];
  float pyb[2], pxb2[2];
#pragma unroll
  for (int mf = 0; mf < 2; mf++) {
    pm[mf] = px0 + wid * 32 + mf * 16 + (lane & 15);
    pyb[mf] = (float)(pm[mf] >> 7);
    pxb2[mf] = (float)(pm[mf] & 127);
  }

  f4_t acc[2];
  { f4_t z = {0.f, 0.f, 0.f, 0.f}; acc[0] = z; acc[1] = z; }

  const size_t wbase = (size_t)(g * 16 + (lane & 15)) * 160;
#pragma unroll
  for (int s = 0; s < 5; s++) {
    h8_t ah[2];
#pragma unroll
    for (int mf = 0; mf < 2; mf++) {
      int t = 2 * s + thalf;
      int teff = t > 8 ? 8 : t;
      float dy = ob[(size_t)(2 * teff) * NPIX + pm[mf]];
      float dx = ob[(size_t)(2 * teff + 1) * NPIX + pm[mf]];
      float mk = sigmoidf_(ob[(size_t)teff * NPIX + pm[mf]]);
      int ky = teff / 3, kx = teff - 3 * ky;
      float pyf = pyb[mf] - 1.f + (float)ky + dy;
      float pxf = pxb2[mf] - 1.f + (float)kx + dx;
      float y0f = floorf(pyf), x0f = floorf(pxf);
      float fy = pyf - y0f, fx = pxf - x0f;
      int y0 = (int)y0f, x0 = (int)x0f;
      int y1 = y0 + 1, x1 = x0 + 1;
      float w00 = (1.f - fy) * (1.f - fx) * mk;
      float w01 = (1.f - fy) * fx * mk;
      float w10 = fy * (1.f - fx) * mk;
      float w11 = fy * fx * mk;
      bool vy0 = (y0 >= 0 && y0 < HH), vy1 = (y1 >= 0 && y1 < HH);
      bool vx0 = (x0 >= 0 && x0 < WW), vx1 = (x1 >= 0 && x1 < WW);
      if (!(vy0 && vx0)) w00 = 0.f;
      if (!(vy0 && vx1)) w01 = 0.f;
      if (!(vy1 && vx0)) w10 = 0.f;
      if (!(vy1 && vx1)) w11 = 0.f;
      int cy0 = min(max(y0, 0), HH - 1), cy1 = min(max(y1, 0), HH - 1);
      int cx0 = min(max(x0, 0), WW - 1), cx1 = min(max(x1, 0), WW - 1);
      const f16* p00 = yb + (size_t)(cy0 * WW + cx0) * C2 + g * 16 + ic0;
      const f16* p01 = yb + (size_t)(cy0 * WW + cx1) * C2 + g * 16 + ic0;
      const f16* p10 = yb + (size_t)(cy1 * WW + cx0) * C2 + g * 16 + ic0;
      const f16* p11 = yb + (size_t)(cy1 * WW + cx1) * C2 + g * 16 + ic0;
      h8_t a00 = *(const h8_t*)p00;
      h8_t a01 = *(const h8_t*)p01;
      h8_t a10 = *(const h8_t*)p10;
      h8_t a11 = *(const h8_t*)p11;
      h8_t hh;
#pragma unroll
      for (int j = 0; j < 8; j++) {
        float sv = w00 * (float)a00[j] + w01 * (float)a01[j] +
                   w10 * (float)a10[j] + w11 * (float)a11[j];
        hh[j] = (f16)sv;
      }
      ah[mf] = hh;
    }
    h8_t wv = *(const h8_t*)(wd + wbase + s * 32 + chunk * 8);
#pragma unroll
    for (int mf = 0; mf < 2; mf++)
      acc[mf] = __builtin_amdgcn_mfma_f32_16x16x32_f16(ah[mf], wv, acc[mf], 0, 0, 0);
  }

  const int oc = g * 16 + (lane & 15);
  const float bv = dbias[oc];
#pragma unroll
  for (int mf = 0; mf < 2; mf++) {
    const int pxq = px0 + wid * 32 + mf * 16 + (lane >> 4) * 4;
#pragma unroll
    for (int r = 0; r < 4; r++) {
      float v = fmaxf(acc[mf][r] + bv, 0.f);
      feat[((size_t)b * NPIX + pxq + r) * 128 + oc] = (f16)v;
    }
  }
}

// ---------------- depthwise 3x3, pad=1, f16 NCHW in/out, x8 vectorized ----------------
__global__ __launch_bounds__(256) void dw3x3h_k(const f16* __restrict__ in,
                                                const float* __restrict__ w,
                                                f16* __restrict__ out, int Cc) {
  int i8 = blockIdx.x * 256 + threadIdx.x;
  int total8 = NB * Cc * (NPIX / 8);
  if (i8 >= total8) return;
  int n8 = i8 & (NPIX / 8 - 1);
  int bc = i8 >> 11;
  int c = bc % Cc;
  int n = n8 << 3;
  int yy = n >> 7, xx = n & 127;
  const f16* p = in + (size_t)bc * NPIX;
  const float* wc = w + c * 9;
  float acc[8] = {0.f, 0.f, 0.f, 0.f, 0.f, 0.f, 0.f, 0.f};
#pragma unroll
  for (int ky = 0; ky < 3; ky++) {
    int iy = yy + ky - 1;
    if (iy < 0 || iy >= HH) continue;
    const f16* row = p + iy * WW;
    float v[10];
    v[0] = (xx > 0) ? (float)row[xx - 1] : 0.f;
    h8_t m = *(const h8_t*)(row + xx);
#pragma unroll
    for (int j = 0; j < 8; j++) v[j + 1] = (float)m[j];
    v[9] = (xx + 8 < WW) ? (float)row[xx + 8] : 0.f;
#pragma unroll
    for (int kx = 0; kx < 3; kx++) {
      float wv = wc[ky * 3 + kx];
#pragma unroll
      for (int j = 0; j < 8; j++) acc[j] += wv * v[j + kx];
    }
  }
  h8_t o;
#pragma unroll
  for (int j = 0; j < 8; j++) o[j] = (f16)acc[j];
  *(h8_t*)&out[(size_t)bc * NPIX + n] = o;
}

// ---------------- attention Gram (Q·K^T 16x16 over N=16384) via fp16 MFMA ----------------
__global__ __launch_bounds__(256) void gram_k(const f16* __restrict__ qbuf,
                                              const f16* __restrict__ kvbuf,
                                              float* __restrict__ s_acc,
                                              float* __restrict__ qss,
                                              float* __restrict__ kss) {
  int b = blockIdx.z, h = blockIdx.y;
  int tid = threadIdx.x, lane = tid & 63, wid = tid >> 6;
  int r = lane & 15, ks = lane >> 4;
  const f16* qb = qbuf + ((size_t)b * C1 + h * DH + r) * NPIX;
  const f16* kb = kvbuf + ((size_t)b * C2 + h * DH + r) * NPIX;
  int n0 = (blockIdx.x * 4 + wid) * 512;
  f4_t acc = {0.f, 0.f, 0.f, 0.f};
  float q2 = 0.f, k2 = 0.f;
  for (int s = 0; s < 16; s++) {
    int k = n0 + s * 32 + ks * 8;
    h8_t qv = *(const h8_t*)(qb + k);
    h8_t kv = *(const h8_t*)(kb + k);
#pragma unroll
    for (int j = 0; j < 8; j++) {
      float qf = (float)qv[j], kf = (float)kv[j];
      q2 += qf * qf;
      k2 += kf * kf;
    }
    acc = __builtin_amdgcn_mfma_f32_16x16x32_f16(qv, kv, acc, 0, 0, 0);
  }
  int bh = b * NHEADS + h;
#pragma unroll
  for (int rr = 0; rr < 4; rr++)
    atomicAdd(&s_acc[((size_t)bh * 16 + ks * 4 + rr) * 16 + r], acc[rr]);
  q2 += __shfl_xor(q2, 16);
  q2 += __shfl_xor(q2, 32);
  k2 += __shfl_xor(k2, 16);
  k2 += __shfl_xor(k2, 32);
  if (ks == 0) {
    atomicAdd(&qss[bh * 16 + r], q2);
    atomicAdd(&kss[bh * 16 + r], k2);
  }
}

// ---------------- attention: fused softmax + (attn @ v) -> NHWC f16 ----------------
__global__ __launch_bounds__(256) void attnout_k(const float* __restrict__ s_acc,
                                                 const float* __restrict__ qss,
                                                 const float* __restrict__ kss,
                                                 const float* __restrict__ temp,
                                                 const f16* __restrict__ kvbuf,
                                                 f16* __restrict__ outA) {
  __shared__ float S[16][17];
  __shared__ float A[16][17];
  __shared__ float qn[16], kn[16];
  int b = blockIdx.z, h = blockIdx.y;
  int tid = threadIdx.x;
  int bh = b * NHEADS + h;
  int dd = tid & 15, cc = tid >> 4;
  if (tid < 16) {
    qn[tid] = fmaxf(sqrtf(qss[bh * 16 + tid]), 1e-12f);
    kn[tid] = fmaxf(sqrtf(kss[bh * 16 + tid]), 1e-12f);
  }
  __syncthreads();
  float t = temp[h];
  float s = s_acc[((size_t)bh * 16 + cc) * 16 + dd] / (qn[cc] * kn[dd]) * t;
  S[cc][dd] = s;
  __syncthreads();
  float mx = -1e30f;
#pragma unroll
  for (int j = 0; j < 16; j++) mx = fmaxf(mx, S[cc][j]);
  float sum = 0.f;
#pragma unroll
  for (int j = 0; j < 16; j++) sum += expf(S[cc][j] - mx);
  A[cc][dd] = expf(s - mx) / sum;
  __syncthreads();

  int n = blockIdx.x * 256 + tid;
  const f16* vb = kvbuf + ((size_t)b * C2 + C1 + h * DH) * NPIX;
  float acc[16];
#pragma unroll
  for (int c = 0; c < 16; c++) acc[c] = 0.f;
#pragma unroll
  for (int d = 0; d < 16; d++) {
    float vv = (float)vb[(size_t)d * NPIX + n];
#pragma unroll
    for (int c = 0; c < 16; c++) acc[c] += A[c][d] * vv;
  }
  h8_t o0, o1;
#pragma unroll
  for (int c = 0; c < 8; c++) {
    o0[c] = (f16)acc[c];
    o1[c] = (f16)acc[8 + c];
  }
  size_t base = ((size_t)b * NPIX + n) * 128 + h * 16;
  *(h8_t*)(outA + base) = o0;
  *(h8_t*)(outA + base + 8) = o1;
}

extern "C" void kernel_launch(void* const* d_in, const int* in_sizes, int n_in,
                              void* d_out, int out_size, void* d_ws, size_t ws_size,
                              hipStream_t stream) {
  const float* x = (const float*)d_in[0];
  const float* y = (const float*)d_in[1];
  const float* q_w = (const float*)d_in[2];
  const float* qd_w = (const float*)d_in[3];
  const float* kv_w = (const float*)d_in[4];
  const float* kvd_w = (const float*)d_in[5];
  const float* proj_w = (const float*)d_in[6];
  const float* temperature = (const float*)d_in[7];
  const float* k2_w = (const float*)d_in[8];
  const float* k3_w = (const float*)d_in[9];
  const float* k4_w = (const float*)d_in[10];
  const float* dcn_w = (const float*)d_in[11];
  const float* dcn_b = (const float*)d_in[12];
  const float* pw_w = (const float*)d_in[13];
  const float* pw_b = (const float*)d_in[14];
  float* out = (float*)d_out;

  char* ws = (char*)d_ws;
  size_t off = 0;
  auto alloc = [&](size_t nbytes) {
    char* p = ws + off;
    off += (nbytes + 255) & ~(size_t)255;
    return p;
  };
  f16* CATF = (f16*)alloc((size_t)NB * NPIX * C2 * 2);
  f16* PH = (f16*)alloc((size_t)NB * 4096 * C2 * 2);
  float* A2 = (float*)alloc((size_t)4 * NB * 3844 * C2 * 4);
  f16* OUT3 = (f16*)alloc((size_t)NB * NPIX * C2 * 2);
  float* OF8P = (float*)alloc((size_t)8 * NB * 18 * NPIX * 4);
  float* OFFS = (float*)alloc((size_t)NB * 18 * NPIX * 4);
  f16* FEAT = (f16*)alloc((size_t)NB * NPIX * C1 * 2);
  f16* AL = (f16*)alloc((size_t)NB * NPIX * C1 * 2);
  f16* QbH = (f16*)alloc((size_t)NB * C1 * NPIX * 2);
  f16* W2K2 = (f16*)alloc((size_t)72 * 256 * 32 * 2);
  f16* W2K3 = (f16*)alloc((size_t)72 * 256 * 32 * 2);
  f16* W2K4 = (f16*)alloc((size_t)72 * 32 * 32 * 2);
  f16* WD = (f16*)alloc((size_t)128 * 160 * 2);
  f16* WQ = (f16*)alloc((size_t)128 * 128 * 2);
  f16* WPW = (f16*)alloc((size_t)128 * 128 * 2);
  f16* WKV = (f16*)alloc((size_t)256 * 128 * 2);
  f16* WPJ = (f16*)alloc((size_t)128 * 128 * 2);
  float* SACC = (float*)alloc((size_t)(NB * NHEADS * 256 + 512) * 4);
  float* QSS = SACC + NB * NHEADS * 256;
  float* KSS = QSS + 256;

  // region reuse (lifetimes)
  f16* QT1H = OUT3;             // q 1x1 out, f16 NCHW (dead before k3 writes OUT3)
  f16* KV1H = (f16*)A2;         // kv 1x1 out, f16 NCHW (A2 dead after k3's gate)
  f16* KVbH = OUT3;             // kv dw out, f16 NCHW (OUT3 dead after k4)
  f16* AO = FEAT;               // attn out (FEAT dead after pw)

  dim3 blk(256);

  wprep_all_k<<<dim3(5314), blk, 0, stream>>>(q_w, pw_w, kv_w, proj_w, dcn_w, k2_w, k3_w, k4_w,
                                              WQ, WPW, WKV, WPJ, WD, W2K2, W2K3, W2K4, SACC);

  splitcat2_k<<<dim3(64, C2 / 32, NB), blk, 0, stream>>>(y, x, CATF, PH);

  // q path
  gemm1x1_k<C2, C1, false, 2><<<dim3(NPIX / 128, 1, NB), blk, 0, stream>>>(
      CATF, WQ, nullptr, nullptr, QT1H);
  dw3x3h_k<<<dim3(NB * C1 * (NPIX / 8) / 256), blk, 0, stream>>>(QT1H, qd_w, QbH, C1);

  // offset head (fp16 single-product MFMA)
  convh_k<128, 128, 2, 4, 0, 62, 62, 64, 64, 0, 256, 256, false, true, false>
      <<<dim3(31, 8, NB), blk, 0, stream>>>(PH, W2K2, nullptr, nullptr, nullptr,
                                            A2, (size_t)NB * 3844 * C2, nullptr);
  // k3: 64-px tile (4 blocks/CU) + XCD swizzle
  convh_k<64, 128, 2, 1, 4, 128, 128, 128, 128, 1, 256, 256, true, false, true>
      <<<dim3(256, 2, NB), blk, 0, stream>>>(CATF, W2K3, y, x, A2, nullptr, 0, OUT3);
  convh_k<128, 32, 1, 8, 0, 128, 128, 128, 128, 1, 18, 32, false, false, true>
      <<<dim3(128, 8, NB), blk, 0, stream>>>(OUT3, W2K4, nullptr, nullptr, nullptr,
                                             OF8P, (size_t)NB * 18 * NPIX, nullptr);
  reduceN_k<8><<<dim3((NB * 18 * NPIX / 4 + 255) / 256), blk, 0, stream>>>(
      OF8P, OFFS, NB * 18 * NPIX / 4);

  // deformable alignment + pw 1x1
  dgemm_k<<<dim3(NPIX / 128, NG, NB), blk, 0, stream>>>(CATF, OFFS, WD, dcn_b, FEAT);
  gemm1x1_k<C1, 0, true, 1><<<dim3(NPIX / 128, 1, NB), blk, 0, stream>>>(
      FEAT, WPW, pw_b, nullptr, AL);

  // kv path
  gemm1x1_k<C1, 0, false, 2><<<dim3(NPIX / 128, 2, NB), blk, 0, stream>>>(
      AL, WKV, nullptr, nullptr, KV1H);
  dw3x3h_k<<<dim3(NB * C2 * (NPIX / 8) / 256), blk, 0, stream>>>(KV1H, kvd_w, KVbH, C2);

  // attention
  gram_k<<<dim3(8, NHEADS, NB), blk, 0, stream>>>(QbH, KVbH, SACC, QSS, KSS);
  attnout_k<<<dim3(NPIX / 256, NHEADS, NB), blk, 0, stream>>>(SACC, QSS, KSS, temperature, KVbH, AO);
  gemm1x1_k<C1, 0, false, 0><<<dim3(NPIX / 128, 1, NB), blk, 0, stream>>>(
      AO, WPJ, nullptr, out, nullptr);
}